// Round 1
// baseline (597.604 us; speedup 1.0000x reference)
//
#include <hip/hip_runtime.h>
#include <math.h>

static constexpr float EPSF = 1e-5f;

// ---------------- K0: pack weights into Wj[512][512], Wi[512][512] ----------------
// col c = d*64 + s*32 + p ; s=0 -> o_*, s=1 -> rel_o_*
__global__ void pack_kernel(const float* __restrict__ o_xj, const float* __restrict__ o_xi,
                            const float* __restrict__ rel_o_xj, const float* __restrict__ rel_o_xi,
                            float* __restrict__ Wj, float* __restrict__ Wi) {
  int idx = blockIdx.x * 256 + threadIdx.x;   // 0 .. 524287
  int which = idx >> 18;                      // 0: Wj (rows j), 1: Wi (rows i)
  int e = idx & 262143;
  int r = e >> 9;
  int c = e & 511;
  int d = c >> 6, s = (c >> 5) & 1, p = c & 31;
  const float* src = which ? (s ? rel_o_xi : o_xi) : (s ? rel_o_xj : o_xj);
  float v = src[((size_t)d * 512 + r) * 32 + p];
  (which ? Wi : Wj)[e] = v;
}

// ---------------- K1: per-batch mean/std of x (ddof=1), scaled by 256 ----------------
__global__ void bstats_kernel(const float* __restrict__ x, float* __restrict__ bstat) {
  const int b = blockIdx.x;
  const float* xb = x + (size_t)b * 262144;
  double s = 0.0, s2 = 0.0;
  for (int i = threadIdx.x * 4; i < 262144; i += 256 * 4) {
    float4 v = *reinterpret_cast<const float4*>(&xb[i]);
    s  += (double)v.x + (double)v.y + (double)v.z + (double)v.w;
    s2 += (double)v.x * v.x + (double)v.y * v.y + (double)v.z * v.z + (double)v.w * v.w;
  }
  __shared__ double rs[256], rs2[256];
  rs[threadIdx.x] = s; rs2[threadIdx.x] = s2;
  __syncthreads();
  for (int off = 128; off > 0; off >>= 1) {
    if (threadIdx.x < off) { rs[threadIdx.x] += rs[threadIdx.x + off]; rs2[threadIdx.x] += rs2[threadIdx.x + off]; }
    __syncthreads();
  }
  if (threadIdx.x == 0) {
    const double N = 262144.0;
    double mean = rs[0] / N;
    double var = (rs2[0] - rs[0] * rs[0] / N) / (N - 1.0);
    bstat[b * 2 + 0] = (float)(mean * 256.0);
    bstat[b * 2 + 1] = (float)(sqrt(var < 0.0 ? 0.0 : var) * 256.0);
  }
}

// ---------------- K2: big GEMM + fused epilogue ----------------
// TRANS=false: Y[i][c] = sum_j x[b][i][j] * W[j][c]   (xj path)
// TRANS=true : Y[j][c] = sum_i x[b][i][j] * W[i][c]   (xi path)
// s=0 cols: store tanh -> T, partial sum/sumsq.  s=1 cols: partial column sums of exp.
template<bool TRANS>
__global__ __launch_bounds__(256) void gemm_kernel(const float* __restrict__ x,
                                                   const float* __restrict__ W,
                                                   float* __restrict__ T,
                                                   float* __restrict__ partial) {
  const int d  = blockIdx.x;   // col tile == depth (64 cols per d)
  const int tm = blockIdx.y;   // row tile
  const int b  = blockIdx.z;
  const int tid = threadIdx.x;
  const int ty = tid >> 4, tx = tid & 15;
  __shared__ float As[16][68];
  __shared__ float Bs[16][68];
  __shared__ float red[256];
  __shared__ float red2[256];
  __shared__ float colred[16][32];
  const float* xb = x + (size_t)b * 512 * 512;
  const int m0 = tm * 64, n0 = d * 64;
  float acc[4][4] = {};
  for (int k0 = 0; k0 < 512; k0 += 16) {
    if (TRANS) {
      const int kk = tid >> 4, m4 = (tid & 15) * 4;
      float4 v = *reinterpret_cast<const float4*>(&xb[(size_t)(k0 + kk) * 512 + m0 + m4]);
      *reinterpret_cast<float4*>(&As[kk][m4]) = v;
    } else {
      const int m = tid >> 2, k4 = (tid & 3) * 4;
      float4 v = *reinterpret_cast<const float4*>(&xb[(size_t)(m0 + m) * 512 + k0 + k4]);
      As[k4 + 0][m] = v.x; As[k4 + 1][m] = v.y; As[k4 + 2][m] = v.z; As[k4 + 3][m] = v.w;
    }
    {
      const int kk = tid >> 4, n4 = (tid & 15) * 4;
      float4 v = *reinterpret_cast<const float4*>(&W[(size_t)(k0 + kk) * 512 + n0 + n4]);
      *reinterpret_cast<float4*>(&Bs[kk][n4]) = v;
    }
    __syncthreads();
    #pragma unroll
    for (int kk = 0; kk < 16; ++kk) {
      float4 a  = *reinterpret_cast<const float4*>(&As[kk][ty * 4]);
      float4 bv = *reinterpret_cast<const float4*>(&Bs[kk][tx * 4]);
      float av[4] = {a.x, a.y, a.z, a.w};
      float bb[4] = {bv.x, bv.y, bv.z, bv.w};
      #pragma unroll
      for (int r = 0; r < 4; ++r)
        #pragma unroll
        for (int c = 0; c < 4; ++c)
          acc[r][c] = fmaf(av[r], bb[c], acc[r][c]);
    }
    __syncthreads();
  }
  // epilogue
  float lsum = 0.f, lsq = 0.f;
  float cs[4] = {0.f, 0.f, 0.f, 0.f};
  if (tx < 8) {
    #pragma unroll
    for (int r = 0; r < 4; ++r) {
      const int ig = m0 + ty * 4 + r;
      #pragma unroll
      for (int c = 0; c < 4; ++c) {
        const int p = tx * 4 + c;
        float v = tanhf(acc[r][c]);
        T[(((size_t)b * 8 + d) * 512 + ig) * 32 + p] = v;
        lsum += v; lsq += v * v;
      }
    }
  } else {
    #pragma unroll
    for (int r = 0; r < 4; ++r)
      #pragma unroll
      for (int c = 0; c < 4; ++c)
        cs[c] += expf(acc[r][c]);
  }
  red[tid] = lsum; red2[tid] = lsq;
  if (tx >= 8) {
    const int cb = (tx - 8) * 4;
    #pragma unroll
    for (int c = 0; c < 4; ++c) colred[ty][cb + c] = cs[c];
  }
  __syncthreads();
  for (int off = 128; off > 0; off >>= 1) {
    if (tid < off) { red[tid] += red[tid + off]; red2[tid] += red2[tid + off]; }
    __syncthreads();
  }
  float* pb = partial + (((size_t)b * 8 + tm) * 8 + d) * 34;
  if (tid == 0) { pb[0] = red[0]; pb[1] = red2[0]; }
  if (tid < 32) {
    float s = 0.f;
    #pragma unroll
    for (int t = 0; t < 16; ++t) s += colred[t][tid];
    pb[2 + tid] = s;
  }
}

// ---------------- K3: fold the 8 row-tile partials -> per-(b,d) stats ----------------
// stats[bd][68]: [0]=meanJ [1]=rstdJ [2]=meanI [3]=rstdI [4..35]=orelJ [36..67]=orelI
__global__ void reduce_stats_kernel(const float* __restrict__ pJ, const float* __restrict__ pI,
                                    float* __restrict__ stats) {
  const int bd = blockIdx.x;
  const int b = bd >> 3, d = bd & 7;
  const int t = threadIdx.x;   // 128 threads
  __shared__ float tmp[2][34];
  if (t < 34) {
    float v = 0.f;
    for (int tm = 0; tm < 8; ++tm) v += pJ[(((size_t)b * 8 + tm) * 8 + d) * 34 + t];
    tmp[0][t] = v;
  } else if (t >= 64 && t < 98) {
    const int u = t - 64;
    float v = 0.f;
    for (int tm = 0; tm < 8; ++tm) v += pI[(((size_t)b * 8 + tm) * 8 + d) * 34 + u];
    tmp[1][u] = v;
  }
  __syncthreads();
  if (t < 2) {
    const float* tp = tmp[t];
    float* st = stats + (size_t)bd * 68;
    const float N = 16384.f;
    float mean = tp[0] / N;
    float var = (tp[1] - tp[0] * tp[0] / N) / (N - 1.f);
    float rstd = 1.f / (sqrtf(fmaxf(var, 0.f)) + EPSF);
    st[t * 2 + 0] = mean;
    st[t * 2 + 1] = rstd;
    float tot = 0.f;
    for (int k = 0; k < 32; ++k) tot += tp[2 + k];
    float inv = 1.f / tot;
    for (int k = 0; k < 32; ++k) st[4 + t * 32 + k] = tp[2 + k] * inv;
  }
}

// ---------------- K4: per-(b,d) stage 3 ----------------
__global__ __launch_bounds__(256) void stage3_kernel(
    const float* __restrict__ Txj, const float* __restrict__ Txi,
    const float* __restrict__ p_xj, const float* __restrict__ p_xi,
    const float* __restrict__ rel_pj, const float* __restrict__ rel_pi,
    const float* __restrict__ stats, const float* __restrict__ bstat,
    const float* __restrict__ gamma_p, const float* __restrict__ beta_p,
    float* __restrict__ xball) {
  const int bd = blockIdx.x;
  const int b = bd >> 3, d = bd & 7;
  const int tid = threadIdx.x;
  const int row = tid >> 3;       // 0..31
  const int c4 = (tid & 7) * 4;   // col base
  __shared__ float Ts[64][32];
  __shared__ float Ws[64][32];
  __shared__ float Vj[32][33];
  __shared__ float U[32][33];
  __shared__ float R[32][32];
  __shared__ float cred[32][33];
  __shared__ float red[256];
  __shared__ float red2[256];
  __shared__ float colW[32];
  __shared__ float fj[32], fi[32];
  __shared__ float sred[2];
  const float* st = stats + (size_t)bd * 68;
  const float meanJ = st[0], rstdJ = st[1], meanI = st[2], rstdI = st[3];

  // ===================== path J =====================
  { // colW[q] = sum_i p_xj[d][i][q]
    const int q = tid & 31, g = tid >> 5;
    float s = 0.f;
    const float* wp = p_xj + (size_t)d * 512 * 32;
    for (int i = g * 64; i < g * 64 + 64; ++i) s += wp[(size_t)i * 32 + q];
    red[tid] = s;
    __syncthreads();
    if (g == 0) {
      float v = 0.f;
      for (int gg = 0; gg < 8; ++gg) v += red[gg * 32 + q];
      colW[q] = v;
    }
    __syncthreads();
  }
  float acc[4] = {0.f, 0.f, 0.f, 0.f};
  {
    const float* Tb = Txj + (size_t)bd * 512 * 32;
    const float* wp = p_xj + (size_t)d * 512 * 32;
    for (int i0 = 0; i0 < 512; i0 += 64) {
      #pragma unroll
      for (int l = 0; l < 2; ++l) {
        const int e = tid + l * 256;
        const int ii = e >> 3, p4 = (e & 7) * 4;
        *reinterpret_cast<float4*>(&Ts[ii][p4]) = *reinterpret_cast<const float4*>(&Tb[(size_t)(i0 + ii) * 32 + p4]);
        *reinterpret_cast<float4*>(&Ws[ii][p4]) = *reinterpret_cast<const float4*>(&wp[(size_t)(i0 + ii) * 32 + p4]);
      }
      __syncthreads();
      #pragma unroll 8
      for (int ii = 0; ii < 64; ++ii) {
        const float tv = Ts[ii][row];                                  // T[i][p=row]
        const float4 wv = *reinterpret_cast<const float4*>(&Ws[ii][c4]); // W[i][q]
        acc[0] = fmaf(tv, wv.x, acc[0]);
        acc[1] = fmaf(tv, wv.y, acc[1]);
        acc[2] = fmaf(tv, wv.z, acc[2]);
        acc[3] = fmaf(tv, wv.w, acc[3]);
      }
      __syncthreads();
    }
  }
  { // Vj[p][q] = standardized tanh((acc - meanJ*colW[q]) * rstdJ)
    float tv[4]; float ls = 0.f, lq = 0.f;
    #pragma unroll
    for (int e = 0; e < 4; ++e) {
      float v = (acc[e] - meanJ * colW[c4 + e]) * rstdJ;
      float t = tanhf(v);
      tv[e] = t; ls += t; lq += t * t;
    }
    red[tid] = ls; red2[tid] = lq;
    __syncthreads();
    for (int off = 128; off > 0; off >>= 1) {
      if (tid < off) { red[tid] += red[tid + off]; red2[tid] += red2[tid + off]; }
      __syncthreads();
    }
    if (tid == 0) {
      float s = red[0], ss = red2[0];
      float m = s / 1024.f;
      float var = (ss - s * s / 1024.f) / 1023.f;
      sred[0] = m; sred[1] = 1.f / (sqrtf(fmaxf(var, 0.f)) + EPSF);
    }
    __syncthreads();
    const float m2 = sred[0], r2 = sred[1];
    #pragma unroll
    for (int e = 0; e < 4; ++e) Vj[row][c4 + e] = (tv[e] - m2) * r2;
    __syncthreads();
  }
  { // rel J: r1 = Vj @ rel_pj[d]; softmax colsum -> fj
    for (int l = tid; l < 1024; l += 256) (&R[0][0])[l] = rel_pj[(size_t)d * 1024 + l];
    __syncthreads();
    float racc[4] = {0.f, 0.f, 0.f, 0.f};
    #pragma unroll
    for (int c = 0; c < 32; ++c) {
      const float v = Vj[row][c];
      racc[0] = fmaf(v, R[c][c4 + 0], racc[0]);
      racc[1] = fmaf(v, R[c][c4 + 1], racc[1]);
      racc[2] = fmaf(v, R[c][c4 + 2], racc[2]);
      racc[3] = fmaf(v, R[c][c4 + 3], racc[3]);
    }
    #pragma unroll
    for (int e = 0; e < 4; ++e) cred[row][c4 + e] = expf(racc[e]);
    __syncthreads();
    if (tid < 32) {
      float s = 0.f;
      for (int p = 0; p < 32; ++p) s += cred[p][tid];
      red[tid] = s;
    }
    __syncthreads();
    if (tid == 0) {
      float tot = 0.f;
      for (int k = 0; k < 32; ++k) tot += red[k];
      sred[0] = tot;
    }
    __syncthreads();
    if (tid < 32) {
      float prel = red[tid] / sred[0];
      fj[tid] = sqrtf(st[4 + tid] / prel);
    }
    __syncthreads();
  }

  // ===================== path I =====================
  { // colW[q] = sum_j p_xi[d][j][q]
    const int q = tid & 31, g = tid >> 5;
    float s = 0.f;
    const float* wp = p_xi + (size_t)d * 512 * 32;
    for (int i = g * 64; i < g * 64 + 64; ++i) s += wp[(size_t)i * 32 + q];
    __syncthreads();
    red[tid] = s;
    __syncthreads();
    if (g == 0) {
      float v = 0.f;
      for (int gg = 0; gg < 8; ++gg) v += red[gg * 32 + q];
      colW[q] = v;
    }
    __syncthreads();
  }
  float acc2[4] = {0.f, 0.f, 0.f, 0.f};
  {
    const float* Tb = Txi + (size_t)bd * 512 * 32;
    const float* wp = p_xi + (size_t)d * 512 * 32;
    for (int i0 = 0; i0 < 512; i0 += 64) {
      #pragma unroll
      for (int l = 0; l < 2; ++l) {
        const int e = tid + l * 256;
        const int ii = e >> 3, p4 = (e & 7) * 4;
        *reinterpret_cast<float4*>(&Ts[ii][p4]) = *reinterpret_cast<const float4*>(&Tb[(size_t)(i0 + ii) * 32 + p4]);
        *reinterpret_cast<float4*>(&Ws[ii][p4]) = *reinterpret_cast<const float4*>(&wp[(size_t)(i0 + ii) * 32 + p4]);
      }
      __syncthreads();
      #pragma unroll 8
      for (int ii = 0; ii < 64; ++ii) {
        const float wvs = Ws[ii][row];                                  // W[j][q=row]
        const float4 tv = *reinterpret_cast<const float4*>(&Ts[ii][c4]); // T[j][p]
        acc2[0] = fmaf(wvs, tv.x, acc2[0]);
        acc2[1] = fmaf(wvs, tv.y, acc2[1]);
        acc2[2] = fmaf(wvs, tv.z, acc2[2]);
        acc2[3] = fmaf(wvs, tv.w, acc2[3]);
      }
      __syncthreads();
    }
  }
  { // U[q=row][p] = standardized tanh((acc2 - meanI*colW[row]) * rstdI)
    float tv[4]; float ls = 0.f, lq = 0.f;
    #pragma unroll
    for (int e = 0; e < 4; ++e) {
      float v = (acc2[e] - meanI * colW[row]) * rstdI;
      float t = tanhf(v);
      tv[e] = t; ls += t; lq += t * t;
    }
    red[tid] = ls; red2[tid] = lq;
    __syncthreads();
    for (int off = 128; off > 0; off >>= 1) {
      if (tid < off) { red[tid] += red[tid + off]; red2[tid] += red2[tid + off]; }
      __syncthreads();
    }
    if (tid == 0) {
      float s = red[0], ss = red2[0];
      float m = s / 1024.f;
      float var = (ss - s * s / 1024.f) / 1023.f;
      sred[0] = m; sred[1] = 1.f / (sqrtf(fmaxf(var, 0.f)) + EPSF);
    }
    __syncthreads();
    const float m2 = sred[0], r2 = sred[1];
    #pragma unroll
    for (int e = 0; e < 4; ++e) U[row][c4 + e] = (tv[e] - m2) * r2;
    __syncthreads();
  }
  { // rel I: r2 = U @ rel_pi[d]; softmax colsum -> fi
    for (int l = tid; l < 1024; l += 256) (&R[0][0])[l] = rel_pi[(size_t)d * 1024 + l];
    __syncthreads();
    float racc[4] = {0.f, 0.f, 0.f, 0.f};
    #pragma unroll
    for (int c = 0; c < 32; ++c) {
      const float v = U[row][c];
      racc[0] = fmaf(v, R[c][c4 + 0], racc[0]);
      racc[1] = fmaf(v, R[c][c4 + 1], racc[1]);
      racc[2] = fmaf(v, R[c][c4 + 2], racc[2]);
      racc[3] = fmaf(v, R[c][c4 + 3], racc[3]);
    }
    #pragma unroll
    for (int e = 0; e < 4; ++e) cred[row][c4 + e] = expf(racc[e]);
    __syncthreads();
    if (tid < 32) {
      float s = 0.f;
      for (int p = 0; p < 32; ++p) s += cred[p][tid];
      red[tid] = s;
    }
    __syncthreads();
    if (tid == 0) {
      float tot = 0.f;
      for (int k = 0; k < 32; ++k) tot += red[k];
      sred[0] = tot;
    }
    __syncthreads();
    if (tid < 32) {
      float prel = red[tid] / sred[0];
      fi[tid] = sqrtf(st[36 + tid] / prel);
    }
    __syncthreads();
  }

  // ===================== combine =====================
  {
    float xv[4]; float ls = 0.f, lq = 0.f;
    #pragma unroll
    for (int e = 0; e < 4; ++e) {
      const int q = c4 + e;
      float v = tanhf(Vj[row][q] * fj[row] * U[q][row] * fi[q]);
      xv[e] = v; ls += v; lq += v * v;
    }
    red[tid] = ls; red2[tid] = lq;
    __syncthreads();
    for (int off = 128; off > 0; off >>= 1) {
      if (tid < off) { red[tid] += red[tid + off]; red2[tid] += red2[tid + off]; }
      __syncthreads();
    }
    if (tid == 0) {
      float s = red[0], ss = red2[0];
      float m = s / 1024.f;
      float var = (ss - s * s / 1024.f) / 1023.f;
      sred[0] = m; sred[1] = 1.f / (sqrtf(fmaxf(var, 0.f)) + EPSF);
    }
    __syncthreads();
    const float m3 = sred[0], r3 = sred[1];
    const float xs = bstat[b * 2 + 1], xm = bstat[b * 2 + 0];
    const float g = gamma_p[d], be = beta_p[d];
    #pragma unroll
    for (int e = 0; e < 4; ++e) {
      float v = (xv[e] - m3) * r3 * xs + xm;
      v = v * g + be;
      xball[(size_t)bd * 1024 + row * 32 + c4 + e] = v;
    }
  }
}

// ---------------- K5: sum over d / D ----------------
__global__ void final_kernel(const float* __restrict__ xball, float* __restrict__ out) {
  const int b = blockIdx.x;
  for (int e = threadIdx.x; e < 1024; e += 256) {
    float s = 0.f;
    #pragma unroll
    for (int d = 0; d < 8; ++d) s += xball[((size_t)(b * 8 + d)) * 1024 + e];
    out[(size_t)b * 1024 + e] = s * 0.125f;
  }
}

extern "C" void kernel_launch(void* const* d_in, const int* in_sizes, int n_in,
                              void* d_out, int out_size, void* d_ws, size_t ws_size,
                              hipStream_t stream) {
  const float* x        = (const float*)d_in[0];
  const float* o_xj     = (const float*)d_in[1];
  const float* o_xi     = (const float*)d_in[2];
  const float* p_xj     = (const float*)d_in[3];
  const float* p_xi     = (const float*)d_in[4];
  const float* rel_o_xj = (const float*)d_in[5];
  const float* rel_o_xi = (const float*)d_in[6];
  const float* rel_p_xj = (const float*)d_in[7];
  const float* rel_p_xi = (const float*)d_in[8];
  const float* gamma_p  = (const float*)d_in[9];
  const float* beta_p   = (const float*)d_in[10];
  float* out = (float*)d_out;

  float* w = (float*)d_ws;
  float* Wj    = w; w += 262144;
  float* Wi    = w; w += 262144;
  float* bstat = w; w += 128;
  float* Txj   = w; w += 8388608;   // [B][D][512][32]
  float* Txi   = w; w += 8388608;
  float* pJ    = w; w += 139264;    // [B][8][D][34]
  float* pI    = w; w += 139264;
  float* stats = w; w += 34816;     // [B*D][68]
  float* xball = w; w += 524288;    // [B*D][1024]

  hipLaunchKernelGGL(pack_kernel, dim3(2048), dim3(256), 0, stream,
                     o_xj, o_xi, rel_o_xj, rel_o_xi, Wj, Wi);
  hipLaunchKernelGGL(bstats_kernel, dim3(64), dim3(256), 0, stream, x, bstat);
  hipLaunchKernelGGL((gemm_kernel<false>), dim3(8, 8, 64), dim3(256), 0, stream, x, Wj, Txj, pJ);
  hipLaunchKernelGGL((gemm_kernel<true>),  dim3(8, 8, 64), dim3(256), 0, stream, x, Wi, Txi, pI);
  hipLaunchKernelGGL(reduce_stats_kernel, dim3(512), dim3(128), 0, stream, pJ, pI, stats);
  hipLaunchKernelGGL(stage3_kernel, dim3(512), dim3(256), 0, stream,
                     Txj, Txi, p_xj, p_xi, rel_p_xj, rel_p_xi, stats, bstat, gamma_p, beta_p, xball);
  hipLaunchKernelGGL(final_kernel, dim3(64), dim3(256), 0, stream, xball, out);
}

// Round 2
// 253.381 us; speedup vs baseline: 2.3585x; 2.3585x over previous
//
#include <hip/hip_runtime.h>
#include <math.h>

static constexpr float EPSF = 1e-5f;

typedef short bf16x8 __attribute__((ext_vector_type(8)));
typedef float f32x4 __attribute__((ext_vector_type(4)));

__device__ inline ushort bf16rn(float f) {
  unsigned u = __float_as_uint(f);
  unsigned r = (u + 0x7FFFu + ((u >> 16) & 1u)) >> 16;
  return (ushort)r;
}
__device__ inline void split2(float f, ushort& hi, ushort& lo) {
  ushort h = bf16rn(f);
  float hf = __uint_as_float(((unsigned)h) << 16);
  hi = h;
  lo = bf16rn(f - hf);
}

__device__ inline void gload16(const ushort* g, ushort* l) {
  __builtin_amdgcn_global_load_lds((const __attribute__((address_space(1))) void*)g,
                                   (__attribute__((address_space(3))) void*)l, 16, 0, 0);
}

// ---------------- K0a: pack W transposed + hi/lo split: Wt[c][k], c = d*64+s*32+p ----------------
__global__ void pack_w(const float* __restrict__ o_xj, const float* __restrict__ o_xi,
                       const float* __restrict__ rel_o_xj, const float* __restrict__ rel_o_xi,
                       ushort* __restrict__ wjhi, ushort* __restrict__ wjlo,
                       ushort* __restrict__ wihi, ushort* __restrict__ wilo) {
  int u = blockIdx.x * 256 + threadIdx.x;   // 2 paths * 512 c * 128 k4 = 131072
  int path = u >> 16;
  int v = u & 65535;
  int c = v >> 7;
  int k4 = (v & 127) << 2;
  int d = c >> 6, s = (c >> 5) & 1, p = c & 31;
  const float* src = path ? (s ? rel_o_xi : o_xi) : (s ? rel_o_xj : o_xj);
  ushort4 hi, lo;
  float f0 = src[((size_t)d * 512 + k4 + 0) * 32 + p];
  float f1 = src[((size_t)d * 512 + k4 + 1) * 32 + p];
  float f2 = src[((size_t)d * 512 + k4 + 2) * 32 + p];
  float f3 = src[((size_t)d * 512 + k4 + 3) * 32 + p];
  split2(f0, hi.x, lo.x); split2(f1, hi.y, lo.y);
  split2(f2, hi.z, lo.z); split2(f3, hi.w, lo.w);
  ushort* whi = path ? wihi : wjhi;
  ushort* wlo = path ? wilo : wjlo;
  *reinterpret_cast<ushort4*>(&whi[(size_t)c * 512 + k4]) = hi;
  *reinterpret_cast<ushort4*>(&wlo[(size_t)c * 512 + k4]) = lo;
}

// ---------------- K0b: convert x -> xhi/xlo and transposed xthi/xtlo ----------------
__global__ __launch_bounds__(256) void convx(const float* __restrict__ x,
                                             ushort* __restrict__ xhi, ushort* __restrict__ xlo,
                                             ushort* __restrict__ xthi, ushort* __restrict__ xtlo) {
  __shared__ float tile[64][65];
  const int ti = blockIdx.x, tj = blockIdx.y, b = blockIdx.z;
  const int i0 = ti * 64, j0 = tj * 64;
  const float* xb = x + (size_t)b * 262144;
  const int tr = threadIdx.x >> 4;
  const int tc = (threadIdx.x & 15) * 4;
  #pragma unroll
  for (int r = 0; r < 4; ++r) {
    const int row = r * 16 + tr;
    float4 v = *reinterpret_cast<const float4*>(&xb[(size_t)(i0 + row) * 512 + j0 + tc]);
    tile[row][tc + 0] = v.x; tile[row][tc + 1] = v.y;
    tile[row][tc + 2] = v.z; tile[row][tc + 3] = v.w;
    ushort4 h, l;
    split2(v.x, h.x, l.x); split2(v.y, h.y, l.y);
    split2(v.z, h.z, l.z); split2(v.w, h.w, l.w);
    size_t o = (size_t)b * 262144 + (size_t)(i0 + row) * 512 + j0 + tc;
    *reinterpret_cast<ushort4*>(&xhi[o]) = h;
    *reinterpret_cast<ushort4*>(&xlo[o]) = l;
  }
  __syncthreads();
  #pragma unroll
  for (int r = 0; r < 4; ++r) {
    const int row = r * 16 + tr;   // local j
    ushort4 h, l;
    float f0 = tile[tc + 0][row];
    float f1 = tile[tc + 1][row];
    float f2 = tile[tc + 2][row];
    float f3 = tile[tc + 3][row];
    split2(f0, h.x, l.x); split2(f1, h.y, l.y);
    split2(f2, h.z, l.z); split2(f3, h.w, l.w);
    size_t o = (size_t)b * 262144 + (size_t)(j0 + row) * 512 + i0 + tc;
    *reinterpret_cast<ushort4*>(&xthi[o]) = h;
    *reinterpret_cast<ushort4*>(&xtlo[o]) = l;
  }
}

// ---------------- K1: batch stats (two stage) ----------------
__global__ void bstats_p(const float* __restrict__ x, double* __restrict__ bpart) {
  const int blk = blockIdx.x;            // 256 blocks
  const int b = blk >> 2, q = blk & 3;
  const float* xb = x + (size_t)b * 262144 + (size_t)q * 65536;
  double s = 0.0, s2 = 0.0;
  for (int i = threadIdx.x * 4; i < 65536; i += 1024) {
    float4 v = *reinterpret_cast<const float4*>(&xb[i]);
    s  += (double)v.x + (double)v.y + (double)v.z + (double)v.w;
    s2 += (double)v.x * v.x + (double)v.y * v.y + (double)v.z * v.z + (double)v.w * v.w;
  }
  __shared__ double rs[256], rs2[256];
  rs[threadIdx.x] = s; rs2[threadIdx.x] = s2;
  __syncthreads();
  for (int off = 128; off > 0; off >>= 1) {
    if (threadIdx.x < off) { rs[threadIdx.x] += rs[threadIdx.x + off]; rs2[threadIdx.x] += rs2[threadIdx.x + off]; }
    __syncthreads();
  }
  if (threadIdx.x == 0) { bpart[blk * 2 + 0] = rs[0]; bpart[blk * 2 + 1] = rs2[0]; }
}

__global__ void bstats_f(const double* __restrict__ bpart, float* __restrict__ bstat) {
  const int b = threadIdx.x;  // 64 threads
  if (b >= 64) return;
  double s = 0.0, s2 = 0.0;
  for (int q = 0; q < 4; ++q) { s += bpart[(b * 4 + q) * 2]; s2 += bpart[(b * 4 + q) * 2 + 1]; }
  const double N = 262144.0;
  double mean = s / N;
  double var = (s2 - s * s / N) / (N - 1.0);
  bstat[b * 2 + 0] = (float)(mean * 256.0);
  bstat[b * 2 + 1] = (float)(sqrt(var < 0.0 ? 0.0 : var) * 256.0);
}

// ---------------- K2: MFMA split-bf16 GEMM + fused epilogue ----------------
// path0: Y = x[b] @ Wj        (rows = i)
// path1: Y = xT[b] @ Wi       (rows = j)
// cols c = d*64 + s*32 + p;  s=0: tanh -> T + sum/sumsq partials; s=1: exp col-sums.
__global__ __launch_bounds__(256) void mfma_gemm(
    const ushort* __restrict__ xhi, const ushort* __restrict__ xlo,
    const ushort* __restrict__ xthi, const ushort* __restrict__ xtlo,
    const ushort* __restrict__ wjhi, const ushort* __restrict__ wjlo,
    const ushort* __restrict__ wihi, const ushort* __restrict__ wilo,
    float* __restrict__ Txj, float* __restrict__ Txi,
    float* __restrict__ pJ, float* __restrict__ pI) {
  const int ct = blockIdx.x, tm = blockIdx.y, bz = blockIdx.z;
  const int b = bz >> 1, path = bz & 1;
  const ushort* Ahi = (path ? xthi : xhi) + (size_t)b * 262144;
  const ushort* Alo = (path ? xtlo : xlo) + (size_t)b * 262144;
  const ushort* Bhi = path ? wihi : wjhi;
  const ushort* Blo = path ? wilo : wjlo;
  float* Tb = (path ? Txi : Txj) + (size_t)b * 131072;
  float* partial = path ? pI : pJ;

  __shared__ alignas(16) ushort As_hi[4096], As_lo[4096], Bs_hi[4096], Bs_lo[4096];
  __shared__ float rsum[4], rsq[4], rcol[4][32];

  const int tid = threadIdx.x;
  const int lane = tid & 63, w = tid >> 6;
  const int wr = w >> 1, wc = w & 1;
  const int m0 = tm * 128, n0 = ct * 128;

  int srow[2], soff[2];
  #pragma unroll
  for (int c = 0; c < 2; ++c) {
    int chunk = c * 256 + w * 64 + lane;
    srow[c] = chunk >> 2;
    soff[c] = (chunk & 3) << 3;
  }

  f32x4 acc[4][4] = {};
  const int fr = lane & 15;
  const int ko = (lane >> 4) << 3;

  for (int k0 = 0; k0 < 512; k0 += 32) {
    #pragma unroll
    for (int c = 0; c < 2; ++c) {
      const int cbase = c * 256 + w * 64;
      const size_t ga = (size_t)(m0 + srow[c]) * 512 + k0 + soff[c];
      const size_t gb = (size_t)(n0 + srow[c]) * 512 + k0 + soff[c];
      gload16(Ahi + ga, &As_hi[cbase * 8]);
      gload16(Alo + ga, &As_lo[cbase * 8]);
      gload16(Bhi + gb, &Bs_hi[cbase * 8]);
      gload16(Blo + gb, &Bs_lo[cbase * 8]);
    }
    __syncthreads();
    bf16x8 ah[4], al[4], bh[4], bl[4];
    #pragma unroll
    for (int mi = 0; mi < 4; ++mi) {
      const int ra = (wr * 64 + mi * 16 + fr) * 32 + ko;
      ah[mi] = *reinterpret_cast<const bf16x8*>(&As_hi[ra]);
      al[mi] = *reinterpret_cast<const bf16x8*>(&As_lo[ra]);
    }
    #pragma unroll
    for (int ni = 0; ni < 4; ++ni) {
      const int rb = (wc * 64 + ni * 16 + fr) * 32 + ko;
      bh[ni] = *reinterpret_cast<const bf16x8*>(&Bs_hi[rb]);
      bl[ni] = *reinterpret_cast<const bf16x8*>(&Bs_lo[rb]);
    }
    #pragma unroll
    for (int mi = 0; mi < 4; ++mi)
      #pragma unroll
      for (int ni = 0; ni < 4; ++ni) {
        acc[mi][ni] = __builtin_amdgcn_mfma_f32_16x16x32_bf16(ah[mi], bh[ni], acc[mi][ni], 0, 0, 0);
        acc[mi][ni] = __builtin_amdgcn_mfma_f32_16x16x32_bf16(ah[mi], bl[ni], acc[mi][ni], 0, 0, 0);
        acc[mi][ni] = __builtin_amdgcn_mfma_f32_16x16x32_bf16(al[mi], bh[ni], acc[mi][ni], 0, 0, 0);
      }
    __syncthreads();
  }

  // -------- epilogue --------
  float lsum = 0.f, lsq = 0.f, cs0 = 0.f, cs1 = 0.f;
  const int d = ct * 2 + wc;
  #pragma unroll
  for (int mi = 0; mi < 4; ++mi) {
    const int rbase = m0 + wr * 64 + mi * 16 + ((lane >> 4) << 2);
    #pragma unroll
    for (int ni = 0; ni < 4; ++ni) {
      #pragma unroll
      for (int r = 0; r < 4; ++r) {
        float v = acc[mi][ni][r];
        if (ni < 2) {
          float t = tanhf(v);
          Tb[((size_t)d * 512 + rbase + r) * 32 + ni * 16 + fr] = t;
          lsum += t; lsq += t * t;
        } else {
          float e = expf(v);
          if (ni == 2) cs0 += e; else cs1 += e;
        }
      }
    }
  }
  #pragma unroll
  for (int m = 1; m < 64; m <<= 1) { lsum += __shfl_xor(lsum, m); lsq += __shfl_xor(lsq, m); }
  cs0 += __shfl_xor(cs0, 16); cs0 += __shfl_xor(cs0, 32);
  cs1 += __shfl_xor(cs1, 16); cs1 += __shfl_xor(cs1, 32);
  if (lane == 0) { rsum[w] = lsum; rsq[w] = lsq; }
  if (lane < 16) { rcol[w][lane] = cs0; rcol[w][16 + lane] = cs1; }
  __syncthreads();
  if (tid < 64) {
    const int wc2 = tid >> 5, p = tid & 31;
    float* pb = partial + (((size_t)b * 4 + tm) * 8 + ct * 2 + wc2) * 34;
    pb[2 + p] = rcol[wc2][p] + rcol[wc2 + 2][p];
    if (p == 0) {
      pb[0] = rsum[wc2] + rsum[wc2 + 2];
      pb[1] = rsq[wc2] + rsq[wc2 + 2];
    }
  }
}

// ---------------- K3: fold the 4 row-tile partials -> per-(b,d) stats ----------------
__global__ void reduce_stats_kernel(const float* __restrict__ pJ, const float* __restrict__ pI,
                                    float* __restrict__ stats) {
  const int bd = blockIdx.x;
  const int b = bd >> 3, d = bd & 7;
  const int t = threadIdx.x;   // 128 threads
  __shared__ float tmp[2][34];
  if (t < 34) {
    float v = 0.f;
    for (int tm = 0; tm < 4; ++tm) v += pJ[(((size_t)b * 4 + tm) * 8 + d) * 34 + t];
    tmp[0][t] = v;
  } else if (t >= 64 && t < 98) {
    const int u = t - 64;
    float v = 0.f;
    for (int tm = 0; tm < 4; ++tm) v += pI[(((size_t)b * 4 + tm) * 8 + d) * 34 + u];
    tmp[1][u] = v;
  }
  __syncthreads();
  if (t < 2) {
    const float* tp = tmp[t];
    float* st = stats + (size_t)bd * 68;
    const float N = 16384.f;
    float mean = tp[0] / N;
    float var = (tp[1] - tp[0] * tp[0] / N) / (N - 1.f);
    float rstd = 1.f / (sqrtf(fmaxf(var, 0.f)) + EPSF);
    st[t * 2 + 0] = mean;
    st[t * 2 + 1] = rstd;
    float tot = 0.f;
    for (int k = 0; k < 32; ++k) tot += tp[2 + k];
    float inv = 1.f / tot;
    for (int k = 0; k < 32; ++k) st[4 + t * 32 + k] = tp[2 + k] * inv;
  }
}

// ---------------- K4: per-(b,d) stage 3 ----------------
__global__ __launch_bounds__(256) void stage3_kernel(
    const float* __restrict__ Txj, const float* __restrict__ Txi,
    const float* __restrict__ p_xj, const float* __restrict__ p_xi,
    const float* __restrict__ rel_pj, const float* __restrict__ rel_pi,
    const float* __restrict__ stats, const float* __restrict__ bstat,
    const float* __restrict__ gamma_p, const float* __restrict__ beta_p,
    float* __restrict__ xball) {
  const int bd = blockIdx.x;
  const int b = bd >> 3, d = bd & 7;
  const int tid = threadIdx.x;
  const int row = tid >> 3;       // 0..31
  const int c4 = (tid & 7) * 4;   // col base
  __shared__ float Ts[64][32];
  __shared__ float Ws[64][32];
  __shared__ float Vj[32][33];
  __shared__ float U[32][33];
  __shared__ float R[32][32];
  __shared__ float cred[32][33];
  __shared__ float red[256];
  __shared__ float red2[256];
  __shared__ float colW[32];
  __shared__ float fj[32], fi[32];
  __shared__ float sred[2];
  const float* st = stats + (size_t)bd * 68;
  const float meanJ = st[0], rstdJ = st[1], meanI = st[2], rstdI = st[3];

  // ===================== path J =====================
  {
    const int q = tid & 31, g = tid >> 5;
    float s = 0.f;
    const float* wp = p_xj + (size_t)d * 512 * 32;
    for (int i = g * 64; i < g * 64 + 64; ++i) s += wp[(size_t)i * 32 + q];
    red[tid] = s;
    __syncthreads();
    if (g == 0) {
      float v = 0.f;
      for (int gg = 0; gg < 8; ++gg) v += red[gg * 32 + q];
      colW[q] = v;
    }
    __syncthreads();
  }
  float acc[4] = {0.f, 0.f, 0.f, 0.f};
  {
    const float* Tb = Txj + (size_t)bd * 512 * 32;
    const float* wp = p_xj + (size_t)d * 512 * 32;
    for (int i0 = 0; i0 < 512; i0 += 64) {
      #pragma unroll
      for (int l = 0; l < 2; ++l) {
        const int e = tid + l * 256;
        const int ii = e >> 3, p4 = (e & 7) * 4;
        *reinterpret_cast<float4*>(&Ts[ii][p4]) = *reinterpret_cast<const float4*>(&Tb[(size_t)(i0 + ii) * 32 + p4]);
        *reinterpret_cast<float4*>(&Ws[ii][p4]) = *reinterpret_cast<const float4*>(&wp[(size_t)(i0 + ii) * 32 + p4]);
      }
      __syncthreads();
      #pragma unroll 8
      for (int ii = 0; ii < 64; ++ii) {
        const float tv = Ts[ii][row];
        const float4 wv = *reinterpret_cast<const float4*>(&Ws[ii][c4]);
        acc[0] = fmaf(tv, wv.x, acc[0]);
        acc[1] = fmaf(tv, wv.y, acc[1]);
        acc[2] = fmaf(tv, wv.z, acc[2]);
        acc[3] = fmaf(tv, wv.w, acc[3]);
      }
      __syncthreads();
    }
  }
  {
    float tv[4]; float ls = 0.f, lq = 0.f;
    #pragma unroll
    for (int e = 0; e < 4; ++e) {
      float v = (acc[e] - meanJ * colW[c4 + e]) * rstdJ;
      float t = tanhf(v);
      tv[e] = t; ls += t; lq += t * t;
    }
    red[tid] = ls; red2[tid] = lq;
    __syncthreads();
    for (int off = 128; off > 0; off >>= 1) {
      if (tid < off) { red[tid] += red[tid + off]; red2[tid] += red2[tid + off]; }
      __syncthreads();
    }
    if (tid == 0) {
      float s = red[0], ss = red2[0];
      float m = s / 1024.f;
      float var = (ss - s * s / 1024.f) / 1023.f;
      sred[0] = m; sred[1] = 1.f / (sqrtf(fmaxf(var, 0.f)) + EPSF);
    }
    __syncthreads();
    const float m2 = sred[0], r2 = sred[1];
    #pragma unroll
    for (int e = 0; e < 4; ++e) Vj[row][c4 + e] = (tv[e] - m2) * r2;
    __syncthreads();
  }
  {
    for (int l = tid; l < 1024; l += 256) (&R[0][0])[l] = rel_pj[(size_t)d * 1024 + l];
    __syncthreads();
    float racc[4] = {0.f, 0.f, 0.f, 0.f};
    #pragma unroll
    for (int c = 0; c < 32; ++c) {
      const float v = Vj[row][c];
      racc[0] = fmaf(v, R[c][c4 + 0], racc[0]);
      racc[1] = fmaf(v, R[c][c4 + 1], racc[1]);
      racc[2] = fmaf(v, R[c][c4 + 2], racc[2]);
      racc[3] = fmaf(v, R[c][c4 + 3], racc[3]);
    }
    #pragma unroll
    for (int e = 0; e < 4; ++e) cred[row][c4 + e] = expf(racc[e]);
    __syncthreads();
    if (tid < 32) {
      float s = 0.f;
      for (int p = 0; p < 32; ++p) s += cred[p][tid];
      red[tid] = s;
    }
    __syncthreads();
    if (tid == 0) {
      float tot = 0.f;
      for (int k = 0; k < 32; ++k) tot += red[k];
      sred[0] = tot;
    }
    __syncthreads();
    if (tid < 32) {
      float prel = red[tid] / sred[0];
      fj[tid] = sqrtf(st[4 + tid] / prel);
    }
    __syncthreads();
  }

  // ===================== path I =====================
  {
    const int q = tid & 31, g = tid >> 5;
    float s = 0.f;
    const float* wp = p_xi + (size_t)d * 512 * 32;
    for (int i = g * 64; i < g * 64 + 64; ++i) s += wp[(size_t)i * 32 + q];
    __syncthreads();
    red[tid] = s;
    __syncthreads();
    if (g == 0) {
      float v = 0.f;
      for (int gg = 0; gg < 8; ++gg) v += red[gg * 32 + q];
      colW[q] = v;
    }
    __syncthreads();
  }
  float acc2[4] = {0.f, 0.f, 0.f, 0.f};
  {
    const float* Tb = Txi + (size_t)bd * 512 * 32;
    const float* wp = p_xi + (size_t)d * 512 * 32;
    for (int i0 = 0; i0 < 512; i0 += 64) {
      #pragma unroll
      for (int l = 0; l < 2; ++l) {
        const int e = tid + l * 256;
        const int ii = e >> 3, p4 = (e & 7) * 4;
        *reinterpret_cast<float4*>(&Ts[ii][p4]) = *reinterpret_cast<const float4*>(&Tb[(size_t)(i0 + ii) * 32 + p4]);
        *reinterpret_cast<float4*>(&Ws[ii][p4]) = *reinterpret_cast<const float4*>(&wp[(size_t)(i0 + ii) * 32 + p4]);
      }
      __syncthreads();
      #pragma unroll 8
      for (int ii = 0; ii < 64; ++ii) {
        const float wvs = Ws[ii][row];
        const float4 tv = *reinterpret_cast<const float4*>(&Ts[ii][c4]);
        acc2[0] = fmaf(wvs, tv.x, acc2[0]);
        acc2[1] = fmaf(wvs, tv.y, acc2[1]);
        acc2[2] = fmaf(wvs, tv.z, acc2[2]);
        acc2[3] = fmaf(wvs, tv.w, acc2[3]);
      }
      __syncthreads();
    }
  }
  {
    float tv[4]; float ls = 0.f, lq = 0.f;
    #pragma unroll
    for (int e = 0; e < 4; ++e) {
      float v = (acc2[e] - meanI * colW[row]) * rstdI;
      float t = tanhf(v);
      tv[e] = t; ls += t; lq += t * t;
    }
    red[tid] = ls; red2[tid] = lq;
    __syncthreads();
    for (int off = 128; off > 0; off >>= 1) {
      if (tid < off) { red[tid] += red[tid + off]; red2[tid] += red2[tid + off]; }
      __syncthreads();
    }
    if (tid == 0) {
      float s = red[0], ss = red2[0];
      float m = s / 1024.f;
      float var = (ss - s * s / 1024.f) / 1023.f;
      sred[0] = m; sred[1] = 1.f / (sqrtf(fmaxf(var, 0.f)) + EPSF);
    }
    __syncthreads();
    const float m2 = sred[0], r2 = sred[1];
    #pragma unroll
    for (int e = 0; e < 4; ++e) U[row][c4 + e] = (tv[e] - m2) * r2;
    __syncthreads();
  }
  {
    for (int l = tid; l < 1024; l += 256) (&R[0][0])[l] = rel_pi[(size_t)d * 1024 + l];
    __syncthreads();
    float racc[4] = {0.f, 0.f, 0.f, 0.f};
    #pragma unroll
    for (int c = 0; c < 32; ++c) {
      const float v = U[row][c];
      racc[0] = fmaf(v, R[c][c4 + 0], racc[0]);
      racc[1] = fmaf(v, R[c][c4 + 1], racc[1]);
      racc[2] = fmaf(v, R[c][c4 + 2], racc[2]);
      racc[3] = fmaf(v, R[c][c4 + 3], racc[3]);
    }
    #pragma unroll
    for (int e = 0; e < 4; ++e) cred[row][c4 + e] = expf(racc[e]);
    __syncthreads();
    if (tid < 32) {
      float s = 0.f;
      for (int p = 0; p < 32; ++p) s += cred[p][tid];
      red[tid] = s;
    }
    __syncthreads();
    if (tid == 0) {
      float tot = 0.f;
      for (int k = 0; k < 32; ++k) tot += red[k];
      sred[0] = tot;
    }
    __syncthreads();
    if (tid < 32) {
      float prel = red[tid] / sred[0];
      fi[tid] = sqrtf(st[36 + tid] / prel);
    }
    __syncthreads();
  }

  // ===================== combine =====================
  {
    float xv[4]; float ls = 0.f, lq = 0.f;
    #pragma unroll
    for (int e = 0; e < 4; ++e) {
      const int q = c4 + e;
      float v = tanhf(Vj[row][q] * fj[row] * U[q][row] * fi[q]);
      xv[e] = v; ls += v; lq += v * v;
    }
    red[tid] = ls; red2[tid] = lq;
    __syncthreads();
    for (int off = 128; off > 0; off >>= 1) {
      if (tid < off) { red[tid] += red[tid + off]; red2[tid] += red2[tid + off]; }
      __syncthreads();
    }
    if (tid == 0) {
      float s = red[0], ss = red2[0];
      float m = s / 1024.f;
      float var = (ss - s * s / 1024.f) / 1023.f;
      sred[0] = m; sred[1] = 1.f / (sqrtf(fmaxf(var, 0.f)) + EPSF);
    }
    __syncthreads();
    const float m3 = sred[0], r3 = sred[1];
    const float xs = bstat[b * 2 + 1], xm = bstat[b * 2 + 0];
    const float g = gamma_p[d], be = beta_p[d];
    #pragma unroll
    for (int e = 0; e < 4; ++e) {
      float v = (xv[e] - m3) * r3 * xs + xm;
      v = v * g + be;
      xball[(size_t)bd * 1024 + row * 32 + c4 + e] = v;
    }
  }
}

// ---------------- K5: sum over d / D ----------------
__global__ void final_kernel(const float* __restrict__ xball, float* __restrict__ out) {
  const int b = blockIdx.x;
  for (int e = threadIdx.x; e < 1024; e += 256) {
    float s = 0.f;
    #pragma unroll
    for (int d = 0; d < 8; ++d) s += xball[((size_t)(b * 8 + d)) * 1024 + e];
    out[(size_t)b * 1024 + e] = s * 0.125f;
  }
}

extern "C" void kernel_launch(void* const* d_in, const int* in_sizes, int n_in,
                              void* d_out, int out_size, void* d_ws, size_t ws_size,
                              hipStream_t stream) {
  const float* x        = (const float*)d_in[0];
  const float* o_xj     = (const float*)d_in[1];
  const float* o_xi     = (const float*)d_in[2];
  const float* p_xj     = (const float*)d_in[3];
  const float* p_xi     = (const float*)d_in[4];
  const float* rel_o_xj = (const float*)d_in[5];
  const float* rel_o_xi = (const float*)d_in[6];
  const float* rel_p_xj = (const float*)d_in[7];
  const float* rel_p_xi = (const float*)d_in[8];
  const float* gamma_p  = (const float*)d_in[9];
  const float* beta_p   = (const float*)d_in[10];
  float* out = (float*)d_out;

  char* base = (char*)d_ws;
  ushort* xhi  = (ushort*)base; base += (size_t)33554432;
  ushort* xlo  = (ushort*)base; base += (size_t)33554432;
  ushort* xthi = (ushort*)base; base += (size_t)33554432;
  ushort* xtlo = (ushort*)base; base += (size_t)33554432;
  ushort* wjhi = (ushort*)base; base += 524288;
  ushort* wjlo = (ushort*)base; base += 524288;
  ushort* wihi = (ushort*)base; base += 524288;
  ushort* wilo = (ushort*)base; base += 524288;
  float* Txj   = (float*)base;  base += (size_t)33554432;
  float* Txi   = (float*)base;  base += (size_t)33554432;
  float* pJ    = (float*)base;  base += 278528;
  float* pI    = (float*)base;  base += 278528;
  double* bpart = (double*)base; base += 4096;
  float* bstat = (float*)base;  base += 512;
  float* stats = (float*)base;  base += 139264;
  float* xball = (float*)base;  base += 2097152;

  hipLaunchKernelGGL(pack_w, dim3(512), dim3(256), 0, stream,
                     o_xj, o_xi, rel_o_xj, rel_o_xi, wjhi, wjlo, wihi, wilo);
  hipLaunchKernelGGL(convx, dim3(8, 8, 64), dim3(256), 0, stream, x, xhi, xlo, xthi, xtlo);
  hipLaunchKernelGGL(bstats_p, dim3(256), dim3(256), 0, stream, x, bpart);
  hipLaunchKernelGGL(bstats_f, dim3(1), dim3(64), 0, stream, bpart, bstat);
  hipLaunchKernelGGL(mfma_gemm, dim3(4, 4, 128), dim3(256), 0, stream,
                     xhi, xlo, xthi, xtlo, wjhi, wjlo, wihi, wilo, Txj, Txi, pJ, pI);
  hipLaunchKernelGGL(reduce_stats_kernel, dim3(512), dim3(128), 0, stream, pJ, pI, stats);
  hipLaunchKernelGGL(stage3_kernel, dim3(512), dim3(256), 0, stream,
                     Txj, Txi, p_xj, p_xi, rel_p_xj, rel_p_xi, stats, bstat, gamma_p, beta_p, xball);
  hipLaunchKernelGGL(final_kernel, dim3(64), dim3(256), 0, stream, xball, out);
}

// Round 3
// 250.248 us; speedup vs baseline: 2.3880x; 1.0125x over previous
//
#include <hip/hip_runtime.h>
#include <math.h>

static constexpr float EPSF = 1e-5f;

typedef short bf16x8 __attribute__((ext_vector_type(8)));
typedef float f32x4 __attribute__((ext_vector_type(4)));
typedef ushort u16x8 __attribute__((ext_vector_type(8)));

__device__ inline ushort bf16rn(float f) {
  unsigned u = __float_as_uint(f);
  unsigned r = (u + 0x7FFFu + ((u >> 16) & 1u)) >> 16;
  return (ushort)r;
}
__device__ inline float bf2f(ushort u) { return __uint_as_float(((unsigned)u) << 16); }
__device__ inline void split2(float f, ushort& hi, ushort& lo) {
  ushort h = bf16rn(f);
  float hf = bf2f(h);
  hi = h;
  lo = bf16rn(f - hf);
}

__device__ inline void gload16(const ushort* g, ushort* l) {
  __builtin_amdgcn_global_load_lds((const __attribute__((address_space(1))) void*)g,
                                   (__attribute__((address_space(3))) void*)l, 16, 0, 0);
}

// ---------------- K0a: pack W transposed + hi/lo split: Wt[c][k], c = d*64+s*32+p ----------------
__global__ void pack_w(const float* __restrict__ o_xj, const float* __restrict__ o_xi,
                       const float* __restrict__ rel_o_xj, const float* __restrict__ rel_o_xi,
                       ushort* __restrict__ wjhi, ushort* __restrict__ wjlo,
                       ushort* __restrict__ wihi, ushort* __restrict__ wilo) {
  int u = blockIdx.x * 256 + threadIdx.x;   // 2 paths * 512 c * 128 k4 = 131072
  int path = u >> 16;
  int v = u & 65535;
  int c = v >> 7;
  int k4 = (v & 127) << 2;
  int d = c >> 6, s = (c >> 5) & 1, p = c & 31;
  const float* src = path ? (s ? rel_o_xi : o_xi) : (s ? rel_o_xj : o_xj);
  ushort4 hi, lo;
  float f0 = src[((size_t)d * 512 + k4 + 0) * 32 + p];
  float f1 = src[((size_t)d * 512 + k4 + 1) * 32 + p];
  float f2 = src[((size_t)d * 512 + k4 + 2) * 32 + p];
  float f3 = src[((size_t)d * 512 + k4 + 3) * 32 + p];
  split2(f0, hi.x, lo.x); split2(f1, hi.y, lo.y);
  split2(f2, hi.z, lo.z); split2(f3, hi.w, lo.w);
  ushort* whi = path ? wihi : wjhi;
  ushort* wlo = path ? wilo : wjlo;
  *reinterpret_cast<ushort4*>(&whi[(size_t)c * 512 + k4]) = hi;
  *reinterpret_cast<ushort4*>(&wlo[(size_t)c * 512 + k4]) = lo;
}

// ---------------- K0b: convert x -> xhi/xlo and transposed xthi/xtlo; fused batch-stat partials ----------------
__global__ __launch_bounds__(256) void convx(const float* __restrict__ x,
                                             ushort* __restrict__ xhi, ushort* __restrict__ xlo,
                                             ushort* __restrict__ xthi, ushort* __restrict__ xtlo,
                                             float* __restrict__ bpart) {
  __shared__ float tile[64][65];
  __shared__ float rs[256], rs2[256];
  const int ti = blockIdx.x, tj = blockIdx.y, b = blockIdx.z;
  const int i0 = ti * 64, j0 = tj * 64;
  const float* xb = x + (size_t)b * 262144;
  const int tr = threadIdx.x >> 4;
  const int tc = (threadIdx.x & 15) * 4;
  float s = 0.f, s2 = 0.f;
  #pragma unroll
  for (int r = 0; r < 4; ++r) {
    const int row = r * 16 + tr;
    float4 v = *reinterpret_cast<const float4*>(&xb[(size_t)(i0 + row) * 512 + j0 + tc]);
    tile[row][tc + 0] = v.x; tile[row][tc + 1] = v.y;
    tile[row][tc + 2] = v.z; tile[row][tc + 3] = v.w;
    s += v.x + v.y + v.z + v.w;
    s2 += v.x * v.x + v.y * v.y + v.z * v.z + v.w * v.w;
    ushort4 h, l;
    split2(v.x, h.x, l.x); split2(v.y, h.y, l.y);
    split2(v.z, h.z, l.z); split2(v.w, h.w, l.w);
    size_t o = (size_t)b * 262144 + (size_t)(i0 + row) * 512 + j0 + tc;
    *reinterpret_cast<ushort4*>(&xhi[o]) = h;
    *reinterpret_cast<ushort4*>(&xlo[o]) = l;
  }
  __syncthreads();
  #pragma unroll
  for (int r = 0; r < 4; ++r) {
    const int row = r * 16 + tr;   // local j
    ushort4 h, l;
    float f0 = tile[tc + 0][row];
    float f1 = tile[tc + 1][row];
    float f2 = tile[tc + 2][row];
    float f3 = tile[tc + 3][row];
    split2(f0, h.x, l.x); split2(f1, h.y, l.y);
    split2(f2, h.z, l.z); split2(f3, h.w, l.w);
    size_t o = (size_t)b * 262144 + (size_t)(j0 + row) * 512 + i0 + tc;
    *reinterpret_cast<ushort4*>(&xthi[o]) = h;
    *reinterpret_cast<ushort4*>(&xtlo[o]) = l;
  }
  rs[threadIdx.x] = s; rs2[threadIdx.x] = s2;
  __syncthreads();
  for (int off = 128; off > 0; off >>= 1) {
    if (threadIdx.x < off) { rs[threadIdx.x] += rs[threadIdx.x + off]; rs2[threadIdx.x] += rs2[threadIdx.x + off]; }
    __syncthreads();
  }
  if (threadIdx.x == 0) {
    float* pb = bpart + ((size_t)b * 64 + tj * 8 + ti) * 2;
    pb[0] = rs[0]; pb[1] = rs2[0];
  }
}

__global__ void bstats_f(const float* __restrict__ bpart, float* __restrict__ bstat) {
  const int b = threadIdx.x;  // 64 threads
  if (b >= 64) return;
  double s = 0.0, s2 = 0.0;
  for (int q = 0; q < 64; ++q) {
    s += (double)bpart[((size_t)b * 64 + q) * 2];
    s2 += (double)bpart[((size_t)b * 64 + q) * 2 + 1];
  }
  const double N = 262144.0;
  double mean = s / N;
  double var = (s2 - s * s / N) / (N - 1.0);
  bstat[b * 2 + 0] = (float)(mean * 256.0);
  bstat[b * 2 + 1] = (float)(sqrt(var < 0.0 ? 0.0 : var) * 256.0);
}

// ---------------- K2: MFMA split-bf16 GEMM + fused epilogue ----------------
// LDS layout per operand: [kc=4][row=128][8 ushorts]  (conflict-free fragment reads)
__global__ __launch_bounds__(256) void mfma_gemm(
    const ushort* __restrict__ xhi, const ushort* __restrict__ xlo,
    const ushort* __restrict__ xthi, const ushort* __restrict__ xtlo,
    const ushort* __restrict__ wjhi, const ushort* __restrict__ wjlo,
    const ushort* __restrict__ wihi, const ushort* __restrict__ wilo,
    ushort* __restrict__ Txj, ushort* __restrict__ Txi,
    float* __restrict__ pJ, float* __restrict__ pI) {
  const int id = blockIdx.x;
  const int wid = (id & 7) * 256 + (id >> 3);   // XCD-aware swizzle (2048 = 8*256)
  const int ct = wid & 3, tm = (wid >> 2) & 3, bz = wid >> 4;
  const int b = bz >> 1, path = bz & 1;
  const ushort* Ahi = (path ? xthi : xhi) + (size_t)b * 262144;
  const ushort* Alo = (path ? xtlo : xlo) + (size_t)b * 262144;
  const ushort* Bhi = path ? wihi : wjhi;
  const ushort* Blo = path ? wilo : wjlo;
  ushort* Tb = (path ? Txi : Txj) + (size_t)b * 131072;
  float* partial = path ? pI : pJ;

  __shared__ alignas(16) ushort As_hi[4096], As_lo[4096], Bs_hi[4096], Bs_lo[4096];
  __shared__ float rsum[4], rsq[4], rcol[4][32];

  const int tid = threadIdx.x;
  const int lane = tid & 63, w = tid >> 6;
  const int wr = w >> 1, wc = w & 1;
  const int m0 = tm * 128, n0 = ct * 128;

  const int c0 = w * 64 + lane;
  const int srow = c0 & 127;
  const int skc = c0 >> 7;            // 0 or 1 (g=1 adds 2)
  const int ldsb0 = (w * 64) * 8;     // wave-uniform LDS base (ushort idx)
  const int ldsb1 = (256 + w * 64) * 8;

  f32x4 acc[4][4] = {};
  const int fr = lane & 15;
  const int kc = lane >> 4;           // 0..3

  for (int k0 = 0; k0 < 512; k0 += 32) {
    const size_t ga = (size_t)(m0 + srow) * 512 + k0 + skc * 8;
    const size_t gb = (size_t)(n0 + srow) * 512 + k0 + skc * 8;
    gload16(Ahi + ga,      &As_hi[ldsb0]);
    gload16(Ahi + ga + 16, &As_hi[ldsb1]);
    gload16(Alo + ga,      &As_lo[ldsb0]);
    gload16(Alo + ga + 16, &As_lo[ldsb1]);
    gload16(Bhi + gb,      &Bs_hi[ldsb0]);
    gload16(Bhi + gb + 16, &Bs_hi[ldsb1]);
    gload16(Blo + gb,      &Bs_lo[ldsb0]);
    gload16(Blo + gb + 16, &Bs_lo[ldsb1]);
    __syncthreads();
    bf16x8 ah[4], al[4], bh[4], bl[4];
    #pragma unroll
    for (int mi = 0; mi < 4; ++mi) {
      const int ra = (kc * 128 + wr * 64 + mi * 16 + fr) * 8;
      ah[mi] = *reinterpret_cast<const bf16x8*>(&As_hi[ra]);
      al[mi] = *reinterpret_cast<const bf16x8*>(&As_lo[ra]);
    }
    #pragma unroll
    for (int ni = 0; ni < 4; ++ni) {
      const int rb = (kc * 128 + wc * 64 + ni * 16 + fr) * 8;
      bh[ni] = *reinterpret_cast<const bf16x8*>(&Bs_hi[rb]);
      bl[ni] = *reinterpret_cast<const bf16x8*>(&Bs_lo[rb]);
    }
    #pragma unroll
    for (int mi = 0; mi < 4; ++mi)
      #pragma unroll
      for (int ni = 0; ni < 4; ++ni) {
        acc[mi][ni] = __builtin_amdgcn_mfma_f32_16x16x32_bf16(ah[mi], bh[ni], acc[mi][ni], 0, 0, 0);
        acc[mi][ni] = __builtin_amdgcn_mfma_f32_16x16x32_bf16(ah[mi], bl[ni], acc[mi][ni], 0, 0, 0);
        acc[mi][ni] = __builtin_amdgcn_mfma_f32_16x16x32_bf16(al[mi], bh[ni], acc[mi][ni], 0, 0, 0);
      }
    __syncthreads();
  }

  float lsum = 0.f, lsq = 0.f, cs0 = 0.f, cs1 = 0.f;
  const int d = ct * 2 + wc;
  #pragma unroll
  for (int mi = 0; mi < 4; ++mi) {
    const int rbase = m0 + wr * 64 + mi * 16 + ((lane >> 4) << 2);
    #pragma unroll
    for (int ni = 0; ni < 4; ++ni) {
      #pragma unroll
      for (int r = 0; r < 4; ++r) {
        float v = acc[mi][ni][r];
        if (ni < 2) {
          float t = tanhf(v);
          Tb[((size_t)d * 512 + rbase + r) * 32 + ni * 16 + fr] = bf16rn(t);
          lsum += t; lsq += t * t;
        } else {
          float e = expf(v);
          if (ni == 2) cs0 += e; else cs1 += e;
        }
      }
    }
  }
  #pragma unroll
  for (int m = 1; m < 64; m <<= 1) { lsum += __shfl_xor(lsum, m); lsq += __shfl_xor(lsq, m); }
  cs0 += __shfl_xor(cs0, 16); cs0 += __shfl_xor(cs0, 32);
  cs1 += __shfl_xor(cs1, 16); cs1 += __shfl_xor(cs1, 32);
  if (lane == 0) { rsum[w] = lsum; rsq[w] = lsq; }
  if (lane < 16) { rcol[w][lane] = cs0; rcol[w][16 + lane] = cs1; }
  __syncthreads();
  if (tid < 64) {
    const int wc2 = tid >> 5, p = tid & 31;
    float* pb = partial + (((size_t)b * 4 + tm) * 8 + ct * 2 + wc2) * 34;
    pb[2 + p] = rcol[wc2][p] + rcol[wc2 + 2][p];
    if (p == 0) {
      pb[0] = rsum[wc2] + rsum[wc2 + 2];
      pb[1] = rsq[wc2] + rsq[wc2 + 2];
    }
  }
}

// ---------------- K3: fold the 4 row-tile partials -> per-(b,d) stats ----------------
__global__ void reduce_stats_kernel(const float* __restrict__ pJ, const float* __restrict__ pI,
                                    float* __restrict__ stats) {
  const int bd = blockIdx.x;
  const int b = bd >> 3, d = bd & 7;
  const int t = threadIdx.x;   // 128 threads
  __shared__ float tmp[2][34];
  if (t < 34) {
    float v = 0.f;
    for (int tm = 0; tm < 4; ++tm) v += pJ[(((size_t)b * 4 + tm) * 8 + d) * 34 + t];
    tmp[0][t] = v;
  } else if (t >= 64 && t < 98) {
    const int u = t - 64;
    float v = 0.f;
    for (int tm = 0; tm < 4; ++tm) v += pI[(((size_t)b * 4 + tm) * 8 + d) * 34 + u];
    tmp[1][u] = v;
  }
  __syncthreads();
  if (t < 2) {
    const float* tp = tmp[t];
    float* st = stats + (size_t)bd * 68;
    const float N = 16384.f;
    float mean = tp[0] / N;
    float var = (tp[1] - tp[0] * tp[0] / N) / (N - 1.f);
    float rstd = 1.f / (sqrtf(fmaxf(var, 0.f)) + EPSF);
    st[t * 2 + 0] = mean;
    st[t * 2 + 1] = rstd;
    float tot = 0.f;
    for (int k = 0; k < 32; ++k) tot += tp[2 + k];
    float inv = 1.f / tot;
    for (int k = 0; k < 32; ++k) st[4 + t * 32 + k] = tp[2 + k] * inv;
  }
}

// ---------------- K4: per-(b,d) stage 3 ----------------
__global__ __launch_bounds__(256) void stage3_kernel(
    const ushort* __restrict__ Txj, const ushort* __restrict__ Txi,
    const float* __restrict__ p_xj, const float* __restrict__ p_xi,
    const float* __restrict__ rel_pj, const float* __restrict__ rel_pi,
    const float* __restrict__ stats, const float* __restrict__ bstat,
    const float* __restrict__ gamma_p, const float* __restrict__ beta_p,
    float* __restrict__ xball) {
  const int bd = blockIdx.x;
  const int b = bd >> 3, d = bd & 7;
  const int tid = threadIdx.x;
  const int row = tid >> 3;       // 0..31
  const int c4 = (tid & 7) * 4;   // col base
  __shared__ float Ts[64][32];
  __shared__ float Ws[64][32];
  __shared__ float Vj[32][33];
  __shared__ float U[32][33];
  __shared__ float R[32][32];
  __shared__ float cred[32][33];
  __shared__ float red[256];
  __shared__ float red2[256];
  __shared__ float colW[32];
  __shared__ float fj[32], fi[32];
  __shared__ float sred[2];
  const float* st = stats + (size_t)bd * 68;
  const float meanJ = st[0], rstdJ = st[1], meanI = st[2], rstdI = st[3];

  // ===================== path J =====================
  {
    const int q = tid & 31, g = tid >> 5;
    float s = 0.f;
    const float* wp = p_xj + (size_t)d * 512 * 32;
    for (int i = g * 64; i < g * 64 + 64; ++i) s += wp[(size_t)i * 32 + q];
    red[tid] = s;
    __syncthreads();
    if (g == 0) {
      float v = 0.f;
      for (int gg = 0; gg < 8; ++gg) v += red[gg * 32 + q];
      colW[q] = v;
    }
    __syncthreads();
  }
  float acc[4] = {0.f, 0.f, 0.f, 0.f};
  {
    const ushort* Tb = Txj + (size_t)bd * 16384;
    const float* wp = p_xj + (size_t)d * 512 * 32;
    for (int i0 = 0; i0 < 512; i0 += 64) {
      {
        const int ii = tid >> 2, p8 = (tid & 3) * 8;
        u16x8 tv8 = *reinterpret_cast<const u16x8*>(&Tb[(size_t)(i0 + ii) * 32 + p8]);
        #pragma unroll
        for (int e = 0; e < 8; ++e) Ts[ii][p8 + e] = bf2f((ushort)tv8[e]);
      }
      #pragma unroll
      for (int l = 0; l < 2; ++l) {
        const int e = tid + l * 256;
        const int ii = e >> 3, p4 = (e & 7) * 4;
        *reinterpret_cast<float4*>(&Ws[ii][p4]) = *reinterpret_cast<const float4*>(&wp[(size_t)(i0 + ii) * 32 + p4]);
      }
      __syncthreads();
      #pragma unroll 8
      for (int ii = 0; ii < 64; ++ii) {
        const float tv = Ts[ii][row];
        const float4 wv = *reinterpret_cast<const float4*>(&Ws[ii][c4]);
        acc[0] = fmaf(tv, wv.x, acc[0]);
        acc[1] = fmaf(tv, wv.y, acc[1]);
        acc[2] = fmaf(tv, wv.z, acc[2]);
        acc[3] = fmaf(tv, wv.w, acc[3]);
      }
      __syncthreads();
    }
  }
  {
    float tv[4]; float ls = 0.f, lq = 0.f;
    #pragma unroll
    for (int e = 0; e < 4; ++e) {
      float v = (acc[e] - meanJ * colW[c4 + e]) * rstdJ;
      float t = tanhf(v);
      tv[e] = t; ls += t; lq += t * t;
    }
    red[tid] = ls; red2[tid] = lq;
    __syncthreads();
    for (int off = 128; off > 0; off >>= 1) {
      if (tid < off) { red[tid] += red[tid + off]; red2[tid] += red2[tid + off]; }
      __syncthreads();
    }
    if (tid == 0) {
      float s = red[0], ss = red2[0];
      float m = s / 1024.f;
      float var = (ss - s * s / 1024.f) / 1023.f;
      sred[0] = m; sred[1] = 1.f / (sqrtf(fmaxf(var, 0.f)) + EPSF);
    }
    __syncthreads();
    const float m2 = sred[0], r2 = sred[1];
    #pragma unroll
    for (int e = 0; e < 4; ++e) Vj[row][c4 + e] = (tv[e] - m2) * r2;
    __syncthreads();
  }
  {
    for (int l = tid; l < 1024; l += 256) (&R[0][0])[l] = rel_pj[(size_t)d * 1024 + l];
    __syncthreads();
    float racc[4] = {0.f, 0.f, 0.f, 0.f};
    #pragma unroll
    for (int c = 0; c < 32; ++c) {
      const float v = Vj[row][c];
      racc[0] = fmaf(v, R[c][c4 + 0], racc[0]);
      racc[1] = fmaf(v, R[c][c4 + 1], racc[1]);
      racc[2] = fmaf(v, R[c][c4 + 2], racc[2]);
      racc[3] = fmaf(v, R[c][c4 + 3], racc[3]);
    }
    #pragma unroll
    for (int e = 0; e < 4; ++e) cred[row][c4 + e] = expf(racc[e]);
    __syncthreads();
    if (tid < 32) {
      float s = 0.f;
      for (int p = 0; p < 32; ++p) s += cred[p][tid];
      red[tid] = s;
    }
    __syncthreads();
    if (tid == 0) {
      float tot = 0.f;
      for (int k = 0; k < 32; ++k) tot += red[k];
      sred[0] = tot;
    }
    __syncthreads();
    if (tid < 32) {
      float prel = red[tid] / sred[0];
      fj[tid] = sqrtf(st[4 + tid] / prel);
    }
    __syncthreads();
  }

  // ===================== path I =====================
  {
    const int q = tid & 31, g = tid >> 5;
    float s = 0.f;
    const float* wp = p_xi + (size_t)d * 512 * 32;
    for (int i = g * 64; i < g * 64 + 64; ++i) s += wp[(size_t)i * 32 + q];
    __syncthreads();
    red[tid] = s;
    __syncthreads();
    if (g == 0) {
      float v = 0.f;
      for (int gg = 0; gg < 8; ++gg) v += red[gg * 32 + q];
      colW[q] = v;
    }
    __syncthreads();
  }
  float acc2[4] = {0.f, 0.f, 0.f, 0.f};
  {
    const ushort* Tb = Txi + (size_t)bd * 16384;
    const float* wp = p_xi + (size_t)d * 512 * 32;
    for (int i0 = 0; i0 < 512; i0 += 64) {
      {
        const int ii = tid >> 2, p8 = (tid & 3) * 8;
        u16x8 tv8 = *reinterpret_cast<const u16x8*>(&Tb[(size_t)(i0 + ii) * 32 + p8]);
        #pragma unroll
        for (int e = 0; e < 8; ++e) Ts[ii][p8 + e] = bf2f((ushort)tv8[e]);
      }
      #pragma unroll
      for (int l = 0; l < 2; ++l) {
        const int e = tid + l * 256;
        const int ii = e >> 3, p4 = (e & 7) * 4;
        *reinterpret_cast<float4*>(&Ws[ii][p4]) = *reinterpret_cast<const float4*>(&wp[(size_t)(i0 + ii) * 32 + p4]);
      }
      __syncthreads();
      #pragma unroll 8
      for (int ii = 0; ii < 64; ++ii) {
        const float wvs = Ws[ii][row];
        const float4 tv = *reinterpret_cast<const float4*>(&Ts[ii][c4]);
        acc2[0] = fmaf(wvs, tv.x, acc2[0]);
        acc2[1] = fmaf(wvs, tv.y, acc2[1]);
        acc2[2] = fmaf(wvs, tv.z, acc2[2]);
        acc2[3] = fmaf(wvs, tv.w, acc2[3]);
      }
      __syncthreads();
    }
  }
  {
    float tv[4]; float ls = 0.f, lq = 0.f;
    #pragma unroll
    for (int e = 0; e < 4; ++e) {
      float v = (acc2[e] - meanI * colW[row]) * rstdI;
      float t = tanhf(v);
      tv[e] = t; ls += t; lq += t * t;
    }
    red[tid] = ls; red2[tid] = lq;
    __syncthreads();
    for (int off = 128; off > 0; off >>= 1) {
      if (tid < off) { red[tid] += red[tid + off]; red2[tid] += red2[tid + off]; }
      __syncthreads();
    }
    if (tid == 0) {
      float s = red[0], ss = red2[0];
      float m = s / 1024.f;
      float var = (ss - s * s / 1024.f) / 1023.f;
      sred[0] = m; sred[1] = 1.f / (sqrtf(fmaxf(var, 0.f)) + EPSF);
    }
    __syncthreads();
    const float m2 = sred[0], r2 = sred[1];
    #pragma unroll
    for (int e = 0; e < 4; ++e) U[row][c4 + e] = (tv[e] - m2) * r2;
    __syncthreads();
  }
  {
    for (int l = tid; l < 1024; l += 256) (&R[0][0])[l] = rel_pi[(size_t)d * 1024 + l];
    __syncthreads();
    float racc[4] = {0.f, 0.f, 0.f, 0.f};
    #pragma unroll
    for (int c = 0; c < 32; ++c) {
      const float v = U[row][c];
      racc[0] = fmaf(v, R[c][c4 + 0], racc[0]);
      racc[1] = fmaf(v, R[c][c4 + 1], racc[1]);
      racc[2] = fmaf(v, R[c][c4 + 2], racc[2]);
      racc[3] = fmaf(v, R[c][c4 + 3], racc[3]);
    }
    #pragma unroll
    for (int e = 0; e < 4; ++e) cred[row][c4 + e] = expf(racc[e]);
    __syncthreads();
    if (tid < 32) {
      float s = 0.f;
      for (int p = 0; p < 32; ++p) s += cred[p][tid];
      red[tid] = s;
    }
    __syncthreads();
    if (tid == 0) {
      float tot = 0.f;
      for (int k = 0; k < 32; ++k) tot += red[k];
      sred[0] = tot;
    }
    __syncthreads();
    if (tid < 32) {
      float prel = red[tid] / sred[0];
      fi[tid] = sqrtf(st[36 + tid] / prel);
    }
    __syncthreads();
  }

  // ===================== combine =====================
  {
    float xv[4]; float ls = 0.f, lq = 0.f;
    #pragma unroll
    for (int e = 0; e < 4; ++e) {
      const int q = c4 + e;
      float v = tanhf(Vj[row][q] * fj[row] * U[q][row] * fi[q]);
      xv[e] = v; ls += v; lq += v * v;
    }
    red[tid] = ls; red2[tid] = lq;
    __syncthreads();
    for (int off = 128; off > 0; off >>= 1) {
      if (tid < off) { red[tid] += red[tid + off]; red2[tid] += red2[tid + off]; }
      __syncthreads();
    }
    if (tid == 0) {
      float s = red[0], ss = red2[0];
      float m = s / 1024.f;
      float var = (ss - s * s / 1024.f) / 1023.f;
      sred[0] = m; sred[1] = 1.f / (sqrtf(fmaxf(var, 0.f)) + EPSF);
    }
    __syncthreads();
    const float m3 = sred[0], r3 = sred[1];
    const float xs = bstat[b * 2 + 1], xm = bstat[b * 2 + 0];
    const float g = gamma_p[d], be = beta_p[d];
    #pragma unroll
    for (int e = 0; e < 4; ++e) {
      float v = (xv[e] - m3) * r3 * xs + xm;
      v = v * g + be;
      xball[(size_t)bd * 1024 + row * 32 + c4 + e] = v;
    }
  }
}

// ---------------- K5: sum over d / D ----------------
__global__ void final_kernel(const float* __restrict__ xball, float* __restrict__ out) {
  const int b = blockIdx.x;
  for (int e = threadIdx.x; e < 1024; e += 256) {
    float s = 0.f;
    #pragma unroll
    for (int d = 0; d < 8; ++d) s += xball[((size_t)(b * 8 + d)) * 1024 + e];
    out[(size_t)b * 1024 + e] = s * 0.125f;
  }
}

extern "C" void kernel_launch(void* const* d_in, const int* in_sizes, int n_in,
                              void* d_out, int out_size, void* d_ws, size_t ws_size,
                              hipStream_t stream) {
  const float* x        = (const float*)d_in[0];
  const float* o_xj     = (const float*)d_in[1];
  const float* o_xi     = (const float*)d_in[2];
  const float* p_xj     = (const float*)d_in[3];
  const float* p_xi     = (const float*)d_in[4];
  const float* rel_o_xj = (const float*)d_in[5];
  const float* rel_o_xi = (const float*)d_in[6];
  const float* rel_p_xj = (const float*)d_in[7];
  const float* rel_p_xi = (const float*)d_in[8];
  const float* gamma_p  = (const float*)d_in[9];
  const float* beta_p   = (const float*)d_in[10];
  float* out = (float*)d_out;

  char* base = (char*)d_ws;
  ushort* xhi  = (ushort*)base; base += (size_t)33554432;
  ushort* xlo  = (ushort*)base; base += (size_t)33554432;
  ushort* xthi = (ushort*)base; base += (size_t)33554432;
  ushort* xtlo = (ushort*)base; base += (size_t)33554432;
  ushort* wjhi = (ushort*)base; base += 524288;
  ushort* wjlo = (ushort*)base; base += 524288;
  ushort* wihi = (ushort*)base; base += 524288;
  ushort* wilo = (ushort*)base; base += 524288;
  ushort* Txj  = (ushort*)base; base += (size_t)16777216;
  ushort* Txi  = (ushort*)base; base += (size_t)16777216;
  float* pJ    = (float*)base;  base += 278528;
  float* pI    = (float*)base;  base += 278528;
  float* bpart = (float*)base;  base += 32768;
  float* bstat = (float*)base;  base += 512;
  float* stats = (float*)base;  base += 139264;
  float* xball = (float*)base;  base += 2097152;

  hipLaunchKernelGGL(pack_w, dim3(512), dim3(256), 0, stream,
                     o_xj, o_xi, rel_o_xj, rel_o_xi, wjhi, wjlo, wihi, wilo);
  hipLaunchKernelGGL(convx, dim3(8, 8, 64), dim3(256), 0, stream, x, xhi, xlo, xthi, xtlo, bpart);
  hipLaunchKernelGGL(bstats_f, dim3(1), dim3(64), 0, stream, bpart, bstat);
  hipLaunchKernelGGL(mfma_gemm, dim3(2048), dim3(256), 0, stream,
                     xhi, xlo, xthi, xtlo, wjhi, wjlo, wihi, wilo, Txj, Txi, pJ, pI);
  hipLaunchKernelGGL(reduce_stats_kernel, dim3(512), dim3(128), 0, stream, pJ, pI, stats);
  hipLaunchKernelGGL(stage3_kernel, dim3(512), dim3(256), 0, stream,
                     Txj, Txi, p_xj, p_xi, rel_p_xj, rel_p_xi, stats, bstat, gamma_p, beta_p, xball);
  hipLaunchKernelGGL(final_kernel, dim3(64), dim3(256), 0, stream, xball, out);
}

// Round 4
// 204.120 us; speedup vs baseline: 2.9277x; 1.2260x over previous
//
#include <hip/hip_runtime.h>
#include <math.h>

static constexpr float EPSF = 1e-5f;

typedef short bf16x8 __attribute__((ext_vector_type(8)));
typedef float f32x4 __attribute__((ext_vector_type(4)));
typedef ushort u16x8 __attribute__((ext_vector_type(8)));

__device__ inline ushort bf16rn(float f) {
  unsigned u = __float_as_uint(f);
  unsigned r = (u + 0x7FFFu + ((u >> 16) & 1u)) >> 16;
  return (ushort)r;
}
__device__ inline float bf2f(ushort u) { return __uint_as_float(((unsigned)u) << 16); }
__device__ inline void split2(float f, ushort& hi, ushort& lo) {
  ushort h = bf16rn(f);
  float hf = bf2f(h);
  hi = h;
  lo = bf16rn(f - hf);
}

__device__ inline void gload16(const ushort* g, ushort* l) {
  __builtin_amdgcn_global_load_lds((const __attribute__((address_space(1))) void*)g,
                                   (__attribute__((address_space(3))) void*)l, 16, 0, 0);
}

// Tiled layout (ushort index), identical for A-operands and W-operands:
//   addr(row, k) = (row>>7)*65536 + (k>>5)*4096 + ((k>>3)&3)*1024 + (row&127)*8 + (k&7)
// i.e. [rowtile][kstep][kc][row128][8] — each K-step chunk (8KB) is contiguous,
// and linear global_load_lds reproduces the conflict-free [kc][row][8] LDS image.
__device__ inline size_t tiled_addr(int row, int k) {
  return (size_t)(row >> 7) * 65536 + (size_t)(k >> 5) * 4096 +
         (size_t)((k >> 3) & 3) * 1024 + (size_t)(row & 127) * 8 + (k & 7);
}

// ---------------- K0a: pack W (transposed, hi/lo split, tiled): c = d*64+s*32+p ----------------
__global__ void pack_w(const float* __restrict__ o_xj, const float* __restrict__ o_xi,
                       const float* __restrict__ rel_o_xj, const float* __restrict__ rel_o_xi,
                       ushort* __restrict__ wjhi, ushort* __restrict__ wjlo,
                       ushort* __restrict__ wihi, ushort* __restrict__ wilo) {
  int u = blockIdx.x * 256 + threadIdx.x;   // 2 paths * 512 c * 64 kgroups = 65536
  int path = u >> 15;
  int v = u & 32767;
  int c = v >> 6;
  int k0 = (v & 63) * 8;
  int d = c >> 6, s = (c >> 5) & 1, p = c & 31;
  const float* src = path ? (s ? rel_o_xi : o_xi) : (s ? rel_o_xj : o_xj);
  u16x8 h8, l8;
  #pragma unroll
  for (int e = 0; e < 8; ++e) {
    ushort h, l;
    split2(src[((size_t)d * 512 + k0 + e) * 32 + p], h, l);
    h8[e] = h; l8[e] = l;
  }
  size_t a = tiled_addr(c, k0);
  ushort* whi = path ? wihi : wjhi;
  ushort* wlo = path ? wilo : wjlo;
  *reinterpret_cast<u16x8*>(&whi[a]) = h8;
  *reinterpret_cast<u16x8*>(&wlo[a]) = l8;
}

// ---------------- K0b: convert x -> tiled xhi/xlo and transposed xthi/xtlo; fused batch stats ----------------
__global__ __launch_bounds__(256) void convx(const float* __restrict__ x,
                                             ushort* __restrict__ xhi, ushort* __restrict__ xlo,
                                             ushort* __restrict__ xthi, ushort* __restrict__ xtlo,
                                             float* __restrict__ bpart) {
  __shared__ float tile[64][65];
  __shared__ float rs[256], rs2[256];
  const int ti = blockIdx.x, tj = blockIdx.y, b = blockIdx.z;
  const int i0 = ti * 64, j0 = tj * 64;
  const float* xb = x + (size_t)b * 262144;
  const size_t obase = (size_t)b * 262144;
  const int tid = threadIdx.x;
  const int tr = tid >> 4;
  const int tc = (tid & 15) * 4;
  float s = 0.f, s2 = 0.f;
  #pragma unroll
  for (int r = 0; r < 4; ++r) {
    const int row = r * 16 + tr;
    float4 v = *reinterpret_cast<const float4*>(&xb[(size_t)(i0 + row) * 512 + j0 + tc]);
    tile[row][tc + 0] = v.x; tile[row][tc + 1] = v.y;
    tile[row][tc + 2] = v.z; tile[row][tc + 3] = v.w;
    s += v.x + v.y + v.z + v.w;
    s2 += v.x * v.x + v.y * v.y + v.z * v.z + v.w * v.w;
  }
  __syncthreads();
  // thread -> (kgroup, row-pair): half-wave writes are 1KB-contiguous in tiled layout
  const int kg = tid >> 5;   // 0..7
  const int rp = tid & 31;   // row pair
  #pragma unroll
  for (int rr = 0; rr < 2; ++rr) {
    const int li = rp * 2 + rr;
    u16x8 h8, l8;
    #pragma unroll
    for (int e = 0; e < 8; ++e) {
      ushort h, l;
      split2(tile[li][kg * 8 + e], h, l);
      h8[e] = h; l8[e] = l;
    }
    size_t a = obase + tiled_addr(i0 + li, j0 + kg * 8);
    *reinterpret_cast<u16x8*>(&xhi[a]) = h8;
    *reinterpret_cast<u16x8*>(&xlo[a]) = l8;
  }
  #pragma unroll
  for (int rr = 0; rr < 2; ++rr) {
    const int lj = rp * 2 + rr;
    u16x8 h8, l8;
    #pragma unroll
    for (int e = 0; e < 8; ++e) {
      ushort h, l;
      split2(tile[kg * 8 + e][lj], h, l);
      h8[e] = h; l8[e] = l;
    }
    size_t a = obase + tiled_addr(j0 + lj, i0 + kg * 8);
    *reinterpret_cast<u16x8*>(&xthi[a]) = h8;
    *reinterpret_cast<u16x8*>(&xtlo[a]) = l8;
  }
  rs[tid] = s; rs2[tid] = s2;
  __syncthreads();
  for (int off = 128; off > 0; off >>= 1) {
    if (tid < off) { rs[tid] += rs[tid + off]; rs2[tid] += rs2[tid + off]; }
    __syncthreads();
  }
  if (tid == 0) {
    float* pb = bpart + ((size_t)b * 64 + tj * 8 + ti) * 2;
    pb[0] = rs[0]; pb[1] = rs2[0];
  }
}

__global__ void bstats_f(const float* __restrict__ bpart, float* __restrict__ bstat) {
  const int b = threadIdx.x;  // 64 threads
  if (b >= 64) return;
  double s = 0.0, s2 = 0.0;
  for (int q = 0; q < 64; ++q) {
    s += (double)bpart[((size_t)b * 64 + q) * 2];
    s2 += (double)bpart[((size_t)b * 64 + q) * 2 + 1];
  }
  const double N = 262144.0;
  double mean = s / N;
  double var = (s2 - s * s / N) / (N - 1.0);
  bstat[b * 2 + 0] = (float)(mean * 256.0);
  bstat[b * 2 + 1] = (float)(sqrt(var < 0.0 ? 0.0 : var) * 256.0);
}

// ---------------- K2: MFMA split-bf16 GEMM + fused epilogue ----------------
// A,B read from the tiled layout: each K-step chunk is 8KB contiguous -> each
// global_load_lds is a fully-coalesced 1KB wave read; LDS image = [kc][row][8].
__global__ __launch_bounds__(256) void mfma_gemm(
    const ushort* __restrict__ xhi, const ushort* __restrict__ xlo,
    const ushort* __restrict__ xthi, const ushort* __restrict__ xtlo,
    const ushort* __restrict__ wjhi, const ushort* __restrict__ wjlo,
    const ushort* __restrict__ wihi, const ushort* __restrict__ wilo,
    ushort* __restrict__ Txj, ushort* __restrict__ Txi,
    float* __restrict__ pJ, float* __restrict__ pI) {
  const int id = blockIdx.x;
  const int wid = (id & 7) * 256 + (id >> 3);   // XCD-aware swizzle (2048 = 8*256)
  const int ct = wid & 3, tm = (wid >> 2) & 3, bz = wid >> 4;
  const int b = bz >> 1, path = bz & 1;
  const ushort* Ahi = (path ? xthi : xhi) + (size_t)b * 262144 + (size_t)tm * 65536;
  const ushort* Alo = (path ? xtlo : xlo) + (size_t)b * 262144 + (size_t)tm * 65536;
  const ushort* Bhi = (path ? wihi : wjhi) + (size_t)ct * 65536;
  const ushort* Blo = (path ? wilo : wjlo) + (size_t)ct * 65536;
  ushort* Tb = (path ? Txi : Txj) + (size_t)b * 131072;
  float* partial = path ? pI : pJ;

  __shared__ alignas(16) ushort As_hi[4096], As_lo[4096], Bs_hi[4096], Bs_lo[4096];
  __shared__ float rsum[4], rsq[4], rcol[4][32];

  const int tid = threadIdx.x;
  const int lane = tid & 63, w = tid >> 6;
  const int wr = w >> 1, wc = w & 1;
  const int m0 = tm * 128;

  const int L8 = (w * 64 + lane) * 8;      // per-lane linear offset (ushorts)
  const int ldsb0 = (w * 64) * 8;          // wave-uniform LDS bases
  const int ldsb1 = 2048 + (w * 64) * 8;

  f32x4 acc[4][4] = {};
  const int fr = lane & 15;
  const int kc = lane >> 4;                // 0..3

  for (int ks = 0; ks < 16; ++ks) {
    const ushort* Ah = Ahi + ks * 4096;
    const ushort* Al = Alo + ks * 4096;
    const ushort* Bh = Bhi + ks * 4096;
    const ushort* Bl = Blo + ks * 4096;
    gload16(Ah + L8,        &As_hi[ldsb0]);
    gload16(Ah + 2048 + L8, &As_hi[ldsb1]);
    gload16(Al + L8,        &As_lo[ldsb0]);
    gload16(Al + 2048 + L8, &As_lo[ldsb1]);
    gload16(Bh + L8,        &Bs_hi[ldsb0]);
    gload16(Bh + 2048 + L8, &Bs_hi[ldsb1]);
    gload16(Bl + L8,        &Bs_lo[ldsb0]);
    gload16(Bl + 2048 + L8, &Bs_lo[ldsb1]);
    __syncthreads();
    bf16x8 ah[4], al[4], bh[4], bl[4];
    #pragma unroll
    for (int mi = 0; mi < 4; ++mi) {
      const int ra = (kc * 128 + wr * 64 + mi * 16 + fr) * 8;
      ah[mi] = *reinterpret_cast<const bf16x8*>(&As_hi[ra]);
      al[mi] = *reinterpret_cast<const bf16x8*>(&As_lo[ra]);
    }
    #pragma unroll
    for (int ni = 0; ni < 4; ++ni) {
      const int rb = (kc * 128 + wc * 64 + ni * 16 + fr) * 8;
      bh[ni] = *reinterpret_cast<const bf16x8*>(&Bs_hi[rb]);
      bl[ni] = *reinterpret_cast<const bf16x8*>(&Bs_lo[rb]);
    }
    #pragma unroll
    for (int mi = 0; mi < 4; ++mi)
      #pragma unroll
      for (int ni = 0; ni < 4; ++ni) {
        acc[mi][ni] = __builtin_amdgcn_mfma_f32_16x16x32_bf16(ah[mi], bh[ni], acc[mi][ni], 0, 0, 0);
        acc[mi][ni] = __builtin_amdgcn_mfma_f32_16x16x32_bf16(ah[mi], bl[ni], acc[mi][ni], 0, 0, 0);
        acc[mi][ni] = __builtin_amdgcn_mfma_f32_16x16x32_bf16(al[mi], bh[ni], acc[mi][ni], 0, 0, 0);
      }
    __syncthreads();
  }

  float lsum = 0.f, lsq = 0.f, cs0 = 0.f, cs1 = 0.f;
  const int d = ct * 2 + wc;
  #pragma unroll
  for (int mi = 0; mi < 4; ++mi) {
    const int rbase = m0 + wr * 64 + mi * 16 + ((lane >> 4) << 2);
    #pragma unroll
    for (int ni = 0; ni < 4; ++ni) {
      #pragma unroll
      for (int r = 0; r < 4; ++r) {
        float v = acc[mi][ni][r];
        if (ni < 2) {
          float t = tanhf(v);
          Tb[((size_t)d * 512 + rbase + r) * 32 + ni * 16 + fr] = bf16rn(t);
          lsum += t; lsq += t * t;
        } else {
          float e = expf(v);
          if (ni == 2) cs0 += e; else cs1 += e;
        }
      }
    }
  }
  #pragma unroll
  for (int m = 1; m < 64; m <<= 1) { lsum += __shfl_xor(lsum, m); lsq += __shfl_xor(lsq, m); }
  cs0 += __shfl_xor(cs0, 16); cs0 += __shfl_xor(cs0, 32);
  cs1 += __shfl_xor(cs1, 16); cs1 += __shfl_xor(cs1, 32);
  if (lane == 0) { rsum[w] = lsum; rsq[w] = lsq; }
  if (lane < 16) { rcol[w][lane] = cs0; rcol[w][16 + lane] = cs1; }
  __syncthreads();
  if (tid < 64) {
    const int wc2 = tid >> 5, p = tid & 31;
    float* pb = partial + (((size_t)b * 4 + tm) * 8 + ct * 2 + wc2) * 34;
    pb[2 + p] = rcol[wc2][p] + rcol[wc2 + 2][p];
    if (p == 0) {
      pb[0] = rsum[wc2] + rsum[wc2 + 2];
      pb[1] = rsq[wc2] + rsq[wc2 + 2];
    }
  }
}

// ---------------- K3: fold the 4 row-tile partials -> per-(b,d) stats ----------------
__global__ void reduce_stats_kernel(const float* __restrict__ pJ, const float* __restrict__ pI,
                                    float* __restrict__ stats) {
  const int bd = blockIdx.x;
  const int b = bd >> 3, d = bd & 7;
  const int t = threadIdx.x;   // 128 threads
  __shared__ float tmp[2][34];
  if (t < 34) {
    float v = 0.f;
    for (int tm = 0; tm < 4; ++tm) v += pJ[(((size_t)b * 4 + tm) * 8 + d) * 34 + t];
    tmp[0][t] = v;
  } else if (t >= 64 && t < 98) {
    const int u = t - 64;
    float v = 0.f;
    for (int tm = 0; tm < 4; ++tm) v += pI[(((size_t)b * 4 + tm) * 8 + d) * 34 + u];
    tmp[1][u] = v;
  }
  __syncthreads();
  if (t < 2) {
    const float* tp = tmp[t];
    float* st = stats + (size_t)bd * 68;
    const float N = 16384.f;
    float mean = tp[0] / N;
    float var = (tp[1] - tp[0] * tp[0] / N) / (N - 1.f);
    float rstd = 1.f / (sqrtf(fmaxf(var, 0.f)) + EPSF);
    st[t * 2 + 0] = mean;
    st[t * 2 + 1] = rstd;
    float tot = 0.f;
    for (int k = 0; k < 32; ++k) tot += tp[2 + k];
    float inv = 1.f / tot;
    for (int k = 0; k < 32; ++k) st[4 + t * 32 + k] = tp[2 + k] * inv;
  }
}

// ---------------- K4: per-(b,d) stage 3 ----------------
__global__ __launch_bounds__(256) void stage3_kernel(
    const ushort* __restrict__ Txj, const ushort* __restrict__ Txi,
    const float* __restrict__ p_xj, const float* __restrict__ p_xi,
    const float* __restrict__ rel_pj, const float* __restrict__ rel_pi,
    const float* __restrict__ stats, const float* __restrict__ bstat,
    const float* __restrict__ gamma_p, const float* __restrict__ beta_p,
    float* __restrict__ xball) {
  const int bd = blockIdx.x;
  const int b = bd >> 3, d = bd & 7;
  const int tid = threadIdx.x;
  const int row = tid >> 3;       // 0..31
  const int c4 = (tid & 7) * 4;   // col base
  __shared__ float Ts[64][32];
  __shared__ float Ws[64][32];
  __shared__ float Vj[32][33];
  __shared__ float U[32][33];
  __shared__ float R[32][32];
  __shared__ float cred[32][33];
  __shared__ float red[256];
  __shared__ float red2[256];
  __shared__ float colW[32];
  __shared__ float fj[32], fi[32];
  __shared__ float sred[2];
  const float* st = stats + (size_t)bd * 68;
  const float meanJ = st[0], rstdJ = st[1], meanI = st[2], rstdI = st[3];

  // ===================== path J =====================
  {
    const int q = tid & 31, g = tid >> 5;
    float s = 0.f;
    const float* wp = p_xj + (size_t)d * 512 * 32;
    for (int i = g * 64; i < g * 64 + 64; ++i) s += wp[(size_t)i * 32 + q];
    red[tid] = s;
    __syncthreads();
    if (g == 0) {
      float v = 0.f;
      for (int gg = 0; gg < 8; ++gg) v += red[gg * 32 + q];
      colW[q] = v;
    }
    __syncthreads();
  }
  float acc[4] = {0.f, 0.f, 0.f, 0.f};
  {
    const ushort* Tb = Txj + (size_t)bd * 16384;
    const float* wp = p_xj + (size_t)d * 512 * 32;
    for (int i0 = 0; i0 < 512; i0 += 64) {
      {
        const int ii = tid >> 2, p8 = (tid & 3) * 8;
        u16x8 tv8 = *reinterpret_cast<const u16x8*>(&Tb[(size_t)(i0 + ii) * 32 + p8]);
        #pragma unroll
        for (int e = 0; e < 8; ++e) Ts[ii][p8 + e] = bf2f((ushort)tv8[e]);
      }
      #pragma unroll
      for (int l = 0; l < 2; ++l) {
        const int e = tid + l * 256;
        const int ii = e >> 3, p4 = (e & 7) * 4;
        *reinterpret_cast<float4*>(&Ws[ii][p4]) = *reinterpret_cast<const float4*>(&wp[(size_t)(i0 + ii) * 32 + p4]);
      }
      __syncthreads();
      #pragma unroll 8
      for (int ii = 0; ii < 64; ++ii) {
        const float tv = Ts[ii][row];
        const float4 wv = *reinterpret_cast<const float4*>(&Ws[ii][c4]);
        acc[0] = fmaf(tv, wv.x, acc[0]);
        acc[1] = fmaf(tv, wv.y, acc[1]);
        acc[2] = fmaf(tv, wv.z, acc[2]);
        acc[3] = fmaf(tv, wv.w, acc[3]);
      }
      __syncthreads();
    }
  }
  {
    float tv[4]; float ls = 0.f, lq = 0.f;
    #pragma unroll
    for (int e = 0; e < 4; ++e) {
      float v = (acc[e] - meanJ * colW[c4 + e]) * rstdJ;
      float t = tanhf(v);
      tv[e] = t; ls += t; lq += t * t;
    }
    red[tid] = ls; red2[tid] = lq;
    __syncthreads();
    for (int off = 128; off > 0; off >>= 1) {
      if (tid < off) { red[tid] += red[tid + off]; red2[tid] += red2[tid + off]; }
      __syncthreads();
    }
    if (tid == 0) {
      float s = red[0], ss = red2[0];
      float m = s / 1024.f;
      float var = (ss - s * s / 1024.f) / 1023.f;
      sred[0] = m; sred[1] = 1.f / (sqrtf(fmaxf(var, 0.f)) + EPSF);
    }
    __syncthreads();
    const float m2 = sred[0], r2 = sred[1];
    #pragma unroll
    for (int e = 0; e < 4; ++e) Vj[row][c4 + e] = (tv[e] - m2) * r2;
    __syncthreads();
  }
  {
    for (int l = tid; l < 1024; l += 256) (&R[0][0])[l] = rel_pj[(size_t)d * 1024 + l];
    __syncthreads();
    float racc[4] = {0.f, 0.f, 0.f, 0.f};
    #pragma unroll
    for (int c = 0; c < 32; ++c) {
      const float v = Vj[row][c];
      racc[0] = fmaf(v, R[c][c4 + 0], racc[0]);
      racc[1] = fmaf(v, R[c][c4 + 1], racc[1]);
      racc[2] = fmaf(v, R[c][c4 + 2], racc[2]);
      racc[3] = fmaf(v, R[c][c4 + 3], racc[3]);
    }
    #pragma unroll
    for (int e = 0; e < 4; ++e) cred[row][c4 + e] = expf(racc[e]);
    __syncthreads();
    if (tid < 32) {
      float s = 0.f;
      for (int p = 0; p < 32; ++p) s += cred[p][tid];
      red[tid] = s;
    }
    __syncthreads();
    if (tid == 0) {
      float tot = 0.f;
      for (int k = 0; k < 32; ++k) tot += red[k];
      sred[0] = tot;
    }
    __syncthreads();
    if (tid < 32) {
      float prel = red[tid] / sred[0];
      fj[tid] = sqrtf(st[4 + tid] / prel);
    }
    __syncthreads();
  }

  // ===================== path I =====================
  {
    const int q = tid & 31, g = tid >> 5;
    float s = 0.f;
    const float* wp = p_xi + (size_t)d * 512 * 32;
    for (int i = g * 64; i < g * 64 + 64; ++i) s += wp[(size_t)i * 32 + q];
    __syncthreads();
    red[tid] = s;
    __syncthreads();
    if (g == 0) {
      float v = 0.f;
      for (int gg = 0; gg < 8; ++gg) v += red[gg * 32 + q];
      colW[q] = v;
    }
    __syncthreads();
  }
  float acc2[4] = {0.f, 0.f, 0.f, 0.f};
  {
    const ushort* Tb = Txi + (size_t)bd * 16384;
    const float* wp = p_xi + (size_t)d * 512 * 32;
    for (int i0 = 0; i0 < 512; i0 += 64) {
      {
        const int ii = tid >> 2, p8 = (tid & 3) * 8;
        u16x8 tv8 = *reinterpret_cast<const u16x8*>(&Tb[(size_t)(i0 + ii) * 32 + p8]);
        #pragma unroll
        for (int e = 0; e < 8; ++e) Ts[ii][p8 + e] = bf2f((ushort)tv8[e]);
      }
      #pragma unroll
      for (int l = 0; l < 2; ++l) {
        const int e = tid + l * 256;
        const int ii = e >> 3, p4 = (e & 7) * 4;
        *reinterpret_cast<float4*>(&Ws[ii][p4]) = *reinterpret_cast<const float4*>(&wp[(size_t)(i0 + ii) * 32 + p4]);
      }
      __syncthreads();
      #pragma unroll 8
      for (int ii = 0; ii < 64; ++ii) {
        const float wvs = Ws[ii][row];
        const float4 tv = *reinterpret_cast<const float4*>(&Ts[ii][c4]);
        acc2[0] = fmaf(wvs, tv.x, acc2[0]);
        acc2[1] = fmaf(wvs, tv.y, acc2[1]);
        acc2[2] = fmaf(wvs, tv.z, acc2[2]);
        acc2[3] = fmaf(wvs, tv.w, acc2[3]);
      }
      __syncthreads();
    }
  }
  {
    float tv[4]; float ls = 0.f, lq = 0.f;
    #pragma unroll
    for (int e = 0; e < 4; ++e) {
      float v = (acc2[e] - meanI * colW[row]) * rstdI;
      float t = tanhf(v);
      tv[e] = t; ls += t; lq += t * t;
    }
    red[tid] = ls; red2[tid] = lq;
    __syncthreads();
    for (int off = 128; off > 0; off >>= 1) {
      if (tid < off) { red[tid] += red[tid + off]; red2[tid] += red2[tid + off]; }
      __syncthreads();
    }
    if (tid == 0) {
      float s = red[0], ss = red2[0];
      float m = s / 1024.f;
      float var = (ss - s * s / 1024.f) / 1023.f;
      sred[0] = m; sred[1] = 1.f / (sqrtf(fmaxf(var, 0.f)) + EPSF);
    }
    __syncthreads();
    const float m2 = sred[0], r2 = sred[1];
    #pragma unroll
    for (int e = 0; e < 4; ++e) U[row][c4 + e] = (tv[e] - m2) * r2;
    __syncthreads();
  }
  {
    for (int l = tid; l < 1024; l += 256) (&R[0][0])[l] = rel_pi[(size_t)d * 1024 + l];
    __syncthreads();
    float racc[4] = {0.f, 0.f, 0.f, 0.f};
    #pragma unroll
    for (int c = 0; c < 32; ++c) {
      const float v = U[row][c];
      racc[0] = fmaf(v, R[c][c4 + 0], racc[0]);
      racc[1] = fmaf(v, R[c][c4 + 1], racc[1]);
      racc[2] = fmaf(v, R[c][c4 + 2], racc[2]);
      racc[3] = fmaf(v, R[c][c4 + 3], racc[3]);
    }
    #pragma unroll
    for (int e = 0; e < 4; ++e) cred[row][c4 + e] = expf(racc[e]);
    __syncthreads();
    if (tid < 32) {
      float s = 0.f;
      for (int p = 0; p < 32; ++p) s += cred[p][tid];
      red[tid] = s;
    }
    __syncthreads();
    if (tid == 0) {
      float tot = 0.f;
      for (int k = 0; k < 32; ++k) tot += red[k];
      sred[0] = tot;
    }
    __syncthreads();
    if (tid < 32) {
      float prel = red[tid] / sred[0];
      fi[tid] = sqrtf(st[36 + tid] / prel);
    }
    __syncthreads();
  }

  // ===================== combine =====================
  {
    float xv[4]; float ls = 0.f, lq = 0.f;
    #pragma unroll
    for (int e = 0; e < 4; ++e) {
      const int q = c4 + e;
      float v = tanhf(Vj[row][q] * fj[row] * U[q][row] * fi[q]);
      xv[e] = v; ls += v; lq += v * v;
    }
    red[tid] = ls; red2[tid] = lq;
    __syncthreads();
    for (int off = 128; off > 0; off >>= 1) {
      if (tid < off) { red[tid] += red[tid + off]; red2[tid] += red2[tid + off]; }
      __syncthreads();
    }
    if (tid == 0) {
      float s = red[0], ss = red2[0];
      float m = s / 1024.f;
      float var = (ss - s * s / 1024.f) / 1023.f;
      sred[0] = m; sred[1] = 1.f / (sqrtf(fmaxf(var, 0.f)) + EPSF);
    }
    __syncthreads();
    const float m3 = sred[0], r3 = sred[1];
    const float xs = bstat[b * 2 + 1], xm = bstat[b * 2 + 0];
    const float g = gamma_p[d], be = beta_p[d];
    #pragma unroll
    for (int e = 0; e < 4; ++e) {
      float v = (xv[e] - m3) * r3 * xs + xm;
      v = v * g + be;
      xball[(size_t)bd * 1024 + row * 32 + c4 + e] = v;
    }
  }
}

// ---------------- K5: sum over d / D ----------------
__global__ void final_kernel(const float* __restrict__ xball, float* __restrict__ out) {
  const int b = blockIdx.x;
  for (int e = threadIdx.x; e < 1024; e += 256) {
    float s = 0.f;
    #pragma unroll
    for (int d = 0; d < 8; ++d) s += xball[((size_t)(b * 8 + d)) * 1024 + e];
    out[(size_t)b * 1024 + e] = s * 0.125f;
  }
}

extern "C" void kernel_launch(void* const* d_in, const int* in_sizes, int n_in,
                              void* d_out, int out_size, void* d_ws, size_t ws_size,
                              hipStream_t stream) {
  const float* x        = (const float*)d_in[0];
  const float* o_xj     = (const float*)d_in[1];
  const float* o_xi     = (const float*)d_in[2];
  const float* p_xj     = (const float*)d_in[3];
  const float* p_xi     = (const float*)d_in[4];
  const float* rel_o_xj = (const float*)d_in[5];
  const float* rel_o_xi = (const float*)d_in[6];
  const float* rel_p_xj = (const float*)d_in[7];
  const float* rel_p_xi = (const float*)d_in[8];
  const float* gamma_p  = (const float*)d_in[9];
  const float* beta_p   = (const float*)d_in[10];
  float* out = (float*)d_out;

  char* base = (char*)d_ws;
  ushort* xhi  = (ushort*)base; base += (size_t)33554432;
  ushort* xlo  = (ushort*)base; base += (size_t)33554432;
  ushort* xthi = (ushort*)base; base += (size_t)33554432;
  ushort* xtlo = (ushort*)base; base += (size_t)33554432;
  ushort* wjhi = (ushort*)base; base += 524288;
  ushort* wjlo = (ushort*)base; base += 524288;
  ushort* wihi = (ushort*)base; base += 524288;
  ushort* wilo = (ushort*)base; base += 524288;
  ushort* Txj  = (ushort*)base; base += (size_t)16777216;
  ushort* Txi  = (ushort*)base; base += (size_t)16777216;
  float* pJ    = (float*)base;  base += 278528;
  float* pI    = (float*)base;  base += 278528;
  float* bpart = (float*)base;  base += 32768;
  float* bstat = (float*)base;  base += 512;
  float* stats = (float*)base;  base += 139264;
  float* xball = (float*)base;  base += 2097152;

  hipLaunchKernelGGL(pack_w, dim3(256), dim3(256), 0, stream,
                     o_xj, o_xi, rel_o_xj, rel_o_xi, wjhi, wjlo, wihi, wilo);
  hipLaunchKernelGGL(convx, dim3(8, 8, 64), dim3(256), 0, stream, x, xhi, xlo, xthi, xtlo, bpart);
  hipLaunchKernelGGL(bstats_f, dim3(1), dim3(64), 0, stream, bpart, bstat);
  hipLaunchKernelGGL(mfma_gemm, dim3(2048), dim3(256), 0, stream,
                     xhi, xlo, xthi, xtlo, wjhi, wjlo, wihi, wilo, Txj, Txi, pJ, pI);
  hipLaunchKernelGGL(reduce_stats_kernel, dim3(512), dim3(128), 0, stream, pJ, pI, stats);
  hipLaunchKernelGGL(stage3_kernel, dim3(512), dim3(256), 0, stream,
                     Txj, Txi, p_xj, p_xi, rel_p_xj, rel_p_xi, stats, bstat, gamma_p, beta_p, xball);
  hipLaunchKernelGGL(final_kernel, dim3(64), dim3(256), 0, stream, xball, out);
}

// Round 5
// 151.759 us; speedup vs baseline: 3.9379x; 1.3450x over previous
//
#include <hip/hip_runtime.h>
#include <math.h>

static constexpr float EPSF = 1e-5f;

typedef short bf16x8 __attribute__((ext_vector_type(8)));
typedef float f32x4 __attribute__((ext_vector_type(4)));
typedef ushort u16x8 __attribute__((ext_vector_type(8)));

__device__ inline ushort bf16rn(float f) {
  unsigned u = __float_as_uint(f);
  unsigned r = (u + 0x7FFFu + ((u >> 16) & 1u)) >> 16;
  return (ushort)r;
}
__device__ inline float bf2f(ushort u) { return __uint_as_float(((unsigned)u) << 16); }
__device__ inline void split2(float f, ushort& hi, ushort& lo) {
  ushort h = bf16rn(f);
  float hf = bf2f(h);
  hi = h;
  lo = bf16rn(f - hf);
}
// tanh via hw exp+rcp: exact at saturation, ~1e-7 abs err
__device__ inline float fast_tanh(float x) {
  float e = __expf(2.f * x);
  return 1.f - 2.f * __builtin_amdgcn_rcpf(e + 1.f);
}

__device__ inline void gload16(const ushort* g, ushort* l) {
  __builtin_amdgcn_global_load_lds((const __attribute__((address_space(1))) void*)g,
                                   (__attribute__((address_space(3))) void*)l, 16, 0, 0);
}

// Tiled layout (ushort index): addr(row,k) = (row>>7)*65536 + (k>>5)*4096
//   + ((k>>3)&3)*1024 + (row&127)*8 + (k&7)
// [rowtile][kstep][kc][row128][8] — each K-step chunk (8KB) contiguous; linear
// global_load_lds reproduces the conflict-free [kc][row][8] LDS image.
__device__ inline size_t tiled_addr(int row, int k) {
  return (size_t)(row >> 7) * 65536 + (size_t)(k >> 5) * 4096 +
         (size_t)((k >> 3) & 3) * 1024 + (size_t)(row & 127) * 8 + (k & 7);
}

// ---------------- K0a: pack W (transposed, hi/lo split, tiled): c = d*64+s*32+p ----------------
__global__ void pack_w(const float* __restrict__ o_xj, const float* __restrict__ o_xi,
                       const float* __restrict__ rel_o_xj, const float* __restrict__ rel_o_xi,
                       ushort* __restrict__ wjhi, ushort* __restrict__ wjlo,
                       ushort* __restrict__ wihi, ushort* __restrict__ wilo) {
  int u = blockIdx.x * 256 + threadIdx.x;   // 2 paths * 512 c * 64 kgroups = 65536
  int path = u >> 15;
  int v = u & 32767;
  int c = v >> 6;
  int k0 = (v & 63) * 8;
  int d = c >> 6, s = (c >> 5) & 1, p = c & 31;
  const float* src = path ? (s ? rel_o_xi : o_xi) : (s ? rel_o_xj : o_xj);
  u16x8 h8, l8;
  #pragma unroll
  for (int e = 0; e < 8; ++e) {
    ushort h, l;
    split2(src[((size_t)d * 512 + k0 + e) * 32 + p], h, l);
    h8[e] = h; l8[e] = l;
  }
  size_t a = tiled_addr(c, k0);
  ushort* whi = path ? wihi : wjhi;
  ushort* wlo = path ? wilo : wjlo;
  *reinterpret_cast<u16x8*>(&whi[a]) = h8;
  *reinterpret_cast<u16x8*>(&wlo[a]) = l8;
}

// ---------------- K0b: x -> tiled bf16 xhi and transposed xthi; fused batch stats ----------------
__global__ __launch_bounds__(256) void convx(const float* __restrict__ x,
                                             ushort* __restrict__ xhi, ushort* __restrict__ xthi,
                                             float* __restrict__ bpart) {
  __shared__ float tile[64][65];
  __shared__ float rs[256], rs2[256];
  const int ti = blockIdx.x, tj = blockIdx.y, b = blockIdx.z;
  const int i0 = ti * 64, j0 = tj * 64;
  const float* xb = x + (size_t)b * 262144;
  const size_t obase = (size_t)b * 262144;
  const int tid = threadIdx.x;
  const int tr = tid >> 4;
  const int tc = (tid & 15) * 4;
  float s = 0.f, s2 = 0.f;
  #pragma unroll
  for (int r = 0; r < 4; ++r) {
    const int row = r * 16 + tr;
    float4 v = *reinterpret_cast<const float4*>(&xb[(size_t)(i0 + row) * 512 + j0 + tc]);
    tile[row][tc + 0] = v.x; tile[row][tc + 1] = v.y;
    tile[row][tc + 2] = v.z; tile[row][tc + 3] = v.w;
    s += v.x + v.y + v.z + v.w;
    s2 += v.x * v.x + v.y * v.y + v.z * v.z + v.w * v.w;
  }
  __syncthreads();
  // thread -> (kgroup, row): per-half-wave writes are 512B contiguous in tiled layout
  const int kg = tid >> 5;   // 0..7
  const int rp = tid & 31;
  #pragma unroll
  for (int rr = 0; rr < 2; ++rr) {
    const int li = rp + rr * 32;
    u16x8 h8;
    #pragma unroll
    for (int e = 0; e < 8; ++e) h8[e] = bf16rn(tile[li][kg * 8 + e]);
    *reinterpret_cast<u16x8*>(&xhi[obase + tiled_addr(i0 + li, j0 + kg * 8)]) = h8;
  }
  #pragma unroll
  for (int rr = 0; rr < 2; ++rr) {
    const int lj = rp + rr * 32;
    u16x8 h8;
    #pragma unroll
    for (int e = 0; e < 8; ++e) h8[e] = bf16rn(tile[kg * 8 + e][lj]);
    *reinterpret_cast<u16x8*>(&xthi[obase + tiled_addr(j0 + lj, i0 + kg * 8)]) = h8;
  }
  rs[tid] = s; rs2[tid] = s2;
  __syncthreads();
  for (int off = 128; off > 0; off >>= 1) {
    if (tid < off) { rs[tid] += rs[tid + off]; rs2[tid] += rs2[tid + off]; }
    __syncthreads();
  }
  if (tid == 0) {
    float* pb = bpart + ((size_t)b * 64 + tj * 8 + ti) * 2;
    pb[0] = rs[0]; pb[1] = rs2[0];
  }
}

__global__ void bstats_f(const float* __restrict__ bpart, float* __restrict__ bstat) {
  const int b = threadIdx.x;  // 64 threads
  if (b >= 64) return;
  double s = 0.0, s2 = 0.0;
  for (int q = 0; q < 64; ++q) {
    s += (double)bpart[((size_t)b * 64 + q) * 2];
    s2 += (double)bpart[((size_t)b * 64 + q) * 2 + 1];
  }
  const double N = 262144.0;
  double mean = s / N;
  double var = (s2 - s * s / N) / (N - 1.0);
  bstat[b * 2 + 0] = (float)(mean * 256.0);
  bstat[b * 2 + 1] = (float)(sqrt(var < 0.0 ? 0.0 : var) * 256.0);
}

// ---------------- K2: MFMA GEMM, A=bf16(x), B=split-bf16 weights ----------------
// D = a_hi*(b_hi + b_lo); dropped a_lo*b term (~0.1% rel, within absmax budget).
__global__ __launch_bounds__(256) void mfma_gemm(
    const ushort* __restrict__ xhi, const ushort* __restrict__ xthi,
    const ushort* __restrict__ wjhi, const ushort* __restrict__ wjlo,
    const ushort* __restrict__ wihi, const ushort* __restrict__ wilo,
    ushort* __restrict__ Txj, ushort* __restrict__ Txi,
    float* __restrict__ pJ, float* __restrict__ pI) {
  const int id = blockIdx.x;
  const int wid = (id & 7) * 256 + (id >> 3);   // XCD-aware swizzle (2048 = 8*256)
  const int ct = wid & 3, tm = (wid >> 2) & 3, bz = wid >> 4;
  const int b = bz >> 1, path = bz & 1;
  const ushort* Ahi = (path ? xthi : xhi) + (size_t)b * 262144 + (size_t)tm * 65536;
  const ushort* Bhi = (path ? wihi : wjhi) + (size_t)ct * 65536;
  const ushort* Blo = (path ? wilo : wjlo) + (size_t)ct * 65536;
  ushort* Tb = (path ? Txi : Txj) + (size_t)b * 131072;
  float* partial = path ? pI : pJ;

  __shared__ alignas(16) ushort As_hi[4096], Bs_hi[4096], Bs_lo[4096];
  __shared__ float rsum[4], rsq[4], rcol[4][32];

  const int tid = threadIdx.x;
  const int lane = tid & 63, w = tid >> 6;
  const int wr = w >> 1, wc = w & 1;
  const int m0 = tm * 128;

  const int L8 = (w * 64 + lane) * 8;      // per-lane linear offset (ushorts)
  const int ldsb0 = (w * 64) * 8;          // wave-uniform LDS bases
  const int ldsb1 = 2048 + (w * 64) * 8;

  f32x4 acc[4][4] = {};
  const int fr = lane & 15;
  const int kc = lane >> 4;                // 0..3

  for (int ks = 0; ks < 16; ++ks) {
    const ushort* Ah = Ahi + ks * 4096;
    const ushort* Bh = Bhi + ks * 4096;
    const ushort* Bl = Blo + ks * 4096;
    gload16(Ah + L8,        &As_hi[ldsb0]);
    gload16(Ah + 2048 + L8, &As_hi[ldsb1]);
    gload16(Bh + L8,        &Bs_hi[ldsb0]);
    gload16(Bh + 2048 + L8, &Bs_hi[ldsb1]);
    gload16(Bl + L8,        &Bs_lo[ldsb0]);
    gload16(Bl + 2048 + L8, &Bs_lo[ldsb1]);
    __syncthreads();
    bf16x8 ah[4], bh[4], bl[4];
    #pragma unroll
    for (int mi = 0; mi < 4; ++mi) {
      const int ra = (kc * 128 + wr * 64 + mi * 16 + fr) * 8;
      ah[mi] = *reinterpret_cast<const bf16x8*>(&As_hi[ra]);
    }
    #pragma unroll
    for (int ni = 0; ni < 4; ++ni) {
      const int rb = (kc * 128 + wc * 64 + ni * 16 + fr) * 8;
      bh[ni] = *reinterpret_cast<const bf16x8*>(&Bs_hi[rb]);
      bl[ni] = *reinterpret_cast<const bf16x8*>(&Bs_lo[rb]);
    }
    #pragma unroll
    for (int mi = 0; mi < 4; ++mi)
      #pragma unroll
      for (int ni = 0; ni < 4; ++ni) {
        acc[mi][ni] = __builtin_amdgcn_mfma_f32_16x16x32_bf16(ah[mi], bh[ni], acc[mi][ni], 0, 0, 0);
        acc[mi][ni] = __builtin_amdgcn_mfma_f32_16x16x32_bf16(ah[mi], bl[ni], acc[mi][ni], 0, 0, 0);
      }
    __syncthreads();
  }

  float lsum = 0.f, lsq = 0.f, cs0 = 0.f, cs1 = 0.f;
  const int d = ct * 2 + wc;
  #pragma unroll
  for (int mi = 0; mi < 4; ++mi) {
    const int rbase = m0 + wr * 64 + mi * 16 + ((lane >> 4) << 2);
    #pragma unroll
    for (int ni = 0; ni < 4; ++ni) {
      #pragma unroll
      for (int r = 0; r < 4; ++r) {
        float v = acc[mi][ni][r];
        if (ni < 2) {
          float t = fast_tanh(v);
          Tb[((size_t)d * 512 + rbase + r) * 32 + ni * 16 + fr] = bf16rn(t);
          lsum += t; lsq += t * t;
        } else {
          float e = __expf(v);
          if (ni == 2) cs0 += e; else cs1 += e;
        }
      }
    }
  }
  #pragma unroll
  for (int m = 1; m < 64; m <<= 1) { lsum += __shfl_xor(lsum, m); lsq += __shfl_xor(lsq, m); }
  cs0 += __shfl_xor(cs0, 16); cs0 += __shfl_xor(cs0, 32);
  cs1 += __shfl_xor(cs1, 16); cs1 += __shfl_xor(cs1, 32);
  if (lane == 0) { rsum[w] = lsum; rsq[w] = lsq; }
  if (lane < 16) { rcol[w][lane] = cs0; rcol[w][16 + lane] = cs1; }
  __syncthreads();
  if (tid < 64) {
    const int wc2 = tid >> 5, p = tid & 31;
    float* pb = partial + (((size_t)b * 4 + tm) * 8 + ct * 2 + wc2) * 34;
    pb[2 + p] = rcol[wc2][p] + rcol[wc2 + 2][p];
    if (p == 0) {
      pb[0] = rsum[wc2] + rsum[wc2 + 2];
      pb[1] = rsq[wc2] + rsq[wc2 + 2];
    }
  }
}

// ---------------- K3: fold the 4 row-tile partials -> per-(b,d) stats ----------------
__global__ void reduce_stats_kernel(const float* __restrict__ pJ, const float* __restrict__ pI,
                                    float* __restrict__ stats) {
  const int bd = blockIdx.x;
  const int b = bd >> 3, d = bd & 7;
  const int t = threadIdx.x;   // 128 threads
  __shared__ float tmp[2][34];
  if (t < 34) {
    float v = 0.f;
    for (int tm = 0; tm < 4; ++tm) v += pJ[(((size_t)b * 4 + tm) * 8 + d) * 34 + t];
    tmp[0][t] = v;
  } else if (t >= 64 && t < 98) {
    const int u = t - 64;
    float v = 0.f;
    for (int tm = 0; tm < 4; ++tm) v += pI[(((size_t)b * 4 + tm) * 8 + d) * 34 + u];
    tmp[1][u] = v;
  }
  __syncthreads();
  if (t < 2) {
    const float* tp = tmp[t];
    float* st = stats + (size_t)bd * 68;
    const float N = 16384.f;
    float mean = tp[0] / N;
    float var = (tp[1] - tp[0] * tp[0] / N) / (N - 1.f);
    float rstd = 1.f / (sqrtf(fmaxf(var, 0.f)) + EPSF);
    st[t * 2 + 0] = mean;
    st[t * 2 + 1] = rstd;
    float tot = 0.f;
    for (int k = 0; k < 32; ++k) tot += tp[2 + k];
    float inv = 1.f / tot;
    for (int k = 0; k < 32; ++k) st[4 + t * 32 + k] = tp[2 + k] * inv;
  }
}

// ---------------- K4: per-(b,d) stage 3 ----------------
__global__ __launch_bounds__(256) void stage3_kernel(
    const ushort* __restrict__ Txj, const ushort* __restrict__ Txi,
    const float* __restrict__ p_xj, const float* __restrict__ p_xi,
    const float* __restrict__ rel_pj, const float* __restrict__ rel_pi,
    const float* __restrict__ stats, const float* __restrict__ bstat,
    const float* __restrict__ gamma_p, const float* __restrict__ beta_p,
    float* __restrict__ xball) {
  const int bd = blockIdx.x;
  const int b = bd >> 3, d = bd & 7;
  const int tid = threadIdx.x;
  const int row = tid >> 3;       // 0..31
  const int c4 = (tid & 7) * 4;   // col base
  __shared__ float Ts[64][32];
  __shared__ float Ws[64][32];
  __shared__ float Vj[32][33];
  __shared__ float U[32][33];
  __shared__ float R[32][32];
  __shared__ float cred[32][33];
  __shared__ float red[256];
  __shared__ float red2[256];
  __shared__ float colW[32];
  __shared__ float fj[32], fi[32];
  __shared__ float sred[2];
  const float* st = stats + (size_t)bd * 68;
  const float meanJ = st[0], rstdJ = st[1], meanI = st[2], rstdI = st[3];

  // ===================== path J =====================
  {
    const int q = tid & 31, g = tid >> 5;
    float s = 0.f;
    const float* wp = p_xj + (size_t)d * 512 * 32;
    for (int i = g * 64; i < g * 64 + 64; ++i) s += wp[(size_t)i * 32 + q];
    red[tid] = s;
    __syncthreads();
    if (g == 0) {
      float v = 0.f;
      for (int gg = 0; gg < 8; ++gg) v += red[gg * 32 + q];
      colW[q] = v;
    }
    __syncthreads();
  }
  float acc[4] = {0.f, 0.f, 0.f, 0.f};
  {
    const ushort* Tb = Txj + (size_t)bd * 16384;
    const float* wp = p_xj + (size_t)d * 512 * 32;
    for (int i0 = 0; i0 < 512; i0 += 64) {
      {
        const int ii = tid >> 2, p8 = (tid & 3) * 8;
        u16x8 tv8 = *reinterpret_cast<const u16x8*>(&Tb[(size_t)(i0 + ii) * 32 + p8]);
        #pragma unroll
        for (int e = 0; e < 8; ++e) Ts[ii][p8 + e] = bf2f((ushort)tv8[e]);
      }
      #pragma unroll
      for (int l = 0; l < 2; ++l) {
        const int e = tid + l * 256;
        const int ii = e >> 3, p4 = (e & 7) * 4;
        *reinterpret_cast<float4*>(&Ws[ii][p4]) = *reinterpret_cast<const float4*>(&wp[(size_t)(i0 + ii) * 32 + p4]);
      }
      __syncthreads();
      #pragma unroll 8
      for (int ii = 0; ii < 64; ++ii) {
        const float tv = Ts[ii][row];
        const float4 wv = *reinterpret_cast<const float4*>(&Ws[ii][c4]);
        acc[0] = fmaf(tv, wv.x, acc[0]);
        acc[1] = fmaf(tv, wv.y, acc[1]);
        acc[2] = fmaf(tv, wv.z, acc[2]);
        acc[3] = fmaf(tv, wv.w, acc[3]);
      }
      __syncthreads();
    }
  }
  {
    float tv[4]; float ls = 0.f, lq = 0.f;
    #pragma unroll
    for (int e = 0; e < 4; ++e) {
      float v = (acc[e] - meanJ * colW[c4 + e]) * rstdJ;
      float t = fast_tanh(v);
      tv[e] = t; ls += t; lq += t * t;
    }
    red[tid] = ls; red2[tid] = lq;
    __syncthreads();
    for (int off = 128; off > 0; off >>= 1) {
      if (tid < off) { red[tid] += red[tid + off]; red2[tid] += red2[tid + off]; }
      __syncthreads();
    }
    if (tid == 0) {
      float s = red[0], ss = red2[0];
      float m = s / 1024.f;
      float var = (ss - s * s / 1024.f) / 1023.f;
      sred[0] = m; sred[1] = 1.f / (sqrtf(fmaxf(var, 0.f)) + EPSF);
    }
    __syncthreads();
    const float m2 = sred[0], r2 = sred[1];
    #pragma unroll
    for (int e = 0; e < 4; ++e) Vj[row][c4 + e] = (tv[e] - m2) * r2;
    __syncthreads();
  }
  {
    for (int l = tid; l < 1024; l += 256) (&R[0][0])[l] = rel_pj[(size_t)d * 1024 + l];
    __syncthreads();
    float racc[4] = {0.f, 0.f, 0.f, 0.f};
    #pragma unroll
    for (int c = 0; c < 32; ++c) {
      const float v = Vj[row][c];
      racc[0] = fmaf(v, R[c][c4 + 0], racc[0]);
      racc[1] = fmaf(v, R[c][c4 + 1], racc[1]);
      racc[2] = fmaf(v, R[c][c4 + 2], racc[2]);
      racc[3] = fmaf(v, R[c][c4 + 3], racc[3]);
    }
    #pragma unroll
    for (int e = 0; e < 4; ++e) cred[row][c4 + e] = __expf(racc[e]);
    __syncthreads();
    if (tid < 32) {
      float s = 0.f;
      for (int p = 0; p < 32; ++p) s += cred[p][tid];
      red[tid] = s;
    }
    __syncthreads();
    if (tid == 0) {
      float tot = 0.f;
      for (int k = 0; k < 32; ++k) tot += red[k];
      sred[0] = tot;
    }
    __syncthreads();
    if (tid < 32) {
      float prel = red[tid] / sred[0];
      fj[tid] = sqrtf(st[4 + tid] / prel);
    }
    __syncthreads();
  }

  // ===================== path I =====================
  {
    const int q = tid & 31, g = tid >> 5;
    float s = 0.f;
    const float* wp = p_xi + (size_t)d * 512 * 32;
    for (int i = g * 64; i < g * 64 + 64; ++i) s += wp[(size_t)i * 32 + q];
    __syncthreads();
    red[tid] = s;
    __syncthreads();
    if (g == 0) {
      float v = 0.f;
      for (int gg = 0; gg < 8; ++gg) v += red[gg * 32 + q];
      colW[q] = v;
    }
    __syncthreads();
  }
  float acc2[4] = {0.f, 0.f, 0.f, 0.f};
  {
    const ushort* Tb = Txi + (size_t)bd * 16384;
    const float* wp = p_xi + (size_t)d * 512 * 32;
    for (int i0 = 0; i0 < 512; i0 += 64) {
      {
        const int ii = tid >> 2, p8 = (tid & 3) * 8;
        u16x8 tv8 = *reinterpret_cast<const u16x8*>(&Tb[(size_t)(i0 + ii) * 32 + p8]);
        #pragma unroll
        for (int e = 0; e < 8; ++e) Ts[ii][p8 + e] = bf2f((ushort)tv8[e]);
      }
      #pragma unroll
      for (int l = 0; l < 2; ++l) {
        const int e = tid + l * 256;
        const int ii = e >> 3, p4 = (e & 7) * 4;
        *reinterpret_cast<float4*>(&Ws[ii][p4]) = *reinterpret_cast<const float4*>(&wp[(size_t)(i0 + ii) * 32 + p4]);
      }
      __syncthreads();
      #pragma unroll 8
      for (int ii = 0; ii < 64; ++ii) {
        const float wvs = Ws[ii][row];
        const float4 tv = *reinterpret_cast<const float4*>(&Ts[ii][c4]);
        acc2[0] = fmaf(wvs, tv.x, acc2[0]);
        acc2[1] = fmaf(wvs, tv.y, acc2[1]);
        acc2[2] = fmaf(wvs, tv.z, acc2[2]);
        acc2[3] = fmaf(wvs, tv.w, acc2[3]);
      }
      __syncthreads();
    }
  }
  {
    float tv[4]; float ls = 0.f, lq = 0.f;
    #pragma unroll
    for (int e = 0; e < 4; ++e) {
      float v = (acc2[e] - meanI * colW[row]) * rstdI;
      float t = fast_tanh(v);
      tv[e] = t; ls += t; lq += t * t;
    }
    red[tid] = ls; red2[tid] = lq;
    __syncthreads();
    for (int off = 128; off > 0; off >>= 1) {
      if (tid < off) { red[tid] += red[tid + off]; red2[tid] += red2[tid + off]; }
      __syncthreads();
    }
    if (tid == 0) {
      float s = red[0], ss = red2[0];
      float m = s / 1024.f;
      float var = (ss - s * s / 1024.f) / 1023.f;
      sred[0] = m; sred[1] = 1.f / (sqrtf(fmaxf(var, 0.f)) + EPSF);
    }
    __syncthreads();
    const float m2 = sred[0], r2 = sred[1];
    #pragma unroll
    for (int e = 0; e < 4; ++e) U[row][c4 + e] = (tv[e] - m2) * r2;
    __syncthreads();
  }
  {
    for (int l = tid; l < 1024; l += 256) (&R[0][0])[l] = rel_pi[(size_t)d * 1024 + l];
    __syncthreads();
    float racc[4] = {0.f, 0.f, 0.f, 0.f};
    #pragma unroll
    for (int c = 0; c < 32; ++c) {
      const float v = U[row][c];
      racc[0] = fmaf(v, R[c][c4 + 0], racc[0]);
      racc[1] = fmaf(v, R[c][c4 + 1], racc[1]);
      racc[2] = fmaf(v, R[c][c4 + 2], racc[2]);
      racc[3] = fmaf(v, R[c][c4 + 3], racc[3]);
    }
    #pragma unroll
    for (int e = 0; e < 4; ++e) cred[row][c4 + e] = __expf(racc[e]);
    __syncthreads();
    if (tid < 32) {
      float s = 0.f;
      for (int p = 0; p < 32; ++p) s += cred[p][tid];
      red[tid] = s;
    }
    __syncthreads();
    if (tid == 0) {
      float tot = 0.f;
      for (int k = 0; k < 32; ++k) tot += red[k];
      sred[0] = tot;
    }
    __syncthreads();
    if (tid < 32) {
      float prel = red[tid] / sred[0];
      fi[tid] = sqrtf(st[36 + tid] / prel);
    }
    __syncthreads();
  }

  // ===================== combine =====================
  {
    float xv[4]; float ls = 0.f, lq = 0.f;
    #pragma unroll
    for (int e = 0; e < 4; ++e) {
      const int q = c4 + e;
      float v = fast_tanh(Vj[row][q] * fj[row] * U[q][row] * fi[q]);
      xv[e] = v; ls += v; lq += v * v;
    }
    red[tid] = ls; red2[tid] = lq;
    __syncthreads();
    for (int off = 128; off > 0; off >>= 1) {
      if (tid < off) { red[tid] += red[tid + off]; red2[tid] += red2[tid + off]; }
      __syncthreads();
    }
    if (tid == 0) {
      float s = red[0], ss = red2[0];
      float m = s / 1024.f;
      float var = (ss - s * s / 1024.f) / 1023.f;
      sred[0] = m; sred[1] = 1.f / (sqrtf(fmaxf(var, 0.f)) + EPSF);
    }
    __syncthreads();
    const float m3 = sred[0], r3 = sred[1];
    const float xs = bstat[b * 2 + 1], xm = bstat[b * 2 + 0];
    const float g = gamma_p[d], be = beta_p[d];
    #pragma unroll
    for (int e = 0; e < 4; ++e) {
      float v = (xv[e] - m3) * r3 * xs + xm;
      v = v * g + be;
      xball[(size_t)bd * 1024 + row * 32 + c4 + e] = v;
    }
  }
}

// ---------------- K5: sum over d / D ----------------
__global__ void final_kernel(const float* __restrict__ xball, float* __restrict__ out) {
  const int b = blockIdx.x;
  for (int e = threadIdx.x; e < 1024; e += 256) {
    float s = 0.f;
    #pragma unroll
    for (int d = 0; d < 8; ++d) s += xball[((size_t)(b * 8 + d)) * 1024 + e];
    out[(size_t)b * 1024 + e] = s * 0.125f;
  }
}

extern "C" void kernel_launch(void* const* d_in, const int* in_sizes, int n_in,
                              void* d_out, int out_size, void* d_ws, size_t ws_size,
                              hipStream_t stream) {
  const float* x        = (const float*)d_in[0];
  const float* o_xj     = (const float*)d_in[1];
  const float* o_xi     = (const float*)d_in[2];
  const float* p_xj     = (const float*)d_in[3];
  const float* p_xi     = (const float*)d_in[4];
  const float* rel_o_xj = (const float*)d_in[5];
  const float* rel_o_xi = (const float*)d_in[6];
  const float* rel_p_xj = (const float*)d_in[7];
  const float* rel_p_xi = (const float*)d_in[8];
  const float* gamma_p  = (const float*)d_in[9];
  const float* beta_p   = (const float*)d_in[10];
  float* out = (float*)d_out;

  char* base = (char*)d_ws;
  ushort* xhi  = (ushort*)base; base += (size_t)33554432;
  ushort* xthi = (ushort*)base; base += (size_t)33554432;
  ushort* wjhi = (ushort*)base; base += 524288;
  ushort* wjlo = (ushort*)base; base += 524288;
  ushort* wihi = (ushort*)base; base += 524288;
  ushort* wilo = (ushort*)base; base += 524288;
  ushort* Txj  = (ushort*)base; base += (size_t)16777216;
  ushort* Txi  = (ushort*)base; base += (size_t)16777216;
  float* pJ    = (float*)base;  base += 278528;
  float* pI    = (float*)base;  base += 278528;
  float* bpart = (float*)base;  base += 32768;
  float* bstat = (float*)base;  base += 512;
  float* stats = (float*)base;  base += 139264;
  float* xball = (float*)base;  base += 2097152;

  hipLaunchKernelGGL(pack_w, dim3(256), dim3(256), 0, stream,
                     o_xj, o_xi, rel_o_xj, rel_o_xi, wjhi, wjlo, wihi, wilo);
  hipLaunchKernelGGL(convx, dim3(8, 8, 64), dim3(256), 0, stream, x, xhi, xthi, bpart);
  hipLaunchKernelGGL(bstats_f, dim3(1), dim3(64), 0, stream, bpart, bstat);
  hipLaunchKernelGGL(mfma_gemm, dim3(2048), dim3(256), 0, stream,
                     xhi, xthi, wjhi, wjlo, wihi, wilo, Txj, Txi, pJ, pI);
  hipLaunchKernelGGL(reduce_stats_kernel, dim3(512), dim3(128), 0, stream, pJ, pI, stats);
  hipLaunchKernelGGL(stage3_kernel, dim3(512), dim3(256), 0, stream,
                     Txj, Txi, p_xj, p_xi, rel_p_xj, rel_p_xi, stats, bstat, gamma_p, beta_p, xball);
  hipLaunchKernelGGL(final_kernel, dim3(64), dim3(256), 0, stream, xball, out);
}

// Round 6
// 150.844 us; speedup vs baseline: 3.9617x; 1.0061x over previous
//
#include <hip/hip_runtime.h>
#include <math.h>

static constexpr float EPSF = 1e-5f;

typedef short bf16x8 __attribute__((ext_vector_type(8)));
typedef float f32x4 __attribute__((ext_vector_type(4)));
typedef ushort u16x8 __attribute__((ext_vector_type(8)));

__device__ inline ushort bf16rn(float f) {
  unsigned u = __float_as_uint(f);
  unsigned r = (u + 0x7FFFu + ((u >> 16) & 1u)) >> 16;
  return (ushort)r;
}
__device__ inline float bf2f(ushort u) { return __uint_as_float(((unsigned)u) << 16); }
__device__ inline void split2(float f, ushort& hi, ushort& lo) {
  ushort h = bf16rn(f);
  float hf = bf2f(h);
  hi = h;
  lo = bf16rn(f - hf);
}
// tanh via hw exp+rcp: exact at saturation, ~1e-7 abs err
__device__ inline float fast_tanh(float x) {
  float e = __expf(2.f * x);
  return 1.f - 2.f * __builtin_amdgcn_rcpf(e + 1.f);
}

__device__ inline void gload16(const ushort* g, ushort* l) {
  __builtin_amdgcn_global_load_lds((const __attribute__((address_space(1))) void*)g,
                                   (__attribute__((address_space(3))) void*)l, 16, 0, 0);
}

// Tiled layout (ushort index): addr(row,k) = (row>>7)*65536 + (k>>5)*4096
//   + ((k>>3)&3)*1024 + (row&127)*8 + (k&7)
__device__ inline size_t tiled_addr(int row, int k) {
  return (size_t)(row >> 7) * 65536 + (size_t)(k >> 5) * 4096 +
         (size_t)((k >> 3) & 3) * 1024 + (size_t)(row & 127) * 8 + (k & 7);
}

// ---------------- K1: fused convx (blocks 0..4095) + pack_w (blocks 4096..4351) ----------------
__global__ __launch_bounds__(256) void conv_pack(
    const float* __restrict__ x,
    const float* __restrict__ o_xj, const float* __restrict__ o_xi,
    const float* __restrict__ rel_o_xj, const float* __restrict__ rel_o_xi,
    ushort* __restrict__ xhi, ushort* __restrict__ xthi,
    ushort* __restrict__ wjhi, ushort* __restrict__ wjlo,
    ushort* __restrict__ wihi, ushort* __restrict__ wilo,
    float* __restrict__ bpart) {
  const int bx = blockIdx.x;
  const int tid = threadIdx.x;
  if (bx >= 4096) {
    // ---- pack_w part ----
    int u = (bx - 4096) * 256 + tid;   // 0..65535
    int path = u >> 15;
    int v = u & 32767;
    int c = v >> 6;
    int k0 = (v & 63) * 8;
    int d = c >> 6, s = (c >> 5) & 1, p = c & 31;
    const float* src = path ? (s ? rel_o_xi : o_xi) : (s ? rel_o_xj : o_xj);
    u16x8 h8, l8;
    #pragma unroll
    for (int e = 0; e < 8; ++e) {
      ushort h, l;
      split2(src[((size_t)d * 512 + k0 + e) * 32 + p], h, l);
      h8[e] = h; l8[e] = l;
    }
    size_t a = tiled_addr(c, k0);
    ushort* whi = path ? wihi : wjhi;
    ushort* wlo = path ? wilo : wjlo;
    *reinterpret_cast<u16x8*>(&whi[a]) = h8;
    *reinterpret_cast<u16x8*>(&wlo[a]) = l8;
    return;
  }
  // ---- convx part ----
  __shared__ float tile[64][65];
  __shared__ float rs[256], rs2[256];
  const int ti = bx & 7, tj = (bx >> 3) & 7, b = bx >> 6;
  const int i0 = ti * 64, j0 = tj * 64;
  const float* xb = x + (size_t)b * 262144;
  const size_t obase = (size_t)b * 262144;
  const int tr = tid >> 4;
  const int tc = (tid & 15) * 4;
  float s = 0.f, s2 = 0.f;
  #pragma unroll
  for (int r = 0; r < 4; ++r) {
    const int row = r * 16 + tr;
    float4 v = *reinterpret_cast<const float4*>(&xb[(size_t)(i0 + row) * 512 + j0 + tc]);
    tile[row][tc + 0] = v.x; tile[row][tc + 1] = v.y;
    tile[row][tc + 2] = v.z; tile[row][tc + 3] = v.w;
    s += v.x + v.y + v.z + v.w;
    s2 += v.x * v.x + v.y * v.y + v.z * v.z + v.w * v.w;
  }
  __syncthreads();
  const int kg = tid >> 5;   // 0..7
  const int rp = tid & 31;
  #pragma unroll
  for (int rr = 0; rr < 2; ++rr) {
    const int li = rp + rr * 32;
    u16x8 h8;
    #pragma unroll
    for (int e = 0; e < 8; ++e) h8[e] = bf16rn(tile[li][kg * 8 + e]);
    *reinterpret_cast<u16x8*>(&xhi[obase + tiled_addr(i0 + li, j0 + kg * 8)]) = h8;
  }
  #pragma unroll
  for (int rr = 0; rr < 2; ++rr) {
    const int lj = rp + rr * 32;
    u16x8 h8;
    #pragma unroll
    for (int e = 0; e < 8; ++e) h8[e] = bf16rn(tile[kg * 8 + e][lj]);
    *reinterpret_cast<u16x8*>(&xthi[obase + tiled_addr(j0 + lj, i0 + kg * 8)]) = h8;
  }
  rs[tid] = s; rs2[tid] = s2;
  __syncthreads();
  for (int off = 128; off > 0; off >>= 1) {
    if (tid < off) { rs[tid] += rs[tid + off]; rs2[tid] += rs2[tid + off]; }
    __syncthreads();
  }
  if (tid == 0) {
    float* pb = bpart + ((size_t)b * 64 + tj * 8 + ti) * 2;
    pb[0] = rs[0]; pb[1] = rs2[0];
  }
}

// ---------------- K2: MFMA GEMM; b_lo correction only for the T (tanh) columns ----------------
__global__ __launch_bounds__(256) void mfma_gemm(
    const ushort* __restrict__ xhi, const ushort* __restrict__ xthi,
    const ushort* __restrict__ wjhi, const ushort* __restrict__ wjlo,
    const ushort* __restrict__ wihi, const ushort* __restrict__ wilo,
    ushort* __restrict__ Txj, ushort* __restrict__ Txi,
    float* __restrict__ pJ, float* __restrict__ pI) {
  const int id = blockIdx.x;
  const int wid = (id & 7) * 256 + (id >> 3);   // XCD-aware swizzle (2048 = 8*256)
  const int ct = wid & 3, tm = (wid >> 2) & 3, bz = wid >> 4;
  const int b = bz >> 1, path = bz & 1;
  const ushort* Ahi = (path ? xthi : xhi) + (size_t)b * 262144 + (size_t)tm * 65536;
  const ushort* Bhi = (path ? wihi : wjhi) + (size_t)ct * 65536;
  const ushort* Blo = (path ? wilo : wjlo) + (size_t)ct * 65536;
  ushort* Tb = (path ? Txi : Txj) + (size_t)b * 131072;
  float* partial = path ? pI : pJ;

  __shared__ alignas(16) ushort As_hi[4096], Bs_hi[4096], Bs_lo[4096];
  __shared__ float rsum[4], rsq[4], rcol[4][32];

  const int tid = threadIdx.x;
  const int lane = tid & 63, w = tid >> 6;
  const int wr = w >> 1, wc = w & 1;
  const int m0 = tm * 128;

  const int L8 = (w * 64 + lane) * 8;
  const int ldsb0 = (w * 64) * 8;
  const int ldsb1 = 2048 + (w * 64) * 8;

  f32x4 acc[4][4] = {};
  const int fr = lane & 15;
  const int kc = lane >> 4;

  for (int ks = 0; ks < 16; ++ks) {
    const ushort* Ah = Ahi + ks * 4096;
    const ushort* Bh = Bhi + ks * 4096;
    const ushort* Bl = Blo + ks * 4096;
    gload16(Ah + L8,        &As_hi[ldsb0]);
    gload16(Ah + 2048 + L8, &As_hi[ldsb1]);
    gload16(Bh + L8,        &Bs_hi[ldsb0]);
    gload16(Bh + 2048 + L8, &Bs_hi[ldsb1]);
    gload16(Bl + L8,        &Bs_lo[ldsb0]);
    gload16(Bl + 2048 + L8, &Bs_lo[ldsb1]);
    __syncthreads();
    bf16x8 ah[4], bh[4], bl2[2];
    #pragma unroll
    for (int mi = 0; mi < 4; ++mi) {
      const int ra = (kc * 128 + wr * 64 + mi * 16 + fr) * 8;
      ah[mi] = *reinterpret_cast<const bf16x8*>(&As_hi[ra]);
    }
    #pragma unroll
    for (int ni = 0; ni < 4; ++ni) {
      const int rb = (kc * 128 + wc * 64 + ni * 16 + fr) * 8;
      bh[ni] = *reinterpret_cast<const bf16x8*>(&Bs_hi[rb]);
      if (ni < 2) bl2[ni] = *reinterpret_cast<const bf16x8*>(&Bs_lo[rb]);
    }
    #pragma unroll
    for (int mi = 0; mi < 4; ++mi) {
      #pragma unroll
      for (int ni = 0; ni < 4; ++ni)
        acc[mi][ni] = __builtin_amdgcn_mfma_f32_16x16x32_bf16(ah[mi], bh[ni], acc[mi][ni], 0, 0, 0);
      #pragma unroll
      for (int ni = 0; ni < 2; ++ni)
        acc[mi][ni] = __builtin_amdgcn_mfma_f32_16x16x32_bf16(ah[mi], bl2[ni], acc[mi][ni], 0, 0, 0);
    }
    __syncthreads();
  }

  float lsum = 0.f, lsq = 0.f, cs0 = 0.f, cs1 = 0.f;
  const int d = ct * 2 + wc;
  #pragma unroll
  for (int mi = 0; mi < 4; ++mi) {
    const int rbase = m0 + wr * 64 + mi * 16 + ((lane >> 4) << 2);
    #pragma unroll
    for (int ni = 0; ni < 4; ++ni) {
      #pragma unroll
      for (int r = 0; r < 4; ++r) {
        float v = acc[mi][ni][r];
        if (ni < 2) {
          float t = fast_tanh(v);
          Tb[((size_t)d * 512 + rbase + r) * 32 + ni * 16 + fr] = bf16rn(t);
          lsum += t; lsq += t * t;
        } else {
          float e = __expf(v);
          if (ni == 2) cs0 += e; else cs1 += e;
        }
      }
    }
  }
  #pragma unroll
  for (int m = 1; m < 64; m <<= 1) { lsum += __shfl_xor(lsum, m); lsq += __shfl_xor(lsq, m); }
  cs0 += __shfl_xor(cs0, 16); cs0 += __shfl_xor(cs0, 32);
  cs1 += __shfl_xor(cs1, 16); cs1 += __shfl_xor(cs1, 32);
  if (lane == 0) { rsum[w] = lsum; rsq[w] = lsq; }
  if (lane < 16) { rcol[w][lane] = cs0; rcol[w][16 + lane] = cs1; }
  __syncthreads();
  if (tid < 64) {
    const int wc2 = tid >> 5, p = tid & 31;
    float* pb = partial + (((size_t)b * 4 + tm) * 8 + ct * 2 + wc2) * 34;
    pb[2 + p] = rcol[wc2][p] + rcol[wc2 + 2][p];
    if (p == 0) {
      pb[0] = rsum[wc2] + rsum[wc2 + 2];
      pb[1] = rsq[wc2] + rsq[wc2 + 2];
    }
  }
}

// ---------------- K3: fold the 4 row-tile partials -> per-(b,d) stats ----------------
__global__ void reduce_stats_kernel(const float* __restrict__ pJ, const float* __restrict__ pI,
                                    float* __restrict__ stats) {
  const int bd = blockIdx.x;
  const int b = bd >> 3, d = bd & 7;
  const int t = threadIdx.x;   // 128 threads
  __shared__ float tmp[2][34];
  if (t < 34) {
    float v = 0.f;
    for (int tm = 0; tm < 4; ++tm) v += pJ[(((size_t)b * 4 + tm) * 8 + d) * 34 + t];
    tmp[0][t] = v;
  } else if (t >= 64 && t < 98) {
    const int u = t - 64;
    float v = 0.f;
    for (int tm = 0; tm < 4; ++tm) v += pI[(((size_t)b * 4 + tm) * 8 + d) * 34 + u];
    tmp[1][u] = v;
  }
  __syncthreads();
  if (t < 2) {
    const float* tp = tmp[t];
    float* st = stats + (size_t)bd * 68;
    const float N = 16384.f;
    float mean = tp[0] / N;
    float var = (tp[1] - tp[0] * tp[0] / N) / (N - 1.f);
    float rstd = 1.f / (sqrtf(fmaxf(var, 0.f)) + EPSF);
    st[t * 2 + 0] = mean;
    st[t * 2 + 1] = rstd;
    float tot = 0.f;
    for (int k = 0; k < 32; ++k) tot += tp[2 + k];
    float inv = 1.f / tot;
    for (int k = 0; k < 32; ++k) st[4 + t * 32 + k] = tp[2 + k] * inv;
  }
}

// ---------------- K4: per-(b,d,path) projection path ----------------
// path 0 (J): M[p][q] = sum_i T[i][p] W[i][q], corr by colW[q]
// path 1 (I): M[q][p] = sum_j W[j][q] T[j][p], corr by colW[q] (= row index)
// then standardize+tanh, rel matmul + softmax colsum -> f.
__global__ __launch_bounds__(256) void stage3_path(
    const ushort* __restrict__ Txj, const ushort* __restrict__ Txi,
    const float* __restrict__ p_xj, const float* __restrict__ p_xi,
    const float* __restrict__ rel_pj, const float* __restrict__ rel_pi,
    const float* __restrict__ stats,
    float* __restrict__ Vws, float* __restrict__ fws) {
  const int blk = blockIdx.x;
  const int path = blk & 1, bd = blk >> 1;
  const int d = bd & 7;
  const int tid = threadIdx.x;
  const int row = tid >> 3;       // 0..31
  const int c4 = (tid & 7) * 4;
  __shared__ float Ts[64][32];
  __shared__ float Ws[64][32];
  __shared__ float Vl[32][33];
  __shared__ float cred[32][33];
  __shared__ float red[256], red2[256];
  __shared__ float colW[32];
  __shared__ float sred[2];
  const ushort* Tb = (path ? Txi : Txj) + (size_t)bd * 16384;
  const float* wp = (path ? p_xi : p_xj) + (size_t)d * 16384;
  const float* Rg = (path ? rel_pi : rel_pj) + (size_t)d * 1024;
  const float* st = stats + (size_t)bd * 68;
  const float mean = st[path * 2], rstd = st[path * 2 + 1];

  // colW[q] = column sums of W
  {
    const int q = tid & 31, g = tid >> 5;
    float s = 0.f;
    for (int i = g * 64; i < g * 64 + 64; ++i) s += wp[(size_t)i * 32 + q];
    red[tid] = s;
    __syncthreads();
    if (g == 0) {
      float v = 0.f;
      for (int gg = 0; gg < 8; ++gg) v += red[gg * 32 + q];
      colW[q] = v;
    }
    __syncthreads();
  }
  float acc[4] = {0.f, 0.f, 0.f, 0.f};
  for (int i0 = 0; i0 < 512; i0 += 64) {
    {
      const int ii = tid >> 2, p8 = (tid & 3) * 8;
      u16x8 tv8 = *reinterpret_cast<const u16x8*>(&Tb[(size_t)(i0 + ii) * 32 + p8]);
      #pragma unroll
      for (int e = 0; e < 8; ++e) Ts[ii][p8 + e] = bf2f((ushort)tv8[e]);
    }
    #pragma unroll
    for (int l = 0; l < 2; ++l) {
      const int e = tid + l * 256;
      const int ii = e >> 3, p4 = (e & 7) * 4;
      *reinterpret_cast<float4*>(&Ws[ii][p4]) = *reinterpret_cast<const float4*>(&wp[(size_t)(i0 + ii) * 32 + p4]);
    }
    __syncthreads();
    if (path == 0) {
      #pragma unroll 8
      for (int ii = 0; ii < 64; ++ii) {
        const float sv = Ts[ii][row];
        const float4 wv = *reinterpret_cast<const float4*>(&Ws[ii][c4]);
        acc[0] = fmaf(sv, wv.x, acc[0]);
        acc[1] = fmaf(sv, wv.y, acc[1]);
        acc[2] = fmaf(sv, wv.z, acc[2]);
        acc[3] = fmaf(sv, wv.w, acc[3]);
      }
    } else {
      #pragma unroll 8
      for (int ii = 0; ii < 64; ++ii) {
        const float sv = Ws[ii][row];
        const float4 tv = *reinterpret_cast<const float4*>(&Ts[ii][c4]);
        acc[0] = fmaf(sv, tv.x, acc[0]);
        acc[1] = fmaf(sv, tv.y, acc[1]);
        acc[2] = fmaf(sv, tv.z, acc[2]);
        acc[3] = fmaf(sv, tv.w, acc[3]);
      }
    }
    __syncthreads();
  }
  // standardize correction + tanh + block standardize
  float tv[4]; float ls = 0.f, lq = 0.f;
  #pragma unroll
  for (int e = 0; e < 4; ++e) {
    const float corr = (path == 0) ? colW[c4 + e] : colW[row];
    float v = (acc[e] - mean * corr) * rstd;
    float t = fast_tanh(v);
    tv[e] = t; ls += t; lq += t * t;
  }
  red[tid] = ls; red2[tid] = lq;
  __syncthreads();
  for (int off = 128; off > 0; off >>= 1) {
    if (tid < off) { red[tid] += red[tid + off]; red2[tid] += red2[tid + off]; }
    __syncthreads();
  }
  if (tid == 0) {
    float s = red[0], ss = red2[0];
    float m = s / 1024.f;
    float var = (ss - s * s / 1024.f) / 1023.f;
    sred[0] = m; sred[1] = 1.f / (sqrtf(fmaxf(var, 0.f)) + EPSF);
  }
  __syncthreads();
  {
    const float m2 = sred[0], r2 = sred[1];
    float4 o;
    o.x = (tv[0] - m2) * r2; o.y = (tv[1] - m2) * r2;
    o.z = (tv[2] - m2) * r2; o.w = (tv[3] - m2) * r2;
    Vl[row][c4 + 0] = o.x; Vl[row][c4 + 1] = o.y;
    Vl[row][c4 + 2] = o.z; Vl[row][c4 + 3] = o.w;
    float* Vout = Vws + ((size_t)bd * 2 + path) * 1024;
    *reinterpret_cast<float4*>(&Vout[row * 32 + c4]) = o;
  }
  // stage R into Ts (reuse), then rel matmul
  __syncthreads();
  for (int l = tid; l < 1024; l += 256) Ts[l >> 5][l & 31] = Rg[l];
  __syncthreads();
  {
    float racc[4] = {0.f, 0.f, 0.f, 0.f};
    #pragma unroll
    for (int c = 0; c < 32; ++c) {
      const float v = Vl[row][c];
      racc[0] = fmaf(v, Ts[c][c4 + 0], racc[0]);
      racc[1] = fmaf(v, Ts[c][c4 + 1], racc[1]);
      racc[2] = fmaf(v, Ts[c][c4 + 2], racc[2]);
      racc[3] = fmaf(v, Ts[c][c4 + 3], racc[3]);
    }
    #pragma unroll
    for (int e = 0; e < 4; ++e) cred[row][c4 + e] = __expf(racc[e]);
  }
  __syncthreads();
  if (tid < 32) {
    float s = 0.f;
    for (int p = 0; p < 32; ++p) s += cred[p][tid];
    red[tid] = s;
  }
  __syncthreads();
  if (tid == 0) {
    float tot = 0.f;
    for (int k = 0; k < 32; ++k) tot += red[k];
    sred[0] = tot;
  }
  __syncthreads();
  if (tid < 32) {
    float prel = red[tid] / sred[0];
    fws[((size_t)bd * 2 + path) * 32 + tid] = sqrtf(st[4 + path * 32 + tid] / prel);
  }
}

// ---------------- K5: combine (also folds batch-stat reduce) ----------------
__global__ __launch_bounds__(256) void stage3_combine(
    const float* __restrict__ Vws, const float* __restrict__ fws,
    const float* __restrict__ bpart,
    const float* __restrict__ gamma_p, const float* __restrict__ beta_p,
    float* __restrict__ xball) {
  const int bd = blockIdx.x;
  const int b = bd >> 3, d = bd & 7;
  const int tid = threadIdx.x;
  const int row = tid >> 3, c4 = (tid & 7) * 4;
  __shared__ float Vj[1024];
  __shared__ float Ut[32][33];   // Ut[p][q] = U[q][p]
  __shared__ float fj[32], fi[32];
  __shared__ float red[256], red2[256];
  __shared__ float sred[2], sbst[2];
  const float* vj = Vws + (size_t)bd * 2048;
  const float* ui = vj + 1024;
  for (int l = tid; l < 1024; l += 256) Vj[l] = vj[l];
  for (int l = tid; l < 1024; l += 256) { int r = l >> 5, c = l & 31; Ut[c][r] = ui[l]; }
  if (tid < 32) { fj[tid] = fws[(size_t)bd * 64 + tid]; fi[tid] = fws[(size_t)bd * 64 + 32 + tid]; }
  if (tid < 64) {
    float s = bpart[(size_t)b * 128 + tid * 2];
    float s2 = bpart[(size_t)b * 128 + tid * 2 + 1];
    #pragma unroll
    for (int m = 1; m < 64; m <<= 1) { s += __shfl_xor(s, m); s2 += __shfl_xor(s2, m); }
    if (tid == 0) {
      const float N = 262144.f;
      float mean = s / N;
      float var = (s2 - s * s / N) / (N - 1.f);
      sbst[0] = mean * 256.f;
      sbst[1] = sqrtf(fmaxf(var, 0.f)) * 256.f;
    }
  }
  __syncthreads();
  float xv[4]; float ls = 0.f, lq = 0.f;
  #pragma unroll
  for (int e = 0; e < 4; ++e) {
    const int q = c4 + e;
    float v = fast_tanh(Vj[row * 32 + q] * fj[row] * Ut[row][q] * fi[q]);
    xv[e] = v; ls += v; lq += v * v;
  }
  red[tid] = ls; red2[tid] = lq;
  __syncthreads();
  for (int off = 128; off > 0; off >>= 1) {
    if (tid < off) { red[tid] += red[tid + off]; red2[tid] += red2[tid + off]; }
    __syncthreads();
  }
  if (tid == 0) {
    float s = red[0], ss = red2[0];
    float m = s / 1024.f;
    float var = (ss - s * s / 1024.f) / 1023.f;
    sred[0] = m; sred[1] = 1.f / (sqrtf(fmaxf(var, 0.f)) + EPSF);
  }
  __syncthreads();
  const float m3 = sred[0], r3 = sred[1];
  const float xm = sbst[0], xs = sbst[1];
  const float g = gamma_p[d], be = beta_p[d];
  #pragma unroll
  for (int e = 0; e < 4; ++e) {
    float v = (xv[e] - m3) * r3 * xs + xm;
    v = v * g + be;
    xball[(size_t)bd * 1024 + row * 32 + c4 + e] = v;
  }
}

// ---------------- K6: sum over d / D ----------------
__global__ void final_kernel(const float* __restrict__ xball, float* __restrict__ out) {
  const int b = blockIdx.x;
  for (int e = threadIdx.x; e < 1024; e += 256) {
    float s = 0.f;
    #pragma unroll
    for (int d = 0; d < 8; ++d) s += xball[((size_t)(b * 8 + d)) * 1024 + e];
    out[(size_t)b * 1024 + e] = s * 0.125f;
  }
}

extern "C" void kernel_launch(void* const* d_in, const int* in_sizes, int n_in,
                              void* d_out, int out_size, void* d_ws, size_t ws_size,
                              hipStream_t stream) {
  const float* x        = (const float*)d_in[0];
  const float* o_xj     = (const float*)d_in[1];
  const float* o_xi     = (const float*)d_in[2];
  const float* p_xj     = (const float*)d_in[3];
  const float* p_xi     = (const float*)d_in[4];
  const float* rel_o_xj = (const float*)d_in[5];
  const float* rel_o_xi = (const float*)d_in[6];
  const float* rel_p_xj = (const float*)d_in[7];
  const float* rel_p_xi = (const float*)d_in[8];
  const float* gamma_p  = (const float*)d_in[9];
  const float* beta_p   = (const float*)d_in[10];
  float* out = (float*)d_out;

  char* base = (char*)d_ws;
  ushort* xhi  = (ushort*)base; base += (size_t)33554432;
  ushort* xthi = (ushort*)base; base += (size_t)33554432;
  ushort* wjhi = (ushort*)base; base += 524288;
  ushort* wjlo = (ushort*)base; base += 524288;
  ushort* wihi = (ushort*)base; base += 524288;
  ushort* wilo = (ushort*)base; base += 524288;
  ushort* Txj  = (ushort*)base; base += (size_t)16777216;
  ushort* Txi  = (ushort*)base; base += (size_t)16777216;
  float* pJ    = (float*)base;  base += 278528;
  float* pI    = (float*)base;  base += 278528;
  float* bpart = (float*)base;  base += 32768;
  float* stats = (float*)base;  base += 139264;
  float* Vws   = (float*)base;  base += 4194304;
  float* fws   = (float*)base;  base += 131072;
  float* xball = (float*)base;  base += 2097152;

  hipLaunchKernelGGL(conv_pack, dim3(4352), dim3(256), 0, stream,
                     x, o_xj, o_xi, rel_o_xj, rel_o_xi,
                     xhi, xthi, wjhi, wjlo, wihi, wilo, bpart);
  hipLaunchKernelGGL(mfma_gemm, dim3(2048), dim3(256), 0, stream,
                     xhi, xthi, wjhi, wjlo, wihi, wilo, Txj, Txi, pJ, pI);
  hipLaunchKernelGGL(reduce_stats_kernel, dim3(512), dim3(128), 0, stream, pJ, pI, stats);
  hipLaunchKernelGGL(stage3_path, dim3(1024), dim3(256), 0, stream,
                     Txj, Txi, p_xj, p_xi, rel_p_xj, rel_p_xi, stats, Vws, fws);
  hipLaunchKernelGGL(stage3_combine, dim3(512), dim3(256), 0, stream,
                     Vws, fws, bpart, gamma_p, beta_p, xball);
  hipLaunchKernelGGL(final_kernel, dim3(64), dim3(256), 0, stream, xball, out);
}

// Round 7
// 124.384 us; speedup vs baseline: 4.8045x; 1.2127x over previous
//
#include <hip/hip_runtime.h>
#include <math.h>

static constexpr float EPSF = 1e-5f;

typedef short bf16x8 __attribute__((ext_vector_type(8)));
typedef float f32x4 __attribute__((ext_vector_type(4)));
typedef ushort u16x8 __attribute__((ext_vector_type(8)));

__device__ inline ushort bf16rn(float f) {
  unsigned u = __float_as_uint(f);
  unsigned r = (u + 0x7FFFu + ((u >> 16) & 1u)) >> 16;
  return (ushort)r;
}
__device__ inline float bf2f(ushort u) { return __uint_as_float(((unsigned)u) << 16); }
__device__ inline void split2(float f, ushort& hi, ushort& lo) {
  ushort h = bf16rn(f);
  float hf = bf2f(h);
  hi = h;
  lo = bf16rn(f - hf);
}
// tanh via hw exp+rcp: exact at saturation, ~1e-7 abs err
__device__ inline float fast_tanh(float x) {
  float e = __expf(2.f * x);
  return 1.f - 2.f * __builtin_amdgcn_rcpf(e + 1.f);
}

__device__ inline void gload16(const ushort* g, ushort* l) {
  __builtin_amdgcn_global_load_lds((const __attribute__((address_space(1))) void*)g,
                                   (__attribute__((address_space(3))) void*)l, 16, 0, 0);
}

// Tiled layout (ushort index): addr(row,k) = (row>>7)*65536 + (k>>5)*4096
//   + ((k>>3)&3)*1024 + (row&127)*8 + (k&7)
__device__ inline size_t tiled_addr(int row, int k) {
  return (size_t)(row >> 7) * 65536 + (size_t)(k >> 5) * 4096 +
         (size_t)((k >> 3) & 3) * 1024 + (size_t)(row & 127) * 8 + (k & 7);
}

// ---------------- K1: fused convx (0..4095) + pack_w (4096..4351) + pack_pw (4352..4367) ----------------
__global__ __launch_bounds__(256) void conv_pack(
    const float* __restrict__ x,
    const float* __restrict__ o_xj, const float* __restrict__ o_xi,
    const float* __restrict__ rel_o_xj, const float* __restrict__ rel_o_xi,
    const float* __restrict__ p_xj, const float* __restrict__ p_xi,
    ushort* __restrict__ xhi, ushort* __restrict__ xthi,
    ushort* __restrict__ wjhi, ushort* __restrict__ wjlo,
    ushort* __restrict__ wihi, ushort* __restrict__ wilo,
    ushort* __restrict__ Wthi, ushort* __restrict__ Wtlo,
    float* __restrict__ colWs,
    float* __restrict__ bpart) {
  const int bx = blockIdx.x;
  const int tid = threadIdx.x;
  if (bx >= 4352) {
    // ---- pack_pw: p_xj/p_xi -> Wt[path][d][q][512] bf16 hi/lo + colWs ----
    const int pd = bx - 4352;            // 0..15
    const int path = pd >> 3, d = pd & 7;
    const float* src = (path ? p_xi : p_xj) + (size_t)d * 16384;
    ushort* whi = Wthi + (size_t)pd * 16384;
    ushort* wlo = Wtlo + (size_t)pd * 16384;
    __shared__ float buf[64][33];
    float cw = 0.f;
    const int q = tid >> 3, je8 = (tid & 7) * 8;
    for (int j0 = 0; j0 < 512; j0 += 64) {
      for (int l = tid; l < 2048; l += 256) buf[l >> 5][l & 31] = src[(size_t)j0 * 32 + l];
      __syncthreads();
      u16x8 h8, l8;
      #pragma unroll
      for (int e = 0; e < 8; ++e) {
        float fv = buf[je8 + e][q];
        cw += fv;
        ushort h, l; split2(fv, h, l);
        h8[e] = h; l8[e] = l;
      }
      *reinterpret_cast<u16x8*>(&whi[(size_t)q * 512 + j0 + je8]) = h8;
      *reinterpret_cast<u16x8*>(&wlo[(size_t)q * 512 + j0 + je8]) = l8;
      __syncthreads();
    }
    cw += __shfl_xor(cw, 1); cw += __shfl_xor(cw, 2); cw += __shfl_xor(cw, 4);
    if ((tid & 7) == 0) colWs[(size_t)pd * 32 + q] = cw;
    return;
  }
  if (bx >= 4096) {
    // ---- pack_w (o-weights, tiled hi/lo) ----
    int u = (bx - 4096) * 256 + tid;   // 0..65535
    int path = u >> 15;
    int v = u & 32767;
    int c = v >> 6;
    int k0 = (v & 63) * 8;
    int d = c >> 6, s = (c >> 5) & 1, p = c & 31;
    const float* src = path ? (s ? rel_o_xi : o_xi) : (s ? rel_o_xj : o_xj);
    u16x8 h8, l8;
    #pragma unroll
    for (int e = 0; e < 8; ++e) {
      ushort h, l;
      split2(src[((size_t)d * 512 + k0 + e) * 32 + p], h, l);
      h8[e] = h; l8[e] = l;
    }
    size_t a = tiled_addr(c, k0);
    ushort* whi = path ? wihi : wjhi;
    ushort* wlo = path ? wilo : wjlo;
    *reinterpret_cast<u16x8*>(&whi[a]) = h8;
    *reinterpret_cast<u16x8*>(&wlo[a]) = l8;
    return;
  }
  // ---- convx part ----
  __shared__ float tile[64][65];
  __shared__ float rs[256], rs2[256];
  const int ti = bx & 7, tj = (bx >> 3) & 7, b = bx >> 6;
  const int i0 = ti * 64, j0 = tj * 64;
  const float* xb = x + (size_t)b * 262144;
  const size_t obase = (size_t)b * 262144;
  const int tr = tid >> 4;
  const int tc = (tid & 15) * 4;
  float s = 0.f, s2 = 0.f;
  #pragma unroll
  for (int r = 0; r < 4; ++r) {
    const int row = r * 16 + tr;
    float4 v = *reinterpret_cast<const float4*>(&xb[(size_t)(i0 + row) * 512 + j0 + tc]);
    tile[row][tc + 0] = v.x; tile[row][tc + 1] = v.y;
    tile[row][tc + 2] = v.z; tile[row][tc + 3] = v.w;
    s += v.x + v.y + v.z + v.w;
    s2 += v.x * v.x + v.y * v.y + v.z * v.z + v.w * v.w;
  }
  __syncthreads();
  const int kg = tid >> 5;   // 0..7
  const int rp = tid & 31;
  #pragma unroll
  for (int rr = 0; rr < 2; ++rr) {
    const int li = rp + rr * 32;
    u16x8 h8;
    #pragma unroll
    for (int e = 0; e < 8; ++e) h8[e] = bf16rn(tile[li][kg * 8 + e]);
    *reinterpret_cast<u16x8*>(&xhi[obase + tiled_addr(i0 + li, j0 + kg * 8)]) = h8;
  }
  #pragma unroll
  for (int rr = 0; rr < 2; ++rr) {
    const int lj = rp + rr * 32;
    u16x8 h8;
    #pragma unroll
    for (int e = 0; e < 8; ++e) h8[e] = bf16rn(tile[kg * 8 + e][lj]);
    *reinterpret_cast<u16x8*>(&xthi[obase + tiled_addr(j0 + lj, i0 + kg * 8)]) = h8;
  }
  rs[tid] = s; rs2[tid] = s2;
  __syncthreads();
  for (int off = 128; off > 0; off >>= 1) {
    if (tid < off) { rs[tid] += rs[tid + off]; rs2[tid] += rs2[tid + off]; }
    __syncthreads();
  }
  if (tid == 0) {
    float* pb = bpart + ((size_t)b * 64 + tj * 8 + ti) * 2;
    pb[0] = rs[0]; pb[1] = rs2[0];
  }
}

// ---------------- K2: MFMA GEMM; b_lo correction only for the T (tanh) columns ----------------
// T output written TRANSPOSED: Tt[b][d][p 32][i 512] (bf16) for MFMA-friendly stage3.
__global__ __launch_bounds__(256) void mfma_gemm(
    const ushort* __restrict__ xhi, const ushort* __restrict__ xthi,
    const ushort* __restrict__ wjhi, const ushort* __restrict__ wjlo,
    const ushort* __restrict__ wihi, const ushort* __restrict__ wilo,
    ushort* __restrict__ Ttj, ushort* __restrict__ Tti,
    float* __restrict__ pJ, float* __restrict__ pI) {
  const int id = blockIdx.x;
  const int wid = (id & 7) * 256 + (id >> 3);   // XCD-aware swizzle (2048 = 8*256)
  const int ct = wid & 3, tm = (wid >> 2) & 3, bz = wid >> 4;
  const int b = bz >> 1, path = bz & 1;
  const ushort* Ahi = (path ? xthi : xhi) + (size_t)b * 262144 + (size_t)tm * 65536;
  const ushort* Bhi = (path ? wihi : wjhi) + (size_t)ct * 65536;
  const ushort* Blo = (path ? wilo : wjlo) + (size_t)ct * 65536;
  ushort* Tb = (path ? Tti : Ttj) + (size_t)b * 131072;
  float* partial = path ? pI : pJ;

  __shared__ alignas(16) ushort As_hi[4096], Bs_hi[4096], Bs_lo[4096];
  __shared__ float rsum[4], rsq[4], rcol[4][32];

  const int tid = threadIdx.x;
  const int lane = tid & 63, w = tid >> 6;
  const int wr = w >> 1, wc = w & 1;
  const int m0 = tm * 128;

  const int L8 = (w * 64 + lane) * 8;
  const int ldsb0 = (w * 64) * 8;
  const int ldsb1 = 2048 + (w * 64) * 8;

  f32x4 acc[4][4] = {};
  const int fr = lane & 15;
  const int kc = lane >> 4;

  for (int ks = 0; ks < 16; ++ks) {
    const ushort* Ah = Ahi + ks * 4096;
    const ushort* Bh = Bhi + ks * 4096;
    const ushort* Bl = Blo + ks * 4096;
    gload16(Ah + L8,        &As_hi[ldsb0]);
    gload16(Ah + 2048 + L8, &As_hi[ldsb1]);
    gload16(Bh + L8,        &Bs_hi[ldsb0]);
    gload16(Bh + 2048 + L8, &Bs_hi[ldsb1]);
    gload16(Bl + L8,        &Bs_lo[ldsb0]);
    gload16(Bl + 2048 + L8, &Bs_lo[ldsb1]);
    __syncthreads();
    bf16x8 ah[4], bh[4], bl2[2];
    #pragma unroll
    for (int mi = 0; mi < 4; ++mi) {
      const int ra = (kc * 128 + wr * 64 + mi * 16 + fr) * 8;
      ah[mi] = *reinterpret_cast<const bf16x8*>(&As_hi[ra]);
    }
    #pragma unroll
    for (int ni = 0; ni < 4; ++ni) {
      const int rb = (kc * 128 + wc * 64 + ni * 16 + fr) * 8;
      bh[ni] = *reinterpret_cast<const bf16x8*>(&Bs_hi[rb]);
      if (ni < 2) bl2[ni] = *reinterpret_cast<const bf16x8*>(&Bs_lo[rb]);
    }
    #pragma unroll
    for (int mi = 0; mi < 4; ++mi) {
      #pragma unroll
      for (int ni = 0; ni < 4; ++ni)
        acc[mi][ni] = __builtin_amdgcn_mfma_f32_16x16x32_bf16(ah[mi], bh[ni], acc[mi][ni], 0, 0, 0);
      #pragma unroll
      for (int ni = 0; ni < 2; ++ni)
        acc[mi][ni] = __builtin_amdgcn_mfma_f32_16x16x32_bf16(ah[mi], bl2[ni], acc[mi][ni], 0, 0, 0);
    }
    __syncthreads();
  }

  float lsum = 0.f, lsq = 0.f, cs0 = 0.f, cs1 = 0.f;
  const int d = ct * 2 + wc;
  #pragma unroll
  for (int mi = 0; mi < 4; ++mi) {
    const int rbase = m0 + wr * 64 + mi * 16 + ((lane >> 4) << 2);
    #pragma unroll
    for (int ni = 0; ni < 4; ++ni) {
      if (ni < 2) {
        const int p = ni * 16 + fr;
        float t0 = fast_tanh(acc[mi][ni][0]);
        float t1 = fast_tanh(acc[mi][ni][1]);
        float t2 = fast_tanh(acc[mi][ni][2]);
        float t3 = fast_tanh(acc[mi][ni][3]);
        lsum += t0 + t1 + t2 + t3;
        lsq += t0 * t0 + t1 * t1 + t2 * t2 + t3 * t3;
        ushort4 pk;
        pk.x = bf16rn(t0); pk.y = bf16rn(t1); pk.z = bf16rn(t2); pk.w = bf16rn(t3);
        *reinterpret_cast<ushort4*>(&Tb[((size_t)d * 32 + p) * 512 + rbase]) = pk;
      } else {
        #pragma unroll
        for (int r = 0; r < 4; ++r) {
          float e = __expf(acc[mi][ni][r]);
          if (ni == 2) cs0 += e; else cs1 += e;
        }
      }
    }
  }
  #pragma unroll
  for (int m = 1; m < 64; m <<= 1) { lsum += __shfl_xor(lsum, m); lsq += __shfl_xor(lsq, m); }
  cs0 += __shfl_xor(cs0, 16); cs0 += __shfl_xor(cs0, 32);
  cs1 += __shfl_xor(cs1, 16); cs1 += __shfl_xor(cs1, 32);
  if (lane == 0) { rsum[w] = lsum; rsq[w] = lsq; }
  if (lane < 16) { rcol[w][lane] = cs0; rcol[w][16 + lane] = cs1; }
  __syncthreads();
  if (tid < 64) {
    const int wc2 = tid >> 5, p = tid & 31;
    float* pb = partial + (((size_t)b * 4 + tm) * 8 + ct * 2 + wc2) * 34;
    pb[2 + p] = rcol[wc2][p] + rcol[wc2 + 2][p];
    if (p == 0) {
      pb[0] = rsum[wc2] + rsum[wc2 + 2];
      pb[1] = rsq[wc2] + rsq[wc2 + 2];
    }
  }
}

// ---------------- K3: fold the 4 row-tile partials -> per-(b,d) stats ----------------
__global__ void reduce_stats_kernel(const float* __restrict__ pJ, const float* __restrict__ pI,
                                    float* __restrict__ stats) {
  const int bd = blockIdx.x;
  const int b = bd >> 3, d = bd & 7;
  const int t = threadIdx.x;   // 128 threads
  __shared__ float tmp[2][34];
  if (t < 34) {
    float v = 0.f;
    for (int tm = 0; tm < 4; ++tm) v += pJ[(((size_t)b * 4 + tm) * 8 + d) * 34 + t];
    tmp[0][t] = v;
  } else if (t >= 64 && t < 98) {
    const int u = t - 64;
    float v = 0.f;
    for (int tm = 0; tm < 4; ++tm) v += pI[(((size_t)b * 4 + tm) * 8 + d) * 34 + u];
    tmp[1][u] = v;
  }
  __syncthreads();
  if (t < 2) {
    const float* tp = tmp[t];
    float* st = stats + (size_t)bd * 68;
    const float N = 16384.f;
    float mean = tp[0] / N;
    float var = (tp[1] - tp[0] * tp[0] / N) / (N - 1.f);
    float rstd = 1.f / (sqrtf(fmaxf(var, 0.f)) + EPSF);
    st[t * 2 + 0] = mean;
    st[t * 2 + 1] = rstd;
    float tot = 0.f;
    for (int k = 0; k < 32; ++k) tot += tp[2 + k];
    float inv = 1.f / tot;
    for (int k = 0; k < 32; ++k) st[4 + t * 32 + k] = tp[2 + k] * inv;
  }
}

// ---------------- K4: fused stage3: MFMA projections + rel softmax + combine ----------------
// Block per (b,d). Waves: w = path*2 + mt. All operand loads global->VGPR (no LDS staging).
// path 0 (J): M[p][q] = sum_i Tt_J[p][i] W_J[q][i]  -> A = Tt_J rows, B = W_J(hi+lo)
// path 1 (I): M[q][p] = sum_j W_I[q][j] Tt_I[p][j]  -> A = W_I(hi+lo), B = Tt_I
__global__ __launch_bounds__(256) void stage3_fused(
    const ushort* __restrict__ Ttj, const ushort* __restrict__ Tti,
    const ushort* __restrict__ Wthi, const ushort* __restrict__ Wtlo,
    const float* __restrict__ colWs,
    const float* __restrict__ rel_pj, const float* __restrict__ rel_pi,
    const float* __restrict__ stats, const float* __restrict__ bpart,
    const float* __restrict__ gamma_p, const float* __restrict__ beta_p,
    float* __restrict__ xball) {
  const int bd = blockIdx.x;
  const int b = bd >> 3, d = bd & 7;
  const int tid = threadIdx.x;
  const int lane = tid & 63, w = tid >> 6;
  const int path = w >> 1, mt = w & 1;
  const int fr = lane & 15, kg = lane >> 4;

  __shared__ float Vl[2][32][33];
  __shared__ float Rl[2][32][32];
  __shared__ float cred[2][32][33];
  __shared__ float colw_s[64];
  __shared__ float pred[4][2];
  __shared__ float csum[2][32];
  __shared__ float stot[2];
  __shared__ float fsc[2][32];
  __shared__ float red[256], red2[256];
  __shared__ float sred[2], sbst[2];

  // stage R matrices, colW, batch stats
  for (int l = tid; l < 2048; l += 256) {
    const int pp = l >> 10, idx = l & 1023;
    const float* Rsrc = pp ? rel_pi : rel_pj;
    Rl[pp][idx >> 5][idx & 31] = Rsrc[(size_t)d * 1024 + idx];
  }
  if (tid < 64) colw_s[tid] = colWs[(((size_t)(tid >> 5) * 8 + d)) * 32 + (tid & 31)];
  if (tid >= 128 && tid < 192) {
    const int t = tid - 128;
    float s = bpart[(size_t)b * 128 + t * 2];
    float s2 = bpart[(size_t)b * 128 + t * 2 + 1];
    #pragma unroll
    for (int m = 1; m < 64; m <<= 1) { s += __shfl_xor(s, m); s2 += __shfl_xor(s2, m); }
    if (t == 0) {
      const float N = 262144.f;
      float mean = s / N;
      float var = (s2 - s * s / N) / (N - 1.f);
      sbst[0] = mean * 256.f;
      sbst[1] = sqrtf(fmaxf(var, 0.f)) * 256.f;
    }
  }
  __syncthreads();

  // ---- MFMA projection: 16 rows (this wave) x 32 cols, K=512 ----
  f32x4 acc0 = {}, acc1 = {};
  const ushort* Whi_p = Wthi + ((size_t)path * 8 + d) * 16384;
  const ushort* Wlo_p = Wtlo + ((size_t)path * 8 + d) * 16384;
  const ushort* Tp = (path ? Tti : Ttj) + ((size_t)b * 8 + d) * 16384;

  if (path == 0) {
    const ushort* Arow = Tp + (size_t)(mt * 16 + fr) * 512;
    const ushort* B0h = Whi_p + (size_t)fr * 512;
    const ushort* B0l = Wlo_p + (size_t)fr * 512;
    const ushort* B1h = Whi_p + (size_t)(16 + fr) * 512;
    const ushort* B1l = Wlo_p + (size_t)(16 + fr) * 512;
    for (int k0 = 0; k0 < 512; k0 += 32) {
      const int ko = k0 + kg * 8;
      bf16x8 a   = *reinterpret_cast<const bf16x8*>(Arow + ko);
      bf16x8 b0h = *reinterpret_cast<const bf16x8*>(B0h + ko);
      bf16x8 b0l = *reinterpret_cast<const bf16x8*>(B0l + ko);
      bf16x8 b1h = *reinterpret_cast<const bf16x8*>(B1h + ko);
      bf16x8 b1l = *reinterpret_cast<const bf16x8*>(B1l + ko);
      acc0 = __builtin_amdgcn_mfma_f32_16x16x32_bf16(a, b0h, acc0, 0, 0, 0);
      acc0 = __builtin_amdgcn_mfma_f32_16x16x32_bf16(a, b0l, acc0, 0, 0, 0);
      acc1 = __builtin_amdgcn_mfma_f32_16x16x32_bf16(a, b1h, acc1, 0, 0, 0);
      acc1 = __builtin_amdgcn_mfma_f32_16x16x32_bf16(a, b1l, acc1, 0, 0, 0);
    }
  } else {
    const ushort* Ahr = Whi_p + (size_t)(mt * 16 + fr) * 512;
    const ushort* Alr = Wlo_p + (size_t)(mt * 16 + fr) * 512;
    const ushort* B0 = Tp + (size_t)fr * 512;
    const ushort* B1 = Tp + (size_t)(16 + fr) * 512;
    for (int k0 = 0; k0 < 512; k0 += 32) {
      const int ko = k0 + kg * 8;
      bf16x8 ah = *reinterpret_cast<const bf16x8*>(Ahr + ko);
      bf16x8 al = *reinterpret_cast<const bf16x8*>(Alr + ko);
      bf16x8 b0 = *reinterpret_cast<const bf16x8*>(B0 + ko);
      bf16x8 b1 = *reinterpret_cast<const bf16x8*>(B1 + ko);
      acc0 = __builtin_amdgcn_mfma_f32_16x16x32_bf16(ah, b0, acc0, 0, 0, 0);
      acc0 = __builtin_amdgcn_mfma_f32_16x16x32_bf16(al, b0, acc0, 0, 0, 0);
      acc1 = __builtin_amdgcn_mfma_f32_16x16x32_bf16(ah, b1, acc1, 0, 0, 0);
      acc1 = __builtin_amdgcn_mfma_f32_16x16x32_bf16(al, b1, acc1, 0, 0, 0);
    }
  }

  // ---- corrected standardize + tanh ----
  const float* st = stats + (size_t)bd * 68;
  const float mean = st[path * 2], rstd = st[path * 2 + 1];
  float tv0[4], tv1[4];
  float ls = 0.f, lq = 0.f;
  #pragma unroll
  for (int r = 0; r < 4; ++r) {
    const int rowm = mt * 16 + kg * 4 + r;
    {
      const int col = fr;
      const float cw = (path == 0) ? colw_s[col] : colw_s[32 + rowm];
      float t = fast_tanh((acc0[r] - mean * cw) * rstd);
      tv0[r] = t; ls += t; lq += t * t;
    }
    {
      const int col = 16 + fr;
      const float cw = (path == 0) ? colw_s[col] : colw_s[32 + rowm];
      float t = fast_tanh((acc1[r] - mean * cw) * rstd);
      tv1[r] = t; ls += t; lq += t * t;
    }
  }
  #pragma unroll
  for (int m = 1; m < 64; m <<= 1) { ls += __shfl_xor(ls, m); lq += __shfl_xor(lq, m); }
  if (lane == 0) { pred[w][0] = ls; pred[w][1] = lq; }
  __syncthreads();
  {
    const float S = pred[path * 2][0] + pred[path * 2 + 1][0];
    const float SS = pred[path * 2][1] + pred[path * 2 + 1][1];
    const float m2 = S / 1024.f;
    const float var = (SS - S * S / 1024.f) / 1023.f;
    const float r2 = 1.f / (sqrtf(fmaxf(var, 0.f)) + EPSF);
    #pragma unroll
    for (int r = 0; r < 4; ++r) {
      const int rowm = mt * 16 + kg * 4 + r;
      Vl[path][rowm][fr] = (tv0[r] - m2) * r2;
      Vl[path][rowm][16 + fr] = (tv1[r] - m2) * r2;
    }
  }
  __syncthreads();

  // ---- rel matmul + exp (128 threads per path) ----
  {
    const int t2 = tid & 127;
    const int prow = t2 >> 2, c8 = (t2 & 3) * 8;
    float racc[8] = {};
    #pragma unroll
    for (int c = 0; c < 32; ++c) {
      const float v = Vl[path][prow][c];
      #pragma unroll
      for (int e = 0; e < 8; ++e) racc[e] = fmaf(v, Rl[path][c][c8 + e], racc[e]);
    }
    #pragma unroll
    for (int e = 0; e < 8; ++e) cred[path][prow][c8 + e] = __expf(racc[e]);
  }
  __syncthreads();
  if (tid < 64) {
    const int pp = tid >> 5, q = tid & 31;
    float s = 0.f;
    #pragma unroll 8
    for (int p = 0; p < 32; ++p) s += cred[pp][p][q];
    csum[pp][q] = s;
  }
  __syncthreads();
  if (tid < 2) {
    float tot = 0.f;
    for (int k = 0; k < 32; ++k) tot += csum[tid][k];
    stot[tid] = tot;
  }
  __syncthreads();
  if (tid < 64) {
    const int pp = tid >> 5, q = tid & 31;
    fsc[pp][q] = sqrtf(st[4 + pp * 32 + q] * stot[pp] / csum[pp][q]);
  }
  __syncthreads();

  // ---- combine ----
  const int row = tid >> 3, c4 = (tid & 7) * 4;
  float xv[4]; float ls2 = 0.f, lq2 = 0.f;
  #pragma unroll
  for (int e = 0; e < 4; ++e) {
    const int q = c4 + e;
    float v = fast_tanh(Vl[0][row][q] * fsc[0][row] * Vl[1][q][row] * fsc[1][q]);
    xv[e] = v; ls2 += v; lq2 += v * v;
  }
  red[tid] = ls2; red2[tid] = lq2;
  __syncthreads();
  for (int off = 128; off > 0; off >>= 1) {
    if (tid < off) { red[tid] += red[tid + off]; red2[tid] += red2[tid + off]; }
    __syncthreads();
  }
  if (tid == 0) {
    float s = red[0], ss = red2[0];
    float m = s / 1024.f;
    float var = (ss - s * s / 1024.f) / 1023.f;
    sred[0] = m; sred[1] = 1.f / (sqrtf(fmaxf(var, 0.f)) + EPSF);
  }
  __syncthreads();
  const float m3 = sred[0], r3 = sred[1];
  const float xm = sbst[0], xs = sbst[1];
  const float g = gamma_p[d], be = beta_p[d];
  #pragma unroll
  for (int e = 0; e < 4; ++e) {
    float v = (xv[e] - m3) * r3 * xs + xm;
    xball[(size_t)bd * 1024 + row * 32 + c4 + e] = v * g + be;
  }
}

// ---------------- K5: sum over d / D ----------------
__global__ void final_kernel(const float* __restrict__ xball, float* __restrict__ out) {
  const int b = blockIdx.x;
  for (int e = threadIdx.x; e < 1024; e += 256) {
    float s = 0.f;
    #pragma unroll
    for (int d = 0; d < 8; ++d) s += xball[((size_t)(b * 8 + d)) * 1024 + e];
    out[(size_t)b * 1024 + e] = s * 0.125f;
  }
}

extern "C" void kernel_launch(void* const* d_in, const int* in_sizes, int n_in,
                              void* d_out, int out_size, void* d_ws, size_t ws_size,
                              hipStream_t stream) {
  const float* x        = (const float*)d_in[0];
  const float* o_xj     = (const float*)d_in[1];
  const float* o_xi     = (const float*)d_in[2];
  const float* p_xj     = (const float*)d_in[3];
  const float* p_xi     = (const float*)d_in[4];
  const float* rel_o_xj = (const float*)d_in[5];
  const float* rel_o_xi = (const float*)d_in[6];
  const float* rel_p_xj = (const float*)d_in[7];
  const float* rel_p_xi = (const float*)d_in[8];
  const float* gamma_p  = (const float*)d_in[9];
  const float* beta_p   = (const float*)d_in[10];
  float* out = (float*)d_out;

  char* base = (char*)d_ws;
  ushort* xhi  = (ushort*)base; base += (size_t)33554432;
  ushort* xthi = (ushort*)base; base += (size_t)33554432;
  ushort* wjhi = (ushort*)base; base += 524288;
  ushort* wjlo = (ushort*)base; base += 524288;
  ushort* wihi = (ushort*)base; base += 524288;
  ushort* wilo = (ushort*)base; base += 524288;
  ushort* Ttj  = (ushort*)base; base += (size_t)16777216;
  ushort* Tti  = (ushort*)base; base += (size_t)16777216;
  ushort* Wthi = (ushort*)base; base += 524288;
  ushort* Wtlo = (ushort*)base; base += 524288;
  float* colWs = (float*)base;  base += 2048;
  float* pJ    = (float*)base;  base += 278528;
  float* pI    = (float*)base;  base += 278528;
  float* bpart = (float*)base;  base += 32768;
  float* stats = (float*)base;  base += 139264;
  float* xball = (float*)base;  base += 2097152;

  hipLaunchKernelGGL(conv_pack, dim3(4368), dim3(256), 0, stream,
                     x, o_xj, o_xi, rel_o_xj, rel_o_xi, p_xj, p_xi,
                     xhi, xthi, wjhi, wjlo, wihi, wilo, Wthi, Wtlo, colWs, bpart);
  hipLaunchKernelGGL(mfma_gemm, dim3(2048), dim3(256), 0, stream,
                     xhi, xthi, wjhi, wjlo, wihi, wilo, Ttj, Tti, pJ, pI);
  hipLaunchKernelGGL(reduce_stats_kernel, dim3(512), dim3(128), 0, stream, pJ, pI, stats);
  hipLaunchKernelGGL(stage3_fused, dim3(512), dim3(256), 0, stream,
                     Ttj, Tti, Wthi, Wtlo, colWs, rel_p_xj, rel_p_xi, stats, bpart,
                     gamma_p, beta_p, xball);
  hipLaunchKernelGGL(final_kernel, dim3(64), dim3(256), 0, stream, xball, out);
}

// Round 8
// 105.975 us; speedup vs baseline: 5.6391x; 1.1737x over previous
//
#include <hip/hip_runtime.h>
#include <math.h>

static constexpr float EPSF = 1e-5f;

typedef short bf16x8 __attribute__((ext_vector_type(8)));
typedef float f32x4 __attribute__((ext_vector_type(4)));
typedef ushort u16x8 __attribute__((ext_vector_type(8)));

__device__ inline ushort bf16rn(float f) {
  unsigned u = __float_as_uint(f);
  unsigned r = (u + 0x7FFFu + ((u >> 16) & 1u)) >> 16;
  return (ushort)r;
}
__device__ inline float bf2f(ushort u) { return __uint_as_float(((unsigned)u) << 16); }
__device__ inline void split2(float f, ushort& hi, ushort& lo) {
  ushort h = bf16rn(f);
  float hf = bf2f(h);
  hi = h;
  lo = bf16rn(f - hf);
}
// tanh via hw exp+rcp: exact at saturation, ~1e-7 abs err
__device__ inline float fast_tanh(float x) {
  float e = __expf(2.f * x);
  return 1.f - 2.f * __builtin_amdgcn_rcpf(e + 1.f);
}

__device__ inline void gload16(const ushort* g, ushort* l) {
  __builtin_amdgcn_global_load_lds((const __attribute__((address_space(1))) void*)g,
                                   (__attribute__((address_space(3))) void*)l, 16, 0, 0);
}

// Tiled layout (ushort index): addr(row,k) = (row>>7)*65536 + (k>>5)*4096
//   + ((k>>3)&3)*1024 + (row&127)*8 + (k&7)
__device__ inline size_t tiled_addr(int row, int k) {
  return (size_t)(row >> 7) * 65536 + (size_t)(k >> 5) * 4096 +
         (size_t)((k >> 3) & 3) * 1024 + (size_t)(row & 127) * 8 + (k & 7);
}

// ---------------- K1: fused convx (0..4095) + pack_w (4096..4351) + pack_pw (4352..4367) ----------------
__global__ __launch_bounds__(256) void conv_pack(
    const float* __restrict__ x,
    const float* __restrict__ o_xj, const float* __restrict__ o_xi,
    const float* __restrict__ rel_o_xj, const float* __restrict__ rel_o_xi,
    const float* __restrict__ p_xj, const float* __restrict__ p_xi,
    ushort* __restrict__ xhi, ushort* __restrict__ xthi,
    ushort* __restrict__ wjhi, ushort* __restrict__ wihi,
    ushort* __restrict__ Wthi, ushort* __restrict__ Wtlo,
    float* __restrict__ colWs,
    float* __restrict__ bpart) {
  const int bx = blockIdx.x;
  const int tid = threadIdx.x;
  if (bx >= 4352) {
    // ---- pack_pw: p_xj/p_xi -> Wt[path][d][q][512] bf16 hi/lo + colWs ----
    const int pd = bx - 4352;            // 0..15
    const int path = pd >> 3, d = pd & 7;
    const float* src = (path ? p_xi : p_xj) + (size_t)d * 16384;
    ushort* whi = Wthi + (size_t)pd * 16384;
    ushort* wlo = Wtlo + (size_t)pd * 16384;
    __shared__ float buf[64][33];
    float cw = 0.f;
    const int q = tid >> 3, je8 = (tid & 7) * 8;
    for (int j0 = 0; j0 < 512; j0 += 64) {
      for (int l = tid; l < 2048; l += 256) buf[l >> 5][l & 31] = src[(size_t)j0 * 32 + l];
      __syncthreads();
      u16x8 h8, l8;
      #pragma unroll
      for (int e = 0; e < 8; ++e) {
        float fv = buf[je8 + e][q];
        cw += fv;
        ushort h, l; split2(fv, h, l);
        h8[e] = h; l8[e] = l;
      }
      *reinterpret_cast<u16x8*>(&whi[(size_t)q * 512 + j0 + je8]) = h8;
      *reinterpret_cast<u16x8*>(&wlo[(size_t)q * 512 + j0 + je8]) = l8;
      __syncthreads();
    }
    cw += __shfl_xor(cw, 1); cw += __shfl_xor(cw, 2); cw += __shfl_xor(cw, 4);
    if ((tid & 7) == 0) colWs[(size_t)pd * 32 + q] = cw;
    return;
  }
  if (bx >= 4096) {
    // ---- pack_w (o-weights, tiled bf16) ----
    int u = (bx - 4096) * 256 + tid;   // 0..65535
    int path = u >> 15;
    int v = u & 32767;
    int c = v >> 6;
    int k0 = (v & 63) * 8;
    int d = c >> 6, s = (c >> 5) & 1, p = c & 31;
    const float* src = path ? (s ? rel_o_xi : o_xi) : (s ? rel_o_xj : o_xj);
    u16x8 h8;
    #pragma unroll
    for (int e = 0; e < 8; ++e) h8[e] = bf16rn(src[((size_t)d * 512 + k0 + e) * 32 + p]);
    size_t a = tiled_addr(c, k0);
    ushort* whi = path ? wihi : wjhi;
    *reinterpret_cast<u16x8*>(&whi[a]) = h8;
    return;
  }
  // ---- convx part ----
  __shared__ float tile[64][65];
  __shared__ float rs[256], rs2[256];
  const int ti = bx & 7, tj = (bx >> 3) & 7, b = bx >> 6;
  const int i0 = ti * 64, j0 = tj * 64;
  const float* xb = x + (size_t)b * 262144;
  const size_t obase = (size_t)b * 262144;
  const int tr = tid >> 4;
  const int tc = (tid & 15) * 4;
  float s = 0.f, s2 = 0.f;
  #pragma unroll
  for (int r = 0; r < 4; ++r) {
    const int row = r * 16 + tr;
    float4 v = *reinterpret_cast<const float4*>(&xb[(size_t)(i0 + row) * 512 + j0 + tc]);
    tile[row][tc + 0] = v.x; tile[row][tc + 1] = v.y;
    tile[row][tc + 2] = v.z; tile[row][tc + 3] = v.w;
    s += v.x + v.y + v.z + v.w;
    s2 += v.x * v.x + v.y * v.y + v.z * v.z + v.w * v.w;
  }
  __syncthreads();
  const int kg = tid >> 5;   // 0..7
  const int rp = tid & 31;
  #pragma unroll
  for (int rr = 0; rr < 2; ++rr) {
    const int li = rp + rr * 32;
    u16x8 h8;
    #pragma unroll
    for (int e = 0; e < 8; ++e) h8[e] = bf16rn(tile[li][kg * 8 + e]);
    *reinterpret_cast<u16x8*>(&xhi[obase + tiled_addr(i0 + li, j0 + kg * 8)]) = h8;
  }
  #pragma unroll
  for (int rr = 0; rr < 2; ++rr) {
    const int lj = rp + rr * 32;
    u16x8 h8;
    #pragma unroll
    for (int e = 0; e < 8; ++e) h8[e] = bf16rn(tile[kg * 8 + e][lj]);
    *reinterpret_cast<u16x8*>(&xthi[obase + tiled_addr(j0 + lj, i0 + kg * 8)]) = h8;
  }
  rs[tid] = s; rs2[tid] = s2;
  __syncthreads();
  for (int off = 128; off > 0; off >>= 1) {
    if (tid < off) { rs[tid] += rs[tid + off]; rs2[tid] += rs2[tid + off]; }
    __syncthreads();
  }
  if (tid == 0) {
    float* pb = bpart + ((size_t)b * 64 + tj * 8 + ti) * 2;
    pb[0] = rs[0]; pb[1] = rs2[0];
  }
}

// ---------------- K2: pure-bf16 MFMA GEMM + fused epilogue ----------------
// T output written TRANSPOSED: Tt[b][d][p 32][i 512] (bf16).
__global__ __launch_bounds__(256) void mfma_gemm(
    const ushort* __restrict__ xhi, const ushort* __restrict__ xthi,
    const ushort* __restrict__ wjhi, const ushort* __restrict__ wihi,
    ushort* __restrict__ Ttj, ushort* __restrict__ Tti,
    float* __restrict__ pJ, float* __restrict__ pI) {
  const int id = blockIdx.x;
  const int wid = (id & 7) * 256 + (id >> 3);   // XCD-aware swizzle (2048 = 8*256)
  const int ct = wid & 3, tm = (wid >> 2) & 3, bz = wid >> 4;
  const int b = bz >> 1, path = bz & 1;
  const ushort* Ahi = (path ? xthi : xhi) + (size_t)b * 262144 + (size_t)tm * 65536;
  const ushort* Bhi = (path ? wihi : wjhi) + (size_t)ct * 65536;
  ushort* Tb = (path ? Tti : Ttj) + (size_t)b * 131072;
  float* partial = path ? pI : pJ;

  __shared__ alignas(16) ushort As_hi[4096], Bs_hi[4096];
  __shared__ float rsum[4], rsq[4], rcol[4][32];

  const int tid = threadIdx.x;
  const int lane = tid & 63, w = tid >> 6;
  const int wr = w >> 1, wc = w & 1;
  const int m0 = tm * 128;

  const int L8 = (w * 64 + lane) * 8;
  const int ldsb0 = (w * 64) * 8;
  const int ldsb1 = 2048 + (w * 64) * 8;

  f32x4 acc[4][4] = {};
  const int fr = lane & 15;
  const int kc = lane >> 4;

  for (int ks = 0; ks < 16; ++ks) {
    const ushort* Ah = Ahi + ks * 4096;
    const ushort* Bh = Bhi + ks * 4096;
    gload16(Ah + L8,        &As_hi[ldsb0]);
    gload16(Ah + 2048 + L8, &As_hi[ldsb1]);
    gload16(Bh + L8,        &Bs_hi[ldsb0]);
    gload16(Bh + 2048 + L8, &Bs_hi[ldsb1]);
    __syncthreads();
    bf16x8 ah[4], bh[4];
    #pragma unroll
    for (int mi = 0; mi < 4; ++mi) {
      const int ra = (kc * 128 + wr * 64 + mi * 16 + fr) * 8;
      ah[mi] = *reinterpret_cast<const bf16x8*>(&As_hi[ra]);
    }
    #pragma unroll
    for (int ni = 0; ni < 4; ++ni) {
      const int rb = (kc * 128 + wc * 64 + ni * 16 + fr) * 8;
      bh[ni] = *reinterpret_cast<const bf16x8*>(&Bs_hi[rb]);
    }
    #pragma unroll
    for (int mi = 0; mi < 4; ++mi)
      #pragma unroll
      for (int ni = 0; ni < 4; ++ni)
        acc[mi][ni] = __builtin_amdgcn_mfma_f32_16x16x32_bf16(ah[mi], bh[ni], acc[mi][ni], 0, 0, 0);
    __syncthreads();
  }

  float lsum = 0.f, lsq = 0.f, cs0 = 0.f, cs1 = 0.f;
  const int d = ct * 2 + wc;
  #pragma unroll
  for (int mi = 0; mi < 4; ++mi) {
    const int rbase = m0 + wr * 64 + mi * 16 + ((lane >> 4) << 2);
    #pragma unroll
    for (int ni = 0; ni < 4; ++ni) {
      if (ni < 2) {
        const int p = ni * 16 + fr;
        float t0 = fast_tanh(acc[mi][ni][0]);
        float t1 = fast_tanh(acc[mi][ni][1]);
        float t2 = fast_tanh(acc[mi][ni][2]);
        float t3 = fast_tanh(acc[mi][ni][3]);
        lsum += t0 + t1 + t2 + t3;
        lsq += t0 * t0 + t1 * t1 + t2 * t2 + t3 * t3;
        ushort4 pk;
        pk.x = bf16rn(t0); pk.y = bf16rn(t1); pk.z = bf16rn(t2); pk.w = bf16rn(t3);
        *reinterpret_cast<ushort4*>(&Tb[((size_t)d * 32 + p) * 512 + rbase]) = pk;
      } else {
        #pragma unroll
        for (int r = 0; r < 4; ++r) {
          float e = __expf(acc[mi][ni][r]);
          if (ni == 2) cs0 += e; else cs1 += e;
        }
      }
    }
  }
  #pragma unroll
  for (int m = 1; m < 64; m <<= 1) { lsum += __shfl_xor(lsum, m); lsq += __shfl_xor(lsq, m); }
  cs0 += __shfl_xor(cs0, 16); cs0 += __shfl_xor(cs0, 32);
  cs1 += __shfl_xor(cs1, 16); cs1 += __shfl_xor(cs1, 32);
  if (lane == 0) { rsum[w] = lsum; rsq[w] = lsq; }
  if (lane < 16) { rcol[w][lane] = cs0; rcol[w][16 + lane] = cs1; }
  __syncthreads();
  if (tid < 64) {
    const int wc2 = tid >> 5, p = tid & 31;
    float* pb = partial + (((size_t)b * 4 + tm) * 8 + ct * 2 + wc2) * 34;
    pb[2 + p] = rcol[wc2][p] + rcol[wc2 + 2][p];
    if (p == 0) {
      pb[0] = rsum[wc2] + rsum[wc2 + 2];
      pb[1] = rsq[wc2] + rsq[wc2 + 2];
    }
  }
}

// ---------------- K3: fused stage3 (now also folds the gemm partials) ----------------
// Block per (b,d). Waves: w = path*2 + mt.
__global__ __launch_bounds__(256) void stage3_fused(
    const ushort* __restrict__ Ttj, const ushort* __restrict__ Tti,
    const ushort* __restrict__ Wthi, const ushort* __restrict__ Wtlo,
    const float* __restrict__ colWs,
    const float* __restrict__ rel_pj, const float* __restrict__ rel_pi,
    const float* __restrict__ pJ, const float* __restrict__ pI,
    const float* __restrict__ bpart,
    const float* __restrict__ gamma_p, const float* __restrict__ beta_p,
    float* __restrict__ xball) {
  const int bd = blockIdx.x;
  const int b = bd >> 3, d = bd & 7;
  const int tid = threadIdx.x;
  const int lane = tid & 63, w = tid >> 6;
  const int path = w >> 1, mt = w & 1;
  const int fr = lane & 15, kg = lane >> 4;

  __shared__ float Vl[2][32][33];
  __shared__ float Rl[2][32][32];
  __shared__ float cred[2][32][33];
  __shared__ float colw_s[64];
  __shared__ float stS[2][34];     // folded raw sums: [path]{sum,sumsq,col[32]}
  __shared__ float ms[2][2];       // [path]{mean, rstd}
  __shared__ float orelT[2];
  __shared__ float pred[4][2];
  __shared__ float csum[2][32];
  __shared__ float stot[2];
  __shared__ float fsc[2][32];
  __shared__ float red[256], red2[256];
  __shared__ float sred[2], sbst[2];

  // stage R matrices, colW, folded stats, batch stats
  for (int l = tid; l < 2048; l += 256) {
    const int pp = l >> 10, idx = l & 1023;
    const float* Rsrc = pp ? rel_pi : rel_pj;
    Rl[pp][idx >> 5][idx & 31] = Rsrc[(size_t)d * 1024 + idx];
  }
  if (tid < 64) colw_s[tid] = colWs[(((size_t)(tid >> 5) * 8 + d)) * 32 + (tid & 31)];
  if (tid >= 64 && tid < 132) {
    const int u = tid - 64;
    const int pp = u >= 34, t = pp ? u - 34 : u;
    const float* P = pp ? pI : pJ;
    float v = 0.f;
    #pragma unroll
    for (int tm2 = 0; tm2 < 4; ++tm2) v += P[(((size_t)b * 4 + tm2) * 8 + d) * 34 + t];
    stS[pp][t] = v;
  }
  if (tid >= 192) {
    const int t = tid - 192;
    float s = bpart[(size_t)b * 128 + t * 2];
    float s2 = bpart[(size_t)b * 128 + t * 2 + 1];
    #pragma unroll
    for (int m = 1; m < 64; m <<= 1) { s += __shfl_xor(s, m); s2 += __shfl_xor(s2, m); }
    if (t == 0) {
      const float N = 262144.f;
      float mean = s / N;
      float var = (s2 - s * s / N) / (N - 1.f);
      sbst[0] = mean * 256.f;
      sbst[1] = sqrtf(fmaxf(var, 0.f)) * 256.f;
    }
  }
  __syncthreads();
  if (tid < 2) {
    const float* S = stS[tid];
    const float N = 16384.f;
    float mean = S[0] / N;
    float var = (S[1] - S[0] * S[0] / N) / (N - 1.f);
    ms[tid][0] = mean;
    ms[tid][1] = 1.f / (sqrtf(fmaxf(var, 0.f)) + EPSF);
    float tot = 0.f;
    for (int k = 0; k < 32; ++k) tot += S[2 + k];
    orelT[tid] = tot;
  }

  // ---- MFMA projection: 16 rows (this wave) x 32 cols, K=512 ----
  f32x4 acc0 = {}, acc1 = {};
  const ushort* Whi_p = Wthi + ((size_t)path * 8 + d) * 16384;
  const ushort* Wlo_p = Wtlo + ((size_t)path * 8 + d) * 16384;
  const ushort* Tp = (path ? Tti : Ttj) + ((size_t)b * 8 + d) * 16384;

  if (path == 0) {
    const ushort* Arow = Tp + (size_t)(mt * 16 + fr) * 512;
    const ushort* B0h = Whi_p + (size_t)fr * 512;
    const ushort* B0l = Wlo_p + (size_t)fr * 512;
    const ushort* B1h = Whi_p + (size_t)(16 + fr) * 512;
    const ushort* B1l = Wlo_p + (size_t)(16 + fr) * 512;
    for (int k0 = 0; k0 < 512; k0 += 32) {
      const int ko = k0 + kg * 8;
      bf16x8 a   = *reinterpret_cast<const bf16x8*>(Arow + ko);
      bf16x8 b0h = *reinterpret_cast<const bf16x8*>(B0h + ko);
      bf16x8 b0l = *reinterpret_cast<const bf16x8*>(B0l + ko);
      bf16x8 b1h = *reinterpret_cast<const bf16x8*>(B1h + ko);
      bf16x8 b1l = *reinterpret_cast<const bf16x8*>(B1l + ko);
      acc0 = __builtin_amdgcn_mfma_f32_16x16x32_bf16(a, b0h, acc0, 0, 0, 0);
      acc0 = __builtin_amdgcn_mfma_f32_16x16x32_bf16(a, b0l, acc0, 0, 0, 0);
      acc1 = __builtin_amdgcn_mfma_f32_16x16x32_bf16(a, b1h, acc1, 0, 0, 0);
      acc1 = __builtin_amdgcn_mfma_f32_16x16x32_bf16(a, b1l, acc1, 0, 0, 0);
    }
  } else {
    const ushort* Ahr = Whi_p + (size_t)(mt * 16 + fr) * 512;
    const ushort* Alr = Wlo_p + (size_t)(mt * 16 + fr) * 512;
    const ushort* B0 = Tp + (size_t)fr * 512;
    const ushort* B1 = Tp + (size_t)(16 + fr) * 512;
    for (int k0 = 0; k0 < 512; k0 += 32) {
      const int ko = k0 + kg * 8;
      bf16x8 ah = *reinterpret_cast<const bf16x8*>(Ahr + ko);
      bf16x8 al = *reinterpret_cast<const bf16x8*>(Alr + ko);
      bf16x8 b0 = *reinterpret_cast<const bf16x8*>(B0 + ko);
      bf16x8 b1 = *reinterpret_cast<const bf16x8*>(B1 + ko);
      acc0 = __builtin_amdgcn_mfma_f32_16x16x32_bf16(ah, b0, acc0, 0, 0, 0);
      acc0 = __builtin_amdgcn_mfma_f32_16x16x32_bf16(al, b0, acc0, 0, 0, 0);
      acc1 = __builtin_amdgcn_mfma_f32_16x16x32_bf16(ah, b1, acc1, 0, 0, 0);
      acc1 = __builtin_amdgcn_mfma_f32_16x16x32_bf16(al, b1, acc1, 0, 0, 0);
    }
  }
  __syncthreads();   // ms/orelT ready (also covers stS)

  // ---- corrected standardize + tanh ----
  const float mean = ms[path][0], rstd = ms[path][1];
  float tv0[4], tv1[4];
  float ls = 0.f, lq = 0.f;
  #pragma unroll
  for (int r = 0; r < 4; ++r) {
    const int rowm = mt * 16 + kg * 4 + r;
    {
      const float cw = (path == 0) ? colw_s[fr] : colw_s[32 + rowm];
      float t = fast_tanh((acc0[r] - mean * cw) * rstd);
      tv0[r] = t; ls += t; lq += t * t;
    }
    {
      const float cw = (path == 0) ? colw_s[16 + fr] : colw_s[32 + rowm];
      float t = fast_tanh((acc1[r] - mean * cw) * rstd);
      tv1[r] = t; ls += t; lq += t * t;
    }
  }
  #pragma unroll
  for (int m = 1; m < 64; m <<= 1) { ls += __shfl_xor(ls, m); lq += __shfl_xor(lq, m); }
  if (lane == 0) { pred[w][0] = ls; pred[w][1] = lq; }
  __syncthreads();
  {
    const float S = pred[path * 2][0] + pred[path * 2 + 1][0];
    const float SS = pred[path * 2][1] + pred[path * 2 + 1][1];
    const float m2 = S / 1024.f;
    const float var = (SS - S * S / 1024.f) / 1023.f;
    const float r2 = 1.f / (sqrtf(fmaxf(var, 0.f)) + EPSF);
    #pragma unroll
    for (int r = 0; r < 4; ++r) {
      const int rowm = mt * 16 + kg * 4 + r;
      Vl[path][rowm][fr] = (tv0[r] - m2) * r2;
      Vl[path][rowm][16 + fr] = (tv1[r] - m2) * r2;
    }
  }
  __syncthreads();

  // ---- rel matmul + exp (128 threads per path) ----
  {
    const int t2 = tid & 127;
    const int prow = t2 >> 2, c8 = (t2 & 3) * 8;
    float racc[8] = {};
    #pragma unroll
    for (int c = 0; c < 32; ++c) {
      const float v = Vl[path][prow][c];
      #pragma unroll
      for (int e = 0; e < 8; ++e) racc[e] = fmaf(v, Rl[path][c][c8 + e], racc[e]);
    }
    #pragma unroll
    for (int e = 0; e < 8; ++e) cred[path][prow][c8 + e] = __expf(racc[e]);
  }
  __syncthreads();
  if (tid < 64) {
    const int pp = tid >> 5, q = tid & 31;
    float s = 0.f;
    #pragma unroll 8
    for (int p = 0; p < 32; ++p) s += cred[pp][p][q];
    csum[pp][q] = s;
  }
  __syncthreads();
  if (tid < 2) {
    float tot = 0.f;
    for (int k = 0; k < 32; ++k) tot += csum[tid][k];
    stot[tid] = tot;
  }
  __syncthreads();
  if (tid < 64) {
    const int pp = tid >> 5, q = tid & 31;
    fsc[pp][q] = sqrtf((stS[pp][2 + q] / orelT[pp]) * stot[pp] / csum[pp][q]);
  }
  __syncthreads();

  // ---- combine ----
  const int row = tid >> 3, c4 = (tid & 7) * 4;
  float xv[4]; float ls2 = 0.f, lq2 = 0.f;
  #pragma unroll
  for (int e = 0; e < 4; ++e) {
    const int q = c4 + e;
    float v = fast_tanh(Vl[0][row][q] * fsc[0][row] * Vl[1][q][row] * fsc[1][q]);
    xv[e] = v; ls2 += v; lq2 += v * v;
  }
  red[tid] = ls2; red2[tid] = lq2;
  __syncthreads();
  for (int off = 128; off > 0; off >>= 1) {
    if (tid < off) { red[tid] += red[tid + off]; red2[tid] += red2[tid + off]; }
    __syncthreads();
  }
  if (tid == 0) {
    float s = red[0], ss = red2[0];
    float m = s / 1024.f;
    float var = (ss - s * s / 1024.f) / 1023.f;
    sred[0] = m; sred[1] = 1.f / (sqrtf(fmaxf(var, 0.f)) + EPSF);
  }
  __syncthreads();
  const float m3 = sred[0], r3 = sred[1];
  const float xm = sbst[0], xs = sbst[1];
  const float g = gamma_p[d], be = beta_p[d];
  #pragma unroll
  for (int e = 0; e < 4; ++e) {
    float v = (xv[e] - m3) * r3 * xs + xm;
    xball[(size_t)bd * 1024 + row * 32 + c4 + e] = v * g + be;
  }
}

// ---------------- K4: sum over d / D ----------------
__global__ void final_kernel(const float* __restrict__ xball, float* __restrict__ out) {
  const int b = blockIdx.x;
  for (int e = threadIdx.x; e < 1024; e += 256) {
    float s = 0.f;
    #pragma unroll
    for (int d = 0; d < 8; ++d) s += xball[((size_t)(b * 8 + d)) * 1024 + e];
    out[(size_t)b * 1024 + e] = s * 0.125f;
  }
}

extern "C" void kernel_launch(void* const* d_in, const int* in_sizes, int n_in,
                              void* d_out, int out_size, void* d_ws, size_t ws_size,
                              hipStream_t stream) {
  const float* x        = (const float*)d_in[0];
  const float* o_xj     = (const float*)d_in[1];
  const float* o_xi     = (const float*)d_in[2];
  const float* p_xj     = (const float*)d_in[3];
  const float* p_xi     = (const float*)d_in[4];
  const float* rel_o_xj = (const float*)d_in[5];
  const float* rel_o_xi = (const float*)d_in[6];
  const float* rel_p_xj = (const float*)d_in[7];
  const float* rel_p_xi = (const float*)d_in[8];
  const float* gamma_p  = (const float*)d_in[9];
  const float* beta_p   = (const float*)d_in[10];
  float* out = (float*)d_out;

  char* base = (char*)d_ws;
  ushort* xhi  = (ushort*)base; base += (size_t)33554432;
  ushort* xthi = (ushort*)base; base += (size_t)33554432;
  ushort* wjhi = (ushort*)base; base += 524288;
  ushort* wihi = (ushort*)base; base += 524288;
  ushort* Ttj  = (ushort*)base; base += (size_t)16777216;
  ushort* Tti  = (ushort*)base; base += (size_t)16777216;
  ushort* Wthi = (ushort*)base; base += 524288;
  ushort* Wtlo = (ushort*)base; base += 524288;
  float* colWs = (float*)base;  base += 2048;
  float* pJ    = (float*)base;  base += 278528;
  float* pI    = (float*)base;  base += 278528;
  float* bpart = (float*)base;  base += 32768;
  float* xball = (float*)base;  base += 2097152;

  hipLaunchKernelGGL(conv_pack, dim3(4368), dim3(256), 0, stream,
                     x, o_xj, o_xi, rel_o_xj, rel_o_xi, p_xj, p_xi,
                     xhi, xthi, wjhi, wihi, Wthi, Wtlo, colWs, bpart);
  hipLaunchKernelGGL(mfma_gemm, dim3(2048), dim3(256), 0, stream,
                     xhi, xthi, wjhi, wihi, Ttj, Tti, pJ, pI);
  hipLaunchKernelGGL(stage3_fused, dim3(512), dim3(256), 0, stream,
                     Ttj, Tti, Wthi, Wtlo, colWs, rel_p_xj, rel_p_xi, pJ, pI, bpart,
                     gamma_p, beta_p, xball);
  hipLaunchKernelGGL(final_kernel, dim3(64), dim3(256), 0, stream, xball, out);
}